// Round 1
// baseline (6129.394 us; speedup 1.0000x reference)
//
#include <hip/hip_runtime.h>
#include <math.h>

#define BB 32
#define NN 4096
#define NPp 256
#define NSs 64
#define KC 20

__device__ __forceinline__ float fma4(const float4 w, const float4 v, float a){
  a = fmaf(w.x, v.x, a); a = fmaf(w.y, v.y, a);
  a = fmaf(w.z, v.z, a); a = fmaf(w.w, v.w, a); return a;
}

// ---------------- transpose + point norms ----------------
__global__ void k_prep(const float* __restrict__ pts, float* __restrict__ xyz, float* __restrict__ xnrm){
  int i = blockIdx.x*256 + threadIdx.x;
  if (i >= BB*NN) return;
  int b = i >> 12, n = i & (NN-1);
  float X = pts[(b*3+0)*NN + n];
  float Y = pts[(b*3+1)*NN + n];
  float Z = pts[(b*3+2)*NN + n];
  xyz[i*3+0]=X; xyz[i*3+1]=Y; xyz[i*3+2]=Z;
  xnrm[i] = __fadd_rn(__fadd_rn(__fmul_rn(X,X), __fmul_rn(Y,Y)), __fmul_rn(Z,Z));
}

// ---------------- farthest point sampling ----------------
__global__ __launch_bounds__(256) void k_fps(const float* __restrict__ xyz, float* __restrict__ new_xyz){
  __shared__ float xs[NN], ys[NN], zs[NN];
  __shared__ float rv[4];
  __shared__ int   ri[4];
  __shared__ int   slast;
  int b = blockIdx.x, t = threadIdx.x;
  for (int j = t; j < NN; j += 256){
    const float* p = xyz + ((size_t)b*NN + j)*3;
    xs[j] = p[0]; ys[j] = p[1]; zs[j] = p[2];
  }
  float dist[16];
#pragma unroll
  for (int q = 0; q < 16; ++q) dist[q] = __builtin_inff();
  int last = 0;
  __syncthreads();
  for (int it = 0; it < NPp; ++it){
    if (t == 0){
      float* o = new_xyz + ((size_t)b*NPp + it)*3;
      o[0] = xs[last]; o[1] = ys[last]; o[2] = zs[last];
    }
    float px = xs[last], py = ys[last], pz = zs[last];
    float bv = -1.0f; int bj = 0;
#pragma unroll
    for (int q = 0; q < 16; ++q){
      int j = q*256 + t;
      float dx = __fsub_rn(xs[j], px);
      float dy = __fsub_rn(ys[j], py);
      float dz = __fsub_rn(zs[j], pz);
      float dd = __fadd_rn(__fadd_rn(__fmul_rn(dx,dx), __fmul_rn(dy,dy)), __fmul_rn(dz,dz));
      float dm = fminf(dist[q], dd);
      dist[q] = dm;
      if (dm > bv){ bv = dm; bj = j; }
    }
#pragma unroll
    for (int off = 32; off >= 1; off >>= 1){
      float ov = __shfl_xor(bv, off, 64);
      int   oj = __shfl_xor(bj, off, 64);
      if (ov > bv || (ov == bv && oj < bj)){ bv = ov; bj = oj; }
    }
    int w = t >> 6;
    if ((t & 63) == 0){ rv[w] = bv; ri[w] = bj; }
    __syncthreads();
    if (t == 0){
      float fv = rv[0]; int fj = ri[0];
      for (int ww = 1; ww < 4; ++ww)
        if (rv[ww] > fv || (rv[ww] == fv && ri[ww] < fj)){ fv = rv[ww]; fj = ri[ww]; }
      slast = fj;
    }
    __syncthreads();
    last = slast;
  }
}

// ---------------- ball query + SA convs + maxpool ----------------
__global__ __launch_bounds__(64) void k_sa(const float* __restrict__ xyz, const float* __restrict__ xnrm,
    const float* __restrict__ new_xyz, const float* __restrict__ w0, const float* __restrict__ w1,
    const float* __restrict__ w2, float* __restrict__ feat, float* __restrict__ x131){
  __shared__ float sw0[192];
  __shared__ __align__(16) float sw1[4096];
  __shared__ __align__(16) float h1s[64*68];
  __shared__ int gix[64];
  int bi = blockIdx.x, lane = threadIdx.x;
  int b = bi >> 8;
  for (int j = lane; j < 192; j += 64) sw0[j] = w0[j];
  for (int j = lane; j < 4096; j += 64) sw1[j] = w1[j];
  const float* q = new_xyz + (size_t)bi*3;
  float qx=q[0], qy=q[1], qz=q[2];
  float nq = __fadd_rn(__fadd_rn(__fmul_rn(qx,qx), __fmul_rn(qy,qy)), __fmul_rn(qz,qz));
  int cnt = 0;
  for (int base = 0; base < NN && cnt < NSs; base += 64){
    int j = base + lane;
    const float* p = xyz + ((size_t)b*NN + j)*3;
    float dot = __fadd_rn(__fadd_rn(__fmul_rn(qx,p[0]), __fmul_rn(qy,p[1])), __fmul_rn(qz,p[2]));
    float d2 = __fsub_rn(__fadd_rn(nq, xnrm[b*NN + j]), __fmul_rn(2.0f, dot));
    bool inb = d2 < 0.04f;
    unsigned long long m = __ballot(inb);
    int pos = cnt + (int)__popcll(m & ((1ull << lane) - 1ull));
    if (inb && pos < NSs) gix[pos] = j;
    cnt += (int)__popcll(m);
  }
  __syncthreads();
  int g0 = gix[0];
  if (lane >= cnt) gix[lane] = g0;
  __syncthreads();
  // phase 1: thread = sample
  {
    int gj = gix[lane];
    const float* p = xyz + ((size_t)b*NN + gj)*3;
    float px = p[0]-qx, py = p[1]-qy, pz = p[2]-qz;
    float h0[64];
#pragma unroll
    for (int c = 0; c < 64; ++c){
      float a = fmaf(sw0[c*3+2], pz, fmaf(sw0[c*3+1], py, sw0[c*3]*px));
      h0[c] = fmaxf(a, 0.0f);
    }
    for (int c = 0; c < 64; ++c){
      const float4* wr = (const float4*)(sw1 + c*64);
      float a = 0.0f;
#pragma unroll
      for (int qq = 0; qq < 16; ++qq){
        float4 w = wr[qq];
        a = fmaf(w.x, h0[4*qq+0], a);
        a = fmaf(w.y, h0[4*qq+1], a);
        a = fmaf(w.z, h0[4*qq+2], a);
        a = fmaf(w.w, h0[4*qq+3], a);
      }
      h1s[lane*68 + c] = fmaxf(a, 0.0f);
    }
  }
  __syncthreads();
  // phase 2: thread = output channel (c, c+64), W2 rows cached in regs
  float4 wa[16], wb[16];
#pragma unroll
  for (int qq = 0; qq < 16; ++qq){
    wa[qq] = *(const float4*)(w2 + (size_t)lane*64 + 4*qq);
    wb[qq] = *(const float4*)(w2 + (size_t)(lane+64)*64 + 4*qq);
  }
  float m0 = 0.0f, m1 = 0.0f;
  for (int s = 0; s < 64; ++s){
    const float4* hr = (const float4*)(h1s + s*68);
    float a0 = 0.0f, a1 = 0.0f;
#pragma unroll
    for (int qq = 0; qq < 16; ++qq){
      float4 h = hr[qq];
      a0 = fma4(wa[qq], h, a0);
      a1 = fma4(wb[qq], h, a1);
    }
    m0 = fmaxf(m0, a0); m1 = fmaxf(m1, a1);
  }
  feat[(size_t)bi*128 + lane]      = m0;
  feat[(size_t)bi*128 + 64 + lane] = m1;
  x131[(size_t)bi*132 + lane]      = m0;
  x131[(size_t)bi*132 + 64 + lane] = m1;
  if (lane < 3) x131[(size_t)bi*132 + 128 + lane] = (lane==0)?qx:((lane==1)?qy:qz);
}

// ---------------- feature norms ----------------
template<int CIN>
__global__ void k_norm(const float* __restrict__ x, int xstride, float* __restrict__ nrm){
  int p = blockIdx.x*64 + threadIdx.x;
  if (p >= BB*NPp) return;
  const float* xr = x + (size_t)p*xstride;
  float a = 0.0f;
  for (int m = 0; m < CIN; ++m) a = __fadd_rn(a, __fmul_rn(xr[m], xr[m]));
  nrm[p] = a;
}

// ---------------- kNN (20 smallest, stable ties) ----------------
template<int CIN>
__global__ __launch_bounds__(64) void k_knn(const float* __restrict__ x, int xstride,
    const float* __restrict__ nrm, int* __restrict__ idxo){
  __shared__ float xi[CIN];
  __shared__ float d[NPp];
  int bi = blockIdx.x, lane = threadIdx.x;
  int rb = (bi >> 8) << 8;
  const float* xr = x + (size_t)bi*xstride;
  for (int m = lane; m < CIN; m += 64) xi[m] = xr[m];
  __syncthreads();
  float ni = nrm[bi];
#pragma unroll
  for (int qq = 0; qq < 4; ++qq){
    int j = qq*64 + lane;
    const float* xj = x + (size_t)(rb + j)*xstride;
    float dot = 0.0f;
    for (int m = 0; m < CIN; ++m) dot = fmaf(xj[m], xi[m], dot);
    d[j] = __fsub_rn(__fadd_rn(ni, nrm[rb + j]), __fmul_rn(2.0f, dot));
  }
  __syncthreads();
  for (int r = 0; r < KC; ++r){
    float bv = 3.4e38f; int bj = NPp;
#pragma unroll
    for (int qq = 0; qq < 4; ++qq){
      int j = qq*64 + lane;
      float v = d[j];
      if (v < bv){ bv = v; bj = j; }
    }
#pragma unroll
    for (int off = 32; off >= 1; off >>= 1){
      float ov = __shfl_xor(bv, off, 64);
      int   oj = __shfl_xor(bj, off, 64);
      if (ov < bv || (ov == bv && oj < bj)){ bv = ov; bj = oj; }
    }
    if (lane == 0){ idxo[(size_t)bi*KC + r] = bj; d[bj] = 3.0e38f; }
    __syncthreads();
  }
}

// ---------------- T-Net 2-layer edge conv + k-maxpool ----------------
__global__ __launch_bounds__(64) void k_tedge(const float* __restrict__ x, const int* __restrict__ idx,
    const float* __restrict__ W0, const float* __restrict__ W1, float* __restrict__ out){
  __shared__ float xi[131];
  __shared__ float ed[20*132];
  __shared__ __align__(16) float h0s[20*68];
  int bi = blockIdx.x, lane = threadIdx.x;
  int rb = (bi >> 8) << 8;
  const float* xr = x + (size_t)bi*132;
  for (int m = lane; m < 131; m += 64) xi[m] = xr[m];
  __syncthreads();
  for (int k = 0; k < KC; ++k){
    int j = idx[(size_t)bi*KC + k];
    const float* xj = x + (size_t)(rb + j)*132;
    for (int m = lane; m < 131; m += 64) ed[k*132 + m] = xj[m] - xi[m];
  }
  __syncthreads();
  // phase A: 64 mid channels, c = lane; split W·[xi, xj-xi] into k-invariant + diff parts
  const float* w0r = W0 + (size_t)lane*262;
  float basev = 0.0f;
  for (int m = 0; m < 131; ++m) basev = fmaf(w0r[m], xi[m], basev);
  float acc[KC];
#pragma unroll
  for (int k = 0; k < KC; ++k) acc[k] = basev;
  for (int m = 0; m < 131; ++m){
    float w = w0r[131 + m];
#pragma unroll
    for (int k = 0; k < KC; ++k) acc[k] = fmaf(w, ed[k*132 + m], acc[k]);
  }
#pragma unroll
  for (int k = 0; k < KC; ++k) h0s[k*68 + lane] = fmaxf(acc[k], 0.0f);
  __syncthreads();
  // phase B: 128 out channels
  float a2[2][KC];
#pragma unroll
  for (int cc = 0; cc < 2; ++cc)
#pragma unroll
    for (int k = 0; k < KC; ++k) a2[cc][k] = 0.0f;
#pragma unroll
  for (int qq = 0; qq < 16; ++qq){
    float4 wA = *(const float4*)(W1 + (size_t)lane*64 + 4*qq);
    float4 wB = *(const float4*)(W1 + (size_t)(lane+64)*64 + 4*qq);
#pragma unroll
    for (int k = 0; k < KC; ++k){
      float4 h = *(const float4*)(h0s + k*68 + 4*qq);
      a2[0][k] = fma4(wA, h, a2[0][k]);
      a2[1][k] = fma4(wB, h, a2[1][k]);
    }
  }
#pragma unroll
  for (int cc = 0; cc < 2; ++cc){
    float mx = 0.0f;
#pragma unroll
    for (int k = 0; k < KC; ++k) mx = fmaxf(mx, a2[cc][k]);
    out[(size_t)bi*128 + cc*64 + lane] = mx;
  }
}

// ---------------- T-Net 128->1024 + pool over points ----------------
__global__ __launch_bounds__(128) void k_tpool(const float* __restrict__ h, const float* __restrict__ W,
    float* __restrict__ g1024){
  int b = blockIdx.x, t = threadIdx.x;
  int c = blockIdx.y*128 + t;
  float4 w[32];
#pragma unroll
  for (int qq = 0; qq < 32; ++qq) w[qq] = *(const float4*)(W + (size_t)c*128 + 4*qq);
  const float* hb = h + (size_t)b*NPp*128;
  float mx = 0.0f;
  for (int i = 0; i < NPp; ++i){
    const float4* hr = (const float4*)(hb + (size_t)i*128);
    float a = 0.0f;
#pragma unroll
    for (int qq = 0; qq < 32; ++qq) a = fma4(w[qq], hr[qq], a);
    mx = fmaxf(mx, a);
  }
  g1024[(size_t)b*1024 + c] = mx;
}

// ---------------- T-Net MLP + 3x3 transform applied to new_xyz ----------------
__global__ __launch_bounds__(256) void k_trest(const float* __restrict__ g1024,
    const float* __restrict__ Wg0, const float* __restrict__ Wg1,
    const float* __restrict__ Wl, const float* __restrict__ bl,
    const float* __restrict__ new_xyz, float* __restrict__ x131){
  __shared__ __align__(16) float g1[1024];
  __shared__ __align__(16) float g5[512];
  __shared__ __align__(16) float g2[256];
  __shared__ float tm[12];
  int b = blockIdx.x, t = threadIdx.x;
  for (int m = t; m < 1024; m += 256) g1[m] = g1024[(size_t)b*1024 + m];
  __syncthreads();
#pragma unroll
  for (int cc = 0; cc < 2; ++cc){
    int c = t + cc*256;
    const float4* wr = (const float4*)(Wg0 + (size_t)c*1024);
    const float4* gv = (const float4*)g1;
    float a = 0.0f;
    for (int qq = 0; qq < 256; ++qq) a = fma4(wr[qq], gv[qq], a);
    g5[c] = fmaxf(a, 0.0f);
  }
  __syncthreads();
  {
    const float4* wr = (const float4*)(Wg1 + (size_t)t*512);
    const float4* gv = (const float4*)g5;
    float a = 0.0f;
    for (int qq = 0; qq < 128; ++qq) a = fma4(wr[qq], gv[qq], a);
    g2[t] = fmaxf(a, 0.0f);
  }
  __syncthreads();
  if (t < 9){
    const float4* wr = (const float4*)(Wl + (size_t)t*256);
    const float4* gv = (const float4*)g2;
    float a = 0.0f;
#pragma unroll
    for (int qq = 0; qq < 64; ++qq) a = fma4(wr[qq], gv[qq], a);
    a += bl[t];
    if (t == 0 || t == 4 || t == 8) a += 1.0f;
    tm[t] = a;
  }
  __syncthreads();
  {
    const float* nx = new_xyz + ((size_t)b*NPp + t)*3;
    float X = nx[0], Y = nx[1], Z = nx[2];
#pragma unroll
    for (int i = 0; i < 3; ++i){
      float v = __fadd_rn(__fadd_rn(__fmul_rn(tm[i*3+0], X), __fmul_rn(tm[i*3+1], Y)), __fmul_rn(tm[i*3+2], Z));
      x131[((size_t)b*NPp + t)*132 + 128 + i] = v;
    }
  }
}

// ---------------- DGCNN single-layer edge conv + k-maxpool ----------------
template<int CIN, int COUT, int T, int CPT>
__global__ __launch_bounds__(T) void k_edge(const float* __restrict__ x, int xstride,
    const int* __restrict__ idx, const float* __restrict__ W, float* __restrict__ out){
  constexpr int EP = (CIN + 4) & ~3;
  __shared__ float xi[CIN];
  __shared__ float ed[KC*EP];
  int bi = blockIdx.x, t = threadIdx.x;
  int rb = (bi >> 8) << 8;
  const float* xr = x + (size_t)bi*xstride;
  for (int m = t; m < CIN; m += T) xi[m] = xr[m];
  __syncthreads();
  for (int k = 0; k < KC; ++k){
    int j = idx[(size_t)bi*KC + k];
    const float* xj = x + (size_t)(rb + j)*xstride;
    for (int m = t; m < CIN; m += T) ed[k*EP + m] = xj[m] - xi[m];
  }
  __syncthreads();
  const float* wr[CPT];
#pragma unroll
  for (int cc = 0; cc < CPT; ++cc) wr[cc] = W + (size_t)(t + cc*T)*(2*CIN);
  float basev[CPT];
#pragma unroll
  for (int cc = 0; cc < CPT; ++cc) basev[cc] = 0.0f;
  for (int m = 0; m < CIN; ++m){
    float xv = xi[m];
#pragma unroll
    for (int cc = 0; cc < CPT; ++cc) basev[cc] = fmaf(wr[cc][m], xv, basev[cc]);
  }
  float acc[CPT][KC];
#pragma unroll
  for (int cc = 0; cc < CPT; ++cc)
#pragma unroll
    for (int k = 0; k < KC; ++k) acc[cc][k] = basev[cc];
  for (int m = 0; m < CIN; ++m){
    float w[CPT];
#pragma unroll
    for (int cc = 0; cc < CPT; ++cc) w[cc] = wr[cc][CIN + m];
#pragma unroll
    for (int k = 0; k < KC; ++k){
      float ev = ed[k*EP + m];
#pragma unroll
      for (int cc = 0; cc < CPT; ++cc) acc[cc][k] = fmaf(w[cc], ev, acc[cc][k]);
    }
  }
#pragma unroll
  for (int cc = 0; cc < CPT; ++cc){
    float mx = 0.0f;
#pragma unroll
    for (int k = 0; k < KC; ++k) mx = fmaxf(mx, acc[cc][k]);
    out[(size_t)bi*COUT + t + cc*T] = mx;
  }
}

// ---------------- zero scratch ----------------
__global__ void k_zero(float* p, int n){
  int i = blockIdx.x*256 + threadIdx.x;
  if (i < n) p[i] = 0.0f;
}

// ---------------- 896->128 conv + global max pool (atomic) ----------------
__global__ __launch_bounds__(128) void k_dgl(const float* __restrict__ f1, const float* __restrict__ f2,
    const float* __restrict__ f3, const float* __restrict__ W, float* __restrict__ g128){
  int b = blockIdx.x, t = threadIdx.x;
  int i0 = blockIdx.y * 16;
  const float* wr = W + (size_t)t*896;
  float acc[16];
#pragma unroll
  for (int ii = 0; ii < 16; ++ii) acc[ii] = 0.0f;
  for (int q = 0; q < 32; ++q){
    float4 w = *(const float4*)(wr + 4*q);
#pragma unroll
    for (int ii = 0; ii < 16; ++ii){
      float4 v = *(const float4*)(f1 + ((size_t)b*NPp + i0 + ii)*128 + 4*q);
      acc[ii] = fma4(w, v, acc[ii]);
    }
  }
  for (int q = 0; q < 64; ++q){
    float4 w = *(const float4*)(wr + 128 + 4*q);
#pragma unroll
    for (int ii = 0; ii < 16; ++ii){
      float4 v = *(const float4*)(f2 + ((size_t)b*NPp + i0 + ii)*256 + 4*q);
      acc[ii] = fma4(w, v, acc[ii]);
    }
  }
  for (int q = 0; q < 128; ++q){
    float4 w = *(const float4*)(wr + 384 + 4*q);
#pragma unroll
    for (int ii = 0; ii < 16; ++ii){
      float4 v = *(const float4*)(f3 + ((size_t)b*NPp + i0 + ii)*512 + 4*q);
      acc[ii] = fma4(w, v, acc[ii]);
    }
  }
#pragma unroll
  for (int ii = 0; ii < 16; ++ii){
    float v = fmaxf(acc[ii], 0.0f);
    atomicMax((int*)(g128 + (size_t)b*128 + t), __float_as_int(v));
  }
}

// ---------------- classifier head ----------------
__global__ __launch_bounds__(256) void k_final(const float* __restrict__ g128,
    const float* __restrict__ W0, const float* __restrict__ W1,
    const float* __restrict__ Wc, const float* __restrict__ bc, float* __restrict__ out){
  __shared__ __align__(16) float g0[128];
  __shared__ __align__(16) float g5[512];
  __shared__ __align__(16) float g2[256];
  int b = blockIdx.x, t = threadIdx.x;
  if (t < 128) g0[t] = g128[(size_t)b*128 + t];
  __syncthreads();
#pragma unroll
  for (int cc = 0; cc < 2; ++cc){
    int c = t + cc*256;
    const float4* wr = (const float4*)(W0 + (size_t)c*128);
    const float4* gv = (const float4*)g0;
    float a = 0.0f;
#pragma unroll
    for (int qq = 0; qq < 32; ++qq) a = fma4(wr[qq], gv[qq], a);
    g5[c] = fmaxf(a, 0.0f);
  }
  __syncthreads();
  {
    const float4* wr = (const float4*)(W1 + (size_t)t*512);
    const float4* gv = (const float4*)g5;
    float a = 0.0f;
    for (int qq = 0; qq < 128; ++qq) a = fma4(wr[qq], gv[qq], a);
    g2[t] = fmaxf(a, 0.0f);
  }
  __syncthreads();
  if (t < 40){
    const float4* wr = (const float4*)(Wc + (size_t)t*256);
    const float4* gv = (const float4*)g2;
    float a = 0.0f;
#pragma unroll
    for (int qq = 0; qq < 64; ++qq) a = fma4(wr[qq], gv[qq], a);
    out[(size_t)b*40 + t] = a + bc[t];
  }
}

extern "C" void kernel_launch(void* const* d_in, const int* in_sizes, int n_in,
                              void* d_out, int out_size, void* d_ws, size_t ws_size,
                              hipStream_t stream){
  (void)in_sizes; (void)n_in; (void)out_size; (void)ws_size;
  const float* points     = (const float*)d_in[0];
  const float* sa_w0      = (const float*)d_in[1];
  const float* sa_w1      = (const float*)d_in[2];
  const float* sa_w2      = (const float*)d_in[3];
  const float* t_ec_w0    = (const float*)d_in[4];
  const float* t_ec_w1    = (const float*)d_in[5];
  const float* t_local_w  = (const float*)d_in[6];
  const float* t_g_w0     = (const float*)d_in[7];
  const float* t_g_w1     = (const float*)d_in[8];
  const float* t_lin_w    = (const float*)d_in[9];
  const float* t_lin_b    = (const float*)d_in[10];
  const float* dg_ec_w0   = (const float*)d_in[11];
  const float* dg_ec_w1   = (const float*)d_in[12];
  const float* dg_ec_w2   = (const float*)d_in[13];
  const float* dg_local_w = (const float*)d_in[14];
  const float* dg_g_w0    = (const float*)d_in[15];
  const float* dg_g_w1    = (const float*)d_in[16];
  const float* cls_w      = (const float*)d_in[17];
  const float* cls_b      = (const float*)d_in[18];
  float* out = (float*)d_out;

  float* ws     = (float*)d_ws;
  float* xyz    = ws;                    // B*N*3          = 393216
  float* xnrm   = xyz    + 393216;       // B*N            = 131072
  float* nxyz   = xnrm   + 131072;       // B*256*3        = 24576
  float* feat   = nxyz   + 24576;        // B*256*128      = 1048576
  float* x131   = feat   + 1048576;      // B*256*132      = 1081344
  float* nrm    = x131   + 1081344;      // B*256          = 8192
  int*   idx    = (int*)(nrm + 8192);    // B*256*20       = 163840
  float* ht     = (float*)(idx + 163840);// B*256*128      = 1048576  (reused as f1)
  float* g1024v = ht     + 1048576;      // B*1024         = 32768
  float* f2     = g1024v + 32768;        // B*256*256      = 2097152
  float* f3     = f2     + 2097152;      // B*256*512      = 4194304
  float* g128v  = f3     + 4194304;      // B*128          = 4096
  float* f1 = ht;

  k_prep<<<512, 256, 0, stream>>>(points, xyz, xnrm);
  k_fps<<<BB, 256, 0, stream>>>(xyz, nxyz);
  k_sa<<<BB*NPp, 64, 0, stream>>>(xyz, xnrm, nxyz, sa_w0, sa_w1, sa_w2, feat, x131);

  // T-Net branch (uses x = [feat, new_xyz])
  k_norm<131><<<128, 64, 0, stream>>>(x131, 132, nrm);
  k_knn<131><<<BB*NPp, 64, 0, stream>>>(x131, 132, nrm, idx);
  k_tedge<<<BB*NPp, 64, 0, stream>>>(x131, idx, t_ec_w0, t_ec_w1, ht);
  k_tpool<<<dim3(BB, 8), 128, 0, stream>>>(ht, t_local_w, g1024v);
  k_trest<<<BB, 256, 0, stream>>>(g1024v, t_g_w0, t_g_w1, t_lin_w, t_lin_b, nxyz, x131);

  // DGCNN layer 1 (x = [feat, xyz_t], 131 dims)
  k_norm<131><<<128, 64, 0, stream>>>(x131, 132, nrm);
  k_knn<131><<<BB*NPp, 64, 0, stream>>>(x131, 132, nrm, idx);
  k_edge<131,128,64,2><<<BB*NPp, 64, 0, stream>>>(x131, 132, idx, dg_ec_w0, f1);
  // layer 2
  k_norm<128><<<128, 64, 0, stream>>>(f1, 128, nrm);
  k_knn<128><<<BB*NPp, 64, 0, stream>>>(f1, 128, nrm, idx);
  k_edge<128,256,64,4><<<BB*NPp, 64, 0, stream>>>(f1, 128, idx, dg_ec_w1, f2);
  // layer 3
  k_norm<256><<<128, 64, 0, stream>>>(f2, 256, nrm);
  k_knn<256><<<BB*NPp, 64, 0, stream>>>(f2, 256, nrm, idx);
  k_edge<256,512,128,4><<<BB*NPp, 128, 0, stream>>>(f2, 256, idx, dg_ec_w2, f3);

  // local conv + global pool + head
  k_zero<<<16, 256, 0, stream>>>(g128v, 4096);
  k_dgl<<<dim3(BB, 16), 128, 0, stream>>>(f1, f2, f3, dg_local_w, g128v);
  k_final<<<BB, 256, 0, stream>>>(g128v, dg_g_w0, dg_g_w1, cls_w, cls_b, out);
}

// Round 2
// 2837.426 us; speedup vs baseline: 2.1602x; 2.1602x over previous
//
#include <hip/hip_runtime.h>
#include <math.h>

#define BB 32
#define NN 4096
#define NPp 256
#define NSs 64
#define KC 20

__device__ __forceinline__ float fma4(const float4 w, const float4 v, float a){
  a = fmaf(w.x, v.x, a); a = fmaf(w.y, v.y, a);
  a = fmaf(w.z, v.z, a); a = fmaf(w.w, v.w, a); return a;
}
__device__ __forceinline__ float4 fma4s(const float4 w, float s, float4 a){
  a.x = fmaf(w.x, s, a.x); a.y = fmaf(w.y, s, a.y);
  a.z = fmaf(w.z, s, a.z); a.w = fmaf(w.w, s, a.w); return a;
}
__device__ __forceinline__ float4 max4(float4 a, float4 b){
  a.x = fmaxf(a.x, b.x); a.y = fmaxf(a.y, b.y);
  a.z = fmaxf(a.z, b.z); a.w = fmaxf(a.w, b.w); return a;
}

// ---------------- weight transpose: WT[c*R + r] = W[r*C + c] ----------------
__global__ void k_wt(const float* __restrict__ W, float* __restrict__ WT, int R, int C){
  int i = blockIdx.x*256 + threadIdx.x;
  if (i >= R*C) return;
  int r = i % R, c = i / R;
  WT[(size_t)c*R + r] = W[(size_t)r*C + c];
}

// ---------------- transpose + point norms ----------------
__global__ void k_prep(const float* __restrict__ pts, float* __restrict__ xyz, float* __restrict__ xnrm){
  int i = blockIdx.x*256 + threadIdx.x;
  if (i >= BB*NN) return;
  int b = i >> 12, n = i & (NN-1);
  float X = pts[(b*3+0)*NN + n];
  float Y = pts[(b*3+1)*NN + n];
  float Z = pts[(b*3+2)*NN + n];
  xyz[i*3+0]=X; xyz[i*3+1]=Y; xyz[i*3+2]=Z;
  xnrm[i] = __fadd_rn(__fadd_rn(__fmul_rn(X,X), __fmul_rn(Y,Y)), __fmul_rn(Z,Z));
}

// ---------------- farthest point sampling ----------------
__global__ __launch_bounds__(256) void k_fps(const float* __restrict__ xyz, float* __restrict__ new_xyz){
  __shared__ float xs[NN], ys[NN], zs[NN];
  __shared__ float rv[4];
  __shared__ int   ri[4];
  __shared__ int   slast;
  int b = blockIdx.x, t = threadIdx.x;
  for (int j = t; j < NN; j += 256){
    const float* p = xyz + ((size_t)b*NN + j)*3;
    xs[j] = p[0]; ys[j] = p[1]; zs[j] = p[2];
  }
  float dist[16];
#pragma unroll
  for (int q = 0; q < 16; ++q) dist[q] = __builtin_inff();
  int last = 0;
  __syncthreads();
  for (int it = 0; it < NPp; ++it){
    if (t == 0){
      float* o = new_xyz + ((size_t)b*NPp + it)*3;
      o[0] = xs[last]; o[1] = ys[last]; o[2] = zs[last];
    }
    float px = xs[last], py = ys[last], pz = zs[last];
    float bv = -1.0f; int bj = 0;
#pragma unroll
    for (int q = 0; q < 16; ++q){
      int j = q*256 + t;
      float dx = __fsub_rn(xs[j], px);
      float dy = __fsub_rn(ys[j], py);
      float dz = __fsub_rn(zs[j], pz);
      float dd = __fadd_rn(__fadd_rn(__fmul_rn(dx,dx), __fmul_rn(dy,dy)), __fmul_rn(dz,dz));
      float dm = fminf(dist[q], dd);
      dist[q] = dm;
      if (dm > bv){ bv = dm; bj = j; }
    }
#pragma unroll
    for (int off = 32; off >= 1; off >>= 1){
      float ov = __shfl_xor(bv, off, 64);
      int   oj = __shfl_xor(bj, off, 64);
      if (ov > bv || (ov == bv && oj < bj)){ bv = ov; bj = oj; }
    }
    int w = t >> 6;
    if ((t & 63) == 0){ rv[w] = bv; ri[w] = bj; }
    __syncthreads();
    if (t == 0){
      float fv = rv[0]; int fj = ri[0];
      for (int ww = 1; ww < 4; ++ww)
        if (rv[ww] > fv || (rv[ww] == fv && ri[ww] < fj)){ fv = rv[ww]; fj = ri[ww]; }
      slast = fj;
    }
    __syncthreads();
    last = slast;
  }
}

// ---------------- ball query + SA convs + maxpool ----------------
__global__ __launch_bounds__(64) void k_sa(const float* __restrict__ xyz, const float* __restrict__ xnrm,
    const float* __restrict__ new_xyz, const float* __restrict__ w0, const float* __restrict__ w1,
    const float* __restrict__ w2, float* __restrict__ feat, float* __restrict__ x131){
  __shared__ __align__(16) float h1s[64*68];
  __shared__ int gix[64];
  int bi = blockIdx.x, lane = threadIdx.x;
  int b = bi >> 8;
  const float* q = new_xyz + (size_t)bi*3;
  float qx=q[0], qy=q[1], qz=q[2];
  float nq = __fadd_rn(__fadd_rn(__fmul_rn(qx,qx), __fmul_rn(qy,qy)), __fmul_rn(qz,qz));
  int cnt = 0;
  for (int base = 0; base < NN && cnt < NSs; base += 64){
    int j = base + lane;
    const float* p = xyz + ((size_t)b*NN + j)*3;
    float dot = __fadd_rn(__fadd_rn(__fmul_rn(qx,p[0]), __fmul_rn(qy,p[1])), __fmul_rn(qz,p[2]));
    float d2 = __fsub_rn(__fadd_rn(nq, xnrm[b*NN + j]), __fmul_rn(2.0f, dot));
    bool inb = d2 < 0.04f;
    unsigned long long m = __ballot(inb);
    int pos = cnt + (int)__popcll(m & ((1ull << lane) - 1ull));
    if (inb && pos < NSs) gix[pos] = j;
    cnt += (int)__popcll(m);
  }
  __syncthreads();
  int g0 = gix[0];
  if (lane >= cnt) gix[lane] = g0;
  __syncthreads();
  // phase 1: thread = sample; weights read uniform from global (s_load path)
  {
    int gj = gix[lane];
    const float* p = xyz + ((size_t)b*NN + gj)*3;
    float px = p[0]-qx, py = p[1]-qy, pz = p[2]-qz;
    float h0[64];
#pragma unroll
    for (int c = 0; c < 64; ++c){
      float a = fmaf(w0[c*3+2], pz, fmaf(w0[c*3+1], py, w0[c*3]*px));
      h0[c] = fmaxf(a, 0.0f);
    }
    for (int c = 0; c < 64; ++c){
      const float4* wr = (const float4*)(w1 + c*64);
      float a = 0.0f;
#pragma unroll
      for (int qq = 0; qq < 16; ++qq){
        float4 w = wr[qq];
        a = fmaf(w.x, h0[4*qq+0], a);
        a = fmaf(w.y, h0[4*qq+1], a);
        a = fmaf(w.z, h0[4*qq+2], a);
        a = fmaf(w.w, h0[4*qq+3], a);
      }
      h1s[lane*68 + c] = fmaxf(a, 0.0f);
    }
  }
  __syncthreads();
  // phase 2: thread = output channel (c, c+64), W2 rows cached in regs; s unrolled x2
  float4 wa[16], wb[16];
#pragma unroll
  for (int qq = 0; qq < 16; ++qq){
    wa[qq] = *(const float4*)(w2 + (size_t)lane*64 + 4*qq);
    wb[qq] = *(const float4*)(w2 + (size_t)(lane+64)*64 + 4*qq);
  }
  float m0 = 0.0f, m1 = 0.0f;
  for (int s = 0; s < 64; s += 2){
    const float4* hr0 = (const float4*)(h1s + s*68);
    const float4* hr1 = (const float4*)(h1s + (s+1)*68);
    float a0 = 0.0f, a1 = 0.0f, a2 = 0.0f, a3 = 0.0f;
#pragma unroll
    for (int qq = 0; qq < 16; ++qq){
      float4 h0v = hr0[qq], h1v = hr1[qq];
      a0 = fma4(wa[qq], h0v, a0);
      a1 = fma4(wb[qq], h0v, a1);
      a2 = fma4(wa[qq], h1v, a2);
      a3 = fma4(wb[qq], h1v, a3);
    }
    m0 = fmaxf(fmaxf(m0, a0), a2); m1 = fmaxf(fmaxf(m1, a1), a3);
  }
  feat[(size_t)bi*128 + lane]      = m0;
  feat[(size_t)bi*128 + 64 + lane] = m1;
  x131[(size_t)bi*132 + lane]      = m0;
  x131[(size_t)bi*132 + 64 + lane] = m1;
  if (lane < 3) x131[(size_t)bi*132 + 128 + lane] = (lane==0)?qx:((lane==1)?qy:qz);
}

// ---------------- per-batch feature transpose: xT[b][m][256] ----------------
template<int CIN>
__global__ void k_xt(const float* __restrict__ x, int xstride, float* __restrict__ xT){
  int o = blockIdx.x*256 + threadIdx.x;
  if (o >= BB*CIN*256) return;
  int col = o & 255; int t1 = o >> 8; int m = t1 % CIN; int b = t1 / CIN;
  xT[o] = x[((size_t)(b*256+col))*xstride + m];
}

// ---------------- feature norms (from xT, coalesced) ----------------
template<int CIN>
__global__ void k_norm2(const float* __restrict__ xT, float* __restrict__ nrm){
  int p = blockIdx.x*64 + threadIdx.x;
  if (p >= BB*NPp) return;
  int b = p >> 8, col = p & 255;
  const float* base = xT + (size_t)b*CIN*256 + col;
  float a = 0.0f;
  for (int m = 0; m < CIN; ++m){
    float v = base[m*256];
    a = __fadd_rn(a, __fmul_rn(v, v));
  }
  nrm[p] = a;
}

// ---------------- kNN from xT (coalesced b128 loads) ----------------
template<int CIN>
__global__ __launch_bounds__(64) void k_knn2(const float* __restrict__ xT,
    const float* __restrict__ nrm, int* __restrict__ idxo){
  __shared__ float xi[CIN];
  __shared__ float d[NPp];
  int bi = blockIdx.x, lane = threadIdx.x;
  int b = bi >> 8, coli = bi & 255;
  int rb = b << 8;
  const float* xb = xT + (size_t)b*CIN*256;
  for (int m = lane; m < CIN; m += 64) xi[m] = xb[m*256 + coli];
  __syncthreads();
  float ni = nrm[bi];
  float d0 = 0.0f, d1 = 0.0f, d2a = 0.0f, d3 = 0.0f;
  for (int m = 0; m < CIN; ++m){
    float xm = xi[m];
    float4 v = *(const float4*)(xb + (size_t)m*256 + 4*lane);
    d0 = fmaf(v.x, xm, d0); d1 = fmaf(v.y, xm, d1);
    d2a = fmaf(v.z, xm, d2a); d3 = fmaf(v.w, xm, d3);
  }
#pragma unroll
  for (int q = 0; q < 4; ++q){
    int j = 4*lane + q;
    float dot = (q==0)?d0:((q==1)?d1:((q==2)?d2a:d3));
    d[j] = __fsub_rn(__fadd_rn(ni, nrm[rb + j]), __fmul_rn(2.0f, dot));
  }
  __syncthreads();
  for (int r = 0; r < KC; ++r){
    float bv = 3.4e38f; int bj = NPp;
#pragma unroll
    for (int q = 0; q < 4; ++q){
      int j = 4*lane + q;
      float v = d[j];
      if (v < bv){ bv = v; bj = j; }
    }
#pragma unroll
    for (int off = 32; off >= 1; off >>= 1){
      float ov = __shfl_xor(bv, off, 64);
      int   oj = __shfl_xor(bj, off, 64);
      if (ov < bv || (ov == bv && oj < bj)){ bv = ov; bj = oj; }
    }
    if (lane == 0){ idxo[(size_t)bi*KC + r] = bj; d[bj] = 3.0e38f; }
    __syncthreads();
  }
}

// ---------------- DGCNN edge conv + k-maxpool (transposed weights) ----------------
// wt layout: [2*CIN][COUT]; rows 0..CIN-1 = base (xi) part, CIN..2CIN-1 = diff part.
template<int CIN, int COUT, int T, int KG>
__global__ __launch_bounds__(T) void k_edge2(const float* __restrict__ x, int xstride,
    const int* __restrict__ idx, const float* __restrict__ wt, float* __restrict__ out){
  constexpr int CT   = T / KG;           // channel-threads
  constexpr int CPT4 = COUT / (CT*4);    // float4 channel chunks per thread
  constexpr int KH   = KC / KG;          // k's per thread
  constexpr int EP   = (CIN + 4) & ~3;   // padded row stride (16B-aligned)
  constexpr int MT4  = CIN / 4;
  __shared__ float xi[EP];
  __shared__ float ed[KC*EP];
  __shared__ __align__(16) float smax[KG*COUT];
  int bi = blockIdx.x, t = threadIdx.x;
  int cg = t % CT, kg = t / CT;
  int rb = (bi >> 8) << 8;
  const float* xr = x + (size_t)bi*xstride;
  for (int m = t; m < CIN; m += T) xi[m] = xr[m];
  __syncthreads();
  for (int k = 0; k < KC; ++k){
    int j = idx[(size_t)bi*KC + k];
    const float* xj = x + (size_t)(rb + j)*xstride;
    for (int m = t; m < CIN; m += T) ed[k*EP + m] = xj[m] - xi[m];
  }
  __syncthreads();
  // base part (k-invariant)
  float4 basev[CPT4];
#pragma unroll
  for (int cc = 0; cc < CPT4; ++cc) basev[cc] = make_float4(0.f,0.f,0.f,0.f);
  for (int m = 0; m < CIN; ++m){
    float xm = xi[m];
#pragma unroll
    for (int cc = 0; cc < CPT4; ++cc){
      float4 w = *(const float4*)(wt + (size_t)m*COUT + 4*cg + cc*(4*CT));
      basev[cc] = fma4s(w, xm, basev[cc]);
    }
  }
  float4 acc[CPT4][KH];
#pragma unroll
  for (int cc = 0; cc < CPT4; ++cc)
#pragma unroll
    for (int kk = 0; kk < KH; ++kk) acc[cc][kk] = basev[cc];
  const float* wtd = wt + (size_t)CIN*COUT;
  int k0 = kg*KH;
  for (int m4 = 0; m4 < MT4; ++m4){
    float4 e[KH];
#pragma unroll
    for (int kk = 0; kk < KH; ++kk) e[kk] = *(const float4*)(ed + (k0+kk)*EP + 4*m4);
#pragma unroll
    for (int mm = 0; mm < 4; ++mm){
      int m = 4*m4 + mm;
#pragma unroll
      for (int cc = 0; cc < CPT4; ++cc){
        float4 w = *(const float4*)(wtd + (size_t)m*COUT + 4*cg + cc*(4*CT));
#pragma unroll
        for (int kk = 0; kk < KH; ++kk){
          float ev = (mm==0)?e[kk].x:((mm==1)?e[kk].y:((mm==2)?e[kk].z:e[kk].w));
          acc[cc][kk] = fma4s(w, ev, acc[cc][kk]);
        }
      }
    }
  }
  // tail (CIN % 4)
  for (int m = MT4*4; m < CIN; ++m){
    float4 w[CPT4];
#pragma unroll
    for (int cc = 0; cc < CPT4; ++cc) w[cc] = *(const float4*)(wtd + (size_t)m*COUT + 4*cg + cc*(4*CT));
#pragma unroll
    for (int kk = 0; kk < KH; ++kk){
      float ev = ed[(k0+kk)*EP + m];
#pragma unroll
      for (int cc = 0; cc < CPT4; ++cc) acc[cc][kk] = fma4s(w[cc], ev, acc[cc][kk]);
    }
  }
  // relu+max over this thread's k's
#pragma unroll
  for (int cc = 0; cc < CPT4; ++cc){
    float4 p = make_float4(0.f,0.f,0.f,0.f);
#pragma unroll
    for (int kk = 0; kk < KH; ++kk) p = max4(p, acc[cc][kk]);
    *(float4*)(smax + kg*COUT + 4*cg + cc*(4*CT)) = p;
  }
  __syncthreads();
  if (kg == 0){
#pragma unroll
    for (int cc = 0; cc < CPT4; ++cc){
      int off = 4*cg + cc*(4*CT);
      float4 r = *(const float4*)(smax + off);
#pragma unroll
      for (int g = 1; g < KG; ++g) r = max4(r, *(const float4*)(smax + g*COUT + off));
      *(float4*)(out + (size_t)bi*COUT + off) = r;
    }
  }
}

// ---------------- T-Net 2-layer edge conv + k-maxpool (transposed weights) ----------------
// wt0: [262][64], wt1: [64][128]
__global__ __launch_bounds__(128) void k_tedge2(const float* __restrict__ x, const int* __restrict__ idx,
    const float* __restrict__ wt0, const float* __restrict__ wt1, float* __restrict__ out){
  __shared__ float xi[132];
  __shared__ float ed[20*132];
  __shared__ __align__(16) float h0s[20*68];
  __shared__ __align__(16) float smax[4*128];
  int bi = blockIdx.x, t = threadIdx.x;
  int cg = t & 31, kg = t >> 5, k0 = kg*5;
  int rb = (bi >> 8) << 8;
  const float* xr = x + (size_t)bi*132;
  for (int m = t; m < 131; m += 128) xi[m] = xr[m];
  __syncthreads();
  for (int k = 0; k < KC; ++k){
    int j = idx[(size_t)bi*KC + k];
    const float* xj = x + (size_t)(rb + j)*132;
    for (int m = t; m < 131; m += 128) ed[k*132 + m] = xj[m] - xi[m];
  }
  __syncthreads();
  // phase A: 64 mid channels, this thread owns c = {cg, cg+32}, k's = k0..k0+4
  float base0 = 0.0f, base1 = 0.0f;
  for (int m = 0; m < 131; ++m){
    float xm = xi[m];
    base0 = fmaf(wt0[m*64 + cg],      xm, base0);
    base1 = fmaf(wt0[m*64 + cg + 32], xm, base1);
  }
  float a0[5], a1[5];
#pragma unroll
  for (int kk = 0; kk < 5; ++kk){ a0[kk] = base0; a1[kk] = base1; }
  const float* wt0d = wt0 + 131*64;
  for (int m4 = 0; m4 < 32; ++m4){
    float4 e[5];
#pragma unroll
    for (int kk = 0; kk < 5; ++kk) e[kk] = *(const float4*)(ed + (k0+kk)*132 + 4*m4);
#pragma unroll
    for (int mm = 0; mm < 4; ++mm){
      int m = 4*m4 + mm;
      float w0v = wt0d[m*64 + cg];
      float w1v = wt0d[m*64 + cg + 32];
#pragma unroll
      for (int kk = 0; kk < 5; ++kk){
        float ev = (mm==0)?e[kk].x:((mm==1)?e[kk].y:((mm==2)?e[kk].z:e[kk].w));
        a0[kk] = fmaf(w0v, ev, a0[kk]);
        a1[kk] = fmaf(w1v, ev, a1[kk]);
      }
    }
  }
  for (int m = 128; m < 131; ++m){
    float w0v = wt0d[m*64 + cg];
    float w1v = wt0d[m*64 + cg + 32];
#pragma unroll
    for (int kk = 0; kk < 5; ++kk){
      float ev = ed[(k0+kk)*132 + m];
      a0[kk] = fmaf(w0v, ev, a0[kk]);
      a1[kk] = fmaf(w1v, ev, a1[kk]);
    }
  }
#pragma unroll
  for (int kk = 0; kk < 5; ++kk){
    h0s[(k0+kk)*68 + cg]      = fmaxf(a0[kk], 0.0f);
    h0s[(k0+kk)*68 + cg + 32] = fmaxf(a1[kk], 0.0f);
  }
  __syncthreads();
  // phase B: 128 out channels, c4 = 4*cg, same k's
  float4 b2[5];
#pragma unroll
  for (int kk = 0; kk < 5; ++kk) b2[kk] = make_float4(0.f,0.f,0.f,0.f);
  for (int m4 = 0; m4 < 16; ++m4){
    float4 e[5];
#pragma unroll
    for (int kk = 0; kk < 5; ++kk) e[kk] = *(const float4*)(h0s + (k0+kk)*68 + 4*m4);
#pragma unroll
    for (int mm = 0; mm < 4; ++mm){
      float4 w = *(const float4*)(wt1 + (4*m4+mm)*128 + 4*cg);
#pragma unroll
      for (int kk = 0; kk < 5; ++kk){
        float ev = (mm==0)?e[kk].x:((mm==1)?e[kk].y:((mm==2)?e[kk].z:e[kk].w));
        b2[kk] = fma4s(w, ev, b2[kk]);
      }
    }
  }
  float4 p = make_float4(0.f,0.f,0.f,0.f);
#pragma unroll
  for (int kk = 0; kk < 5; ++kk) p = max4(p, b2[kk]);
  *(float4*)(smax + kg*128 + 4*cg) = p;
  __syncthreads();
  if (kg == 0){
    float4 r = *(const float4*)(smax + 4*cg);
#pragma unroll
    for (int g = 1; g < 4; ++g) r = max4(r, *(const float4*)(smax + g*128 + 4*cg));
    *(float4*)(out + (size_t)bi*128 + 4*cg) = r;
  }
}

// ---------------- T-Net 128->1024 + pool over points ----------------
__global__ __launch_bounds__(128) void k_tpool(const float* __restrict__ h, const float* __restrict__ W,
    float* __restrict__ g1024){
  int b = blockIdx.x, t = threadIdx.x;
  int c = blockIdx.y*128 + t;
  float4 w[32];
#pragma unroll
  for (int qq = 0; qq < 32; ++qq) w[qq] = *(const float4*)(W + (size_t)c*128 + 4*qq);
  const float* hb = h + (size_t)b*NPp*128;
  float mx = 0.0f;
  for (int i = 0; i < NPp; ++i){
    const float4* hr = (const float4*)(hb + (size_t)i*128);
    float a = 0.0f;
#pragma unroll
    for (int qq = 0; qq < 32; ++qq) a = fma4(w[qq], hr[qq], a);
    mx = fmaxf(mx, a);
  }
  g1024[(size_t)b*1024 + c] = mx;
}

// ---------------- T-Net MLP + 3x3 transform applied to new_xyz ----------------
__global__ __launch_bounds__(256) void k_trest(const float* __restrict__ g1024,
    const float* __restrict__ Wg0, const float* __restrict__ Wg1,
    const float* __restrict__ Wl, const float* __restrict__ bl,
    const float* __restrict__ new_xyz, float* __restrict__ x131){
  __shared__ __align__(16) float g1[1024];
  __shared__ __align__(16) float g5[512];
  __shared__ __align__(16) float g2[256];
  __shared__ float tm[12];
  int b = blockIdx.x, t = threadIdx.x;
  for (int m = t; m < 1024; m += 256) g1[m] = g1024[(size_t)b*1024 + m];
  __syncthreads();
#pragma unroll
  for (int cc = 0; cc < 2; ++cc){
    int c = t + cc*256;
    const float4* wr = (const float4*)(Wg0 + (size_t)c*1024);
    const float4* gv = (const float4*)g1;
    float a = 0.0f;
    for (int qq = 0; qq < 256; ++qq) a = fma4(wr[qq], gv[qq], a);
    g5[c] = fmaxf(a, 0.0f);
  }
  __syncthreads();
  {
    const float4* wr = (const float4*)(Wg1 + (size_t)t*512);
    const float4* gv = (const float4*)g5;
    float a = 0.0f;
    for (int qq = 0; qq < 128; ++qq) a = fma4(wr[qq], gv[qq], a);
    g2[t] = fmaxf(a, 0.0f);
  }
  __syncthreads();
  if (t < 9){
    const float4* wr = (const float4*)(Wl + (size_t)t*256);
    const float4* gv = (const float4*)g2;
    float a = 0.0f;
#pragma unroll
    for (int qq = 0; qq < 64; ++qq) a = fma4(wr[qq], gv[qq], a);
    a += bl[t];
    if (t == 0 || t == 4 || t == 8) a += 1.0f;
    tm[t] = a;
  }
  __syncthreads();
  {
    const float* nx = new_xyz + ((size_t)b*NPp + t)*3;
    float X = nx[0], Y = nx[1], Z = nx[2];
#pragma unroll
    for (int i = 0; i < 3; ++i){
      float v = __fadd_rn(__fadd_rn(__fmul_rn(tm[i*3+0], X), __fmul_rn(tm[i*3+1], Y)), __fmul_rn(tm[i*3+2], Z));
      x131[((size_t)b*NPp + t)*132 + 128 + i] = v;
    }
  }
}

// ---------------- zero scratch ----------------
__global__ void k_zero(float* p, int n){
  int i = blockIdx.x*256 + threadIdx.x;
  if (i < n) p[i] = 0.0f;
}

// ---------------- 896->128 conv + global max pool (atomic) ----------------
__global__ __launch_bounds__(128) void k_dgl(const float* __restrict__ f1, const float* __restrict__ f2,
    const float* __restrict__ f3, const float* __restrict__ W, float* __restrict__ g128){
  int b = blockIdx.x, t = threadIdx.x;
  int i0 = blockIdx.y * 16;
  const float* wr = W + (size_t)t*896;
  float acc[16];
#pragma unroll
  for (int ii = 0; ii < 16; ++ii) acc[ii] = 0.0f;
  for (int q = 0; q < 32; ++q){
    float4 w = *(const float4*)(wr + 4*q);
#pragma unroll
    for (int ii = 0; ii < 16; ++ii){
      float4 v = *(const float4*)(f1 + ((size_t)b*NPp + i0 + ii)*128 + 4*q);
      acc[ii] = fma4(w, v, acc[ii]);
    }
  }
  for (int q = 0; q < 64; ++q){
    float4 w = *(const float4*)(wr + 128 + 4*q);
#pragma unroll
    for (int ii = 0; ii < 16; ++ii){
      float4 v = *(const float4*)(f2 + ((size_t)b*NPp + i0 + ii)*256 + 4*q);
      acc[ii] = fma4(w, v, acc[ii]);
    }
  }
  for (int q = 0; q < 128; ++q){
    float4 w = *(const float4*)(wr + 384 + 4*q);
#pragma unroll
    for (int ii = 0; ii < 16; ++ii){
      float4 v = *(const float4*)(f3 + ((size_t)b*NPp + i0 + ii)*512 + 4*q);
      acc[ii] = fma4(w, v, acc[ii]);
    }
  }
#pragma unroll
  for (int ii = 0; ii < 16; ++ii){
    float v = fmaxf(acc[ii], 0.0f);
    atomicMax((int*)(g128 + (size_t)b*128 + t), __float_as_int(v));
  }
}

// ---------------- classifier head ----------------
__global__ __launch_bounds__(256) void k_final(const float* __restrict__ g128,
    const float* __restrict__ W0, const float* __restrict__ W1,
    const float* __restrict__ Wc, const float* __restrict__ bc, float* __restrict__ out){
  __shared__ __align__(16) float g0[128];
  __shared__ __align__(16) float g5[512];
  __shared__ __align__(16) float g2[256];
  int b = blockIdx.x, t = threadIdx.x;
  if (t < 128) g0[t] = g128[(size_t)b*128 + t];
  __syncthreads();
#pragma unroll
  for (int cc = 0; cc < 2; ++cc){
    int c = t + cc*256;
    const float4* wr = (const float4*)(W0 + (size_t)c*128);
    const float4* gv = (const float4*)g0;
    float a = 0.0f;
#pragma unroll
    for (int qq = 0; qq < 32; ++qq) a = fma4(wr[qq], gv[qq], a);
    g5[c] = fmaxf(a, 0.0f);
  }
  __syncthreads();
  {
    const float4* wr = (const float4*)(W1 + (size_t)t*512);
    const float4* gv = (const float4*)g5;
    float a = 0.0f;
    for (int qq = 0; qq < 128; ++qq) a = fma4(wr[qq], gv[qq], a);
    g2[t] = fmaxf(a, 0.0f);
  }
  __syncthreads();
  if (t < 40){
    const float4* wr = (const float4*)(Wc + (size_t)t*256);
    const float4* gv = (const float4*)g2;
    float a = 0.0f;
#pragma unroll
    for (int qq = 0; qq < 64; ++qq) a = fma4(wr[qq], gv[qq], a);
    out[(size_t)b*40 + t] = a + bc[t];
  }
}

extern "C" void kernel_launch(void* const* d_in, const int* in_sizes, int n_in,
                              void* d_out, int out_size, void* d_ws, size_t ws_size,
                              hipStream_t stream){
  (void)in_sizes; (void)n_in; (void)out_size; (void)ws_size;
  const float* points     = (const float*)d_in[0];
  const float* sa_w0      = (const float*)d_in[1];
  const float* sa_w1      = (const float*)d_in[2];
  const float* sa_w2      = (const float*)d_in[3];
  const float* t_ec_w0    = (const float*)d_in[4];
  const float* t_ec_w1    = (const float*)d_in[5];
  const float* t_local_w  = (const float*)d_in[6];
  const float* t_g_w0     = (const float*)d_in[7];
  const float* t_g_w1     = (const float*)d_in[8];
  const float* t_lin_w    = (const float*)d_in[9];
  const float* t_lin_b    = (const float*)d_in[10];
  const float* dg_ec_w0   = (const float*)d_in[11];
  const float* dg_ec_w1   = (const float*)d_in[12];
  const float* dg_ec_w2   = (const float*)d_in[13];
  const float* dg_local_w = (const float*)d_in[14];
  const float* dg_g_w0    = (const float*)d_in[15];
  const float* dg_g_w1    = (const float*)d_in[16];
  const float* cls_w      = (const float*)d_in[17];
  const float* cls_b      = (const float*)d_in[18];
  float* out = (float*)d_out;

  float* ws     = (float*)d_ws;
  float* xyz    = ws;                    // B*N*3          = 393216
  float* xnrm   = xyz    + 393216;       // B*N            = 131072
  float* nxyz   = xnrm   + 131072;       // B*256*3        = 24576
  float* feat   = nxyz   + 24576;        // B*256*128      = 1048576
  float* x131   = feat   + 1048576;      // B*256*132      = 1081344
  float* nrm    = x131   + 1081344;      // B*256          = 8192
  int*   idx    = (int*)(nrm + 8192);    // B*256*20       = 163840
  float* ht     = (float*)(idx + 163840);// B*256*128      = 1048576  (reused as f1)
  float* g1024v = ht     + 1048576;      // B*1024         = 32768
  float* f2     = g1024v + 32768;        // B*256*256      = 2097152
  float* f3     = f2     + 2097152;      // B*256*512      = 4194304
  float* g128v  = f3     + 4194304;      // B*128          = 4096
  float* wt_t0  = g128v  + 4096;         // 262*64         = 16768
  float* wt_t1  = wt_t0  + 16768;        // 64*128         = 8192
  float* wt_d0  = wt_t1  + 8192;         // 262*128        = 33536
  float* wt_d1  = wt_d0  + 33536;        // 256*256        = 65536
  float* wt_d2  = wt_d1  + 65536;        // 512*512        = 262144
  float* f1 = ht;
  float* xT = f3;                        // alias: xT (<=2097152 floats) lives in f3 until k_edge2 layer-3 writes f3

  k_prep<<<512, 256, 0, stream>>>(points, xyz, xnrm);
  // weight transposes (tiny, once per launch)
  k_wt<<<(64*262+255)/256,  256, 0, stream>>>(t_ec_w0,  wt_t0, 64, 262);
  k_wt<<<(128*64+255)/256,  256, 0, stream>>>(t_ec_w1,  wt_t1, 128, 64);
  k_wt<<<(128*262+255)/256, 256, 0, stream>>>(dg_ec_w0, wt_d0, 128, 262);
  k_wt<<<(256*256+255)/256, 256, 0, stream>>>(dg_ec_w1, wt_d1, 256, 256);
  k_wt<<<(512*512+255)/256, 256, 0, stream>>>(dg_ec_w2, wt_d2, 512, 512);

  k_fps<<<BB, 256, 0, stream>>>(xyz, nxyz);
  k_sa<<<BB*NPp, 64, 0, stream>>>(xyz, xnrm, nxyz, sa_w0, sa_w1, sa_w2, feat, x131);

  // T-Net branch (x = [feat, new_xyz])
  k_xt<131><<<(BB*131*256+255)/256, 256, 0, stream>>>(x131, 132, xT);
  k_norm2<131><<<128, 64, 0, stream>>>(xT, nrm);
  k_knn2<131><<<BB*NPp, 64, 0, stream>>>(xT, nrm, idx);
  k_tedge2<<<BB*NPp, 128, 0, stream>>>(x131, idx, wt_t0, wt_t1, ht);
  k_tpool<<<dim3(BB, 8), 128, 0, stream>>>(ht, t_local_w, g1024v);
  k_trest<<<BB, 256, 0, stream>>>(g1024v, t_g_w0, t_g_w1, t_lin_w, t_lin_b, nxyz, x131);

  // DGCNN layer 1 (x = [feat, xyz_t], 131 dims)
  k_xt<131><<<(BB*131*256+255)/256, 256, 0, stream>>>(x131, 132, xT);
  k_norm2<131><<<128, 64, 0, stream>>>(xT, nrm);
  k_knn2<131><<<BB*NPp, 64, 0, stream>>>(xT, nrm, idx);
  k_edge2<131,128,128,4><<<BB*NPp, 128, 0, stream>>>(x131, 132, idx, wt_d0, f1);
  // layer 2
  k_xt<128><<<(BB*128*256+255)/256, 256, 0, stream>>>(f1, 128, xT);
  k_norm2<128><<<128, 64, 0, stream>>>(xT, nrm);
  k_knn2<128><<<BB*NPp, 64, 0, stream>>>(xT, nrm, idx);
  k_edge2<128,256,128,4><<<BB*NPp, 128, 0, stream>>>(f1, 128, idx, wt_d1, f2);
  // layer 3
  k_xt<256><<<(BB*256*256+255)/256, 256, 0, stream>>>(f2, 256, xT);
  k_norm2<256><<<128, 64, 0, stream>>>(xT, nrm);
  k_knn2<256><<<BB*NPp, 64, 0, stream>>>(xT, nrm, idx);
  k_edge2<256,512,128,2><<<BB*NPp, 128, 0, stream>>>(f2, 256, idx, wt_d2, f3);

  // local conv + global pool + head
  k_zero<<<16, 256, 0, stream>>>(g128v, 4096);
  k_dgl<<<dim3(BB, 16), 128, 0, stream>>>(f1, f2, f3, dg_local_w, g128v);
  k_final<<<BB, 256, 0, stream>>>(g128v, dg_g_w0, dg_g_w1, cls_w, cls_b, out);
}

// Round 3
// 2803.708 us; speedup vs baseline: 2.1862x; 1.0120x over previous
//
#include <hip/hip_runtime.h>
#include <math.h>

#define BB 32
#define NN 4096
#define NPp 256
#define NSs 64
#define KC 20

__device__ __forceinline__ float fma4(const float4 w, const float4 v, float a){
  a = fmaf(w.x, v.x, a); a = fmaf(w.y, v.y, a);
  a = fmaf(w.z, v.z, a); a = fmaf(w.w, v.w, a); return a;
}
__device__ __forceinline__ float4 fma4s(const float4 w, float s, float4 a){
  a.x = fmaf(w.x, s, a.x); a.y = fmaf(w.y, s, a.y);
  a.z = fmaf(w.z, s, a.z); a.w = fmaf(w.w, s, a.w); return a;
}
__device__ __forceinline__ float4 max4(float4 a, float4 b){
  a.x = fmaxf(a.x, b.x); a.y = fmaxf(a.y, b.y);
  a.z = fmaxf(a.z, b.z); a.w = fmaxf(a.w, b.w); return a;
}

// ---------------- weight transpose: WT[c*R + r] = W[r*C + c] ----------------
__global__ void k_wt(const float* __restrict__ W, float* __restrict__ WT, int R, int C){
  int i = blockIdx.x*256 + threadIdx.x;
  if (i >= R*C) return;
  int r = i % R, c = i / R;
  WT[(size_t)c*R + r] = W[(size_t)r*C + c];
}

// ---------------- transpose + point norms ----------------
__global__ void k_prep(const float* __restrict__ pts, float* __restrict__ xyz, float* __restrict__ xnrm){
  int i = blockIdx.x*256 + threadIdx.x;
  if (i >= BB*NN) return;
  int b = i >> 12, n = i & (NN-1);
  float X = pts[(b*3+0)*NN + n];
  float Y = pts[(b*3+1)*NN + n];
  float Z = pts[(b*3+2)*NN + n];
  xyz[i*3+0]=X; xyz[i*3+1]=Y; xyz[i*3+2]=Z;
  xnrm[i] = __fadd_rn(__fadd_rn(__fmul_rn(X,X), __fmul_rn(Y,Y)), __fmul_rn(Z,Z));
}

// ---------------- farthest point sampling ----------------
__global__ __launch_bounds__(256) void k_fps(const float* __restrict__ xyz, float* __restrict__ new_xyz){
  __shared__ float xs[NN], ys[NN], zs[NN];
  __shared__ float rv[4];
  __shared__ int   ri[4];
  __shared__ int   slast;
  int b = blockIdx.x, t = threadIdx.x;
  for (int j = t; j < NN; j += 256){
    const float* p = xyz + ((size_t)b*NN + j)*3;
    xs[j] = p[0]; ys[j] = p[1]; zs[j] = p[2];
  }
  float dist[16];
#pragma unroll
  for (int q = 0; q < 16; ++q) dist[q] = __builtin_inff();
  int last = 0;
  __syncthreads();
  for (int it = 0; it < NPp; ++it){
    if (t == 0){
      float* o = new_xyz + ((size_t)b*NPp + it)*3;
      o[0] = xs[last]; o[1] = ys[last]; o[2] = zs[last];
    }
    float px = xs[last], py = ys[last], pz = zs[last];
    float bv = -1.0f; int bj = 0;
#pragma unroll
    for (int q = 0; q < 16; ++q){
      int j = q*256 + t;
      float dx = __fsub_rn(xs[j], px);
      float dy = __fsub_rn(ys[j], py);
      float dz = __fsub_rn(zs[j], pz);
      float dd = __fadd_rn(__fadd_rn(__fmul_rn(dx,dx), __fmul_rn(dy,dy)), __fmul_rn(dz,dz));
      float dm = fminf(dist[q], dd);
      dist[q] = dm;
      if (dm > bv){ bv = dm; bj = j; }
    }
#pragma unroll
    for (int off = 32; off >= 1; off >>= 1){
      float ov = __shfl_xor(bv, off, 64);
      int   oj = __shfl_xor(bj, off, 64);
      if (ov > bv || (ov == bv && oj < bj)){ bv = ov; bj = oj; }
    }
    int w = t >> 6;
    if ((t & 63) == 0){ rv[w] = bv; ri[w] = bj; }
    __syncthreads();
    if (t == 0){
      float fv = rv[0]; int fj = ri[0];
      for (int ww = 1; ww < 4; ++ww)
        if (rv[ww] > fv || (rv[ww] == fv && ri[ww] < fj)){ fv = rv[ww]; fj = ri[ww]; }
      slast = fj;
    }
    __syncthreads();
    last = slast;
  }
}

// ---------------- ball query + SA convs + maxpool ----------------
__global__ __launch_bounds__(64) void k_sa(const float* __restrict__ xyz, const float* __restrict__ xnrm,
    const float* __restrict__ new_xyz, const float* __restrict__ w0, const float* __restrict__ w1,
    const float* __restrict__ w2, float* __restrict__ feat, float* __restrict__ x131){
  __shared__ __align__(16) float h1s[64*68];
  __shared__ int gix[64];
  int bi = blockIdx.x, lane = threadIdx.x;
  int b = bi >> 8;
  const float* q = new_xyz + (size_t)bi*3;
  float qx=q[0], qy=q[1], qz=q[2];
  float nq = __fadd_rn(__fadd_rn(__fmul_rn(qx,qx), __fmul_rn(qy,qy)), __fmul_rn(qz,qz));
  int cnt = 0;
  for (int base = 0; base < NN && cnt < NSs; base += 64){
    int j = base + lane;
    const float* p = xyz + ((size_t)b*NN + j)*3;
    float dot = __fadd_rn(__fadd_rn(__fmul_rn(qx,p[0]), __fmul_rn(qy,p[1])), __fmul_rn(qz,p[2]));
    float d2 = __fsub_rn(__fadd_rn(nq, xnrm[b*NN + j]), __fmul_rn(2.0f, dot));
    bool inb = d2 < 0.04f;
    unsigned long long m = __ballot(inb);
    int pos = cnt + (int)__popcll(m & ((1ull << lane) - 1ull));
    if (inb && pos < NSs) gix[pos] = j;
    cnt += (int)__popcll(m);
  }
  __syncthreads();
  int g0 = gix[0];
  if (lane >= cnt) gix[lane] = g0;
  __syncthreads();
  {
    int gj = gix[lane];
    const float* p = xyz + ((size_t)b*NN + gj)*3;
    float px = p[0]-qx, py = p[1]-qy, pz = p[2]-qz;
    float h0[64];
#pragma unroll
    for (int c = 0; c < 64; ++c){
      float a = fmaf(w0[c*3+2], pz, fmaf(w0[c*3+1], py, w0[c*3]*px));
      h0[c] = fmaxf(a, 0.0f);
    }
    for (int c = 0; c < 64; ++c){
      const float4* wr = (const float4*)(w1 + c*64);
      float a = 0.0f;
#pragma unroll
      for (int qq = 0; qq < 16; ++qq){
        float4 w = wr[qq];
        a = fmaf(w.x, h0[4*qq+0], a);
        a = fmaf(w.y, h0[4*qq+1], a);
        a = fmaf(w.z, h0[4*qq+2], a);
        a = fmaf(w.w, h0[4*qq+3], a);
      }
      h1s[lane*68 + c] = fmaxf(a, 0.0f);
    }
  }
  __syncthreads();
  float4 wa[16], wb[16];
#pragma unroll
  for (int qq = 0; qq < 16; ++qq){
    wa[qq] = *(const float4*)(w2 + (size_t)lane*64 + 4*qq);
    wb[qq] = *(const float4*)(w2 + (size_t)(lane+64)*64 + 4*qq);
  }
  float m0 = 0.0f, m1 = 0.0f;
  for (int s = 0; s < 64; s += 2){
    const float4* hr0 = (const float4*)(h1s + s*68);
    const float4* hr1 = (const float4*)(h1s + (s+1)*68);
    float a0 = 0.0f, a1 = 0.0f, a2 = 0.0f, a3 = 0.0f;
#pragma unroll
    for (int qq = 0; qq < 16; ++qq){
      float4 h0v = hr0[qq], h1v = hr1[qq];
      a0 = fma4(wa[qq], h0v, a0);
      a1 = fma4(wb[qq], h0v, a1);
      a2 = fma4(wa[qq], h1v, a2);
      a3 = fma4(wb[qq], h1v, a3);
    }
    m0 = fmaxf(fmaxf(m0, a0), a2); m1 = fmaxf(fmaxf(m1, a1), a3);
  }
  feat[(size_t)bi*128 + lane]      = m0;
  feat[(size_t)bi*128 + 64 + lane] = m1;
  x131[(size_t)bi*132 + lane]      = m0;
  x131[(size_t)bi*132 + 64 + lane] = m1;
  if (lane < 3) x131[(size_t)bi*132 + 128 + lane] = (lane==0)?qx:((lane==1)?qy:qz);
}

// ---------------- per-batch feature transpose: xT[b][m][256] ----------------
template<int CIN>
__global__ void k_xt(const float* __restrict__ x, int xstride, float* __restrict__ xT){
  int o = blockIdx.x*256 + threadIdx.x;
  if (o >= BB*CIN*256) return;
  int col = o & 255; int t1 = o >> 8; int m = t1 % CIN; int b = t1 / CIN;
  xT[o] = x[((size_t)(b*256+col))*xstride + m];
}

// ---------------- feature norms (from xT, coalesced) ----------------
template<int CIN>
__global__ void k_norm2(const float* __restrict__ xT, float* __restrict__ nrm){
  int p = blockIdx.x*64 + threadIdx.x;
  if (p >= BB*NPp) return;
  int b = p >> 8, col = p & 255;
  const float* base = xT + (size_t)b*CIN*256 + col;
  float a = 0.0f;
  for (int m = 0; m < CIN; ++m){
    float v = base[m*256];
    a = __fadd_rn(a, __fmul_rn(v, v));
  }
  nrm[p] = a;
}

// ---------------- kNN, 8 centroids/block, LDS-staged xT chunks ----------------
template<int CIN>
__global__ __launch_bounds__(512) void k_knn3(const float* __restrict__ xT,
    const float* __restrict__ nrm, int* __restrict__ idxo){
  __shared__ __align__(16) float sch[16*256];   // 16 KB chunk
  __shared__ __align__(16) float ds[8*256];     // 8 KB distances
  int bi = blockIdx.x, t = threadIdx.x;
  int w = t >> 6, lane = t & 63;
  int b = bi >> 5;
  int coli = (bi & 31)*8 + w;
  const float* xb = xT + (size_t)b*CIN*256;
  float d0=0.f, d1=0.f, d2=0.f, d3=0.f;
  for (int m0 = 0; m0 < CIN; m0 += 16){
    int mc = (CIN - m0 < 16) ? (CIN - m0) : 16;
    for (int i = t; i < mc*64; i += 512){
      int mm = i >> 6, c4 = i & 63;
      *(float4*)(sch + mm*256 + c4*4) = *(const float4*)(xb + (size_t)(m0+mm)*256 + c4*4);
    }
    __syncthreads();
    for (int mm = 0; mm < mc; ++mm){
      float xm = sch[mm*256 + coli];
      float4 v = *(const float4*)(sch + mm*256 + 4*lane);
      d0 = fmaf(v.x, xm, d0); d1 = fmaf(v.y, xm, d1);
      d2 = fmaf(v.z, xm, d2); d3 = fmaf(v.w, xm, d3);
    }
    __syncthreads();
  }
  float ni = nrm[b*256 + coli];
  {
    int j0 = 4*lane;
    float4 dv;
    dv.x = __fsub_rn(__fadd_rn(ni, nrm[b*256 + j0+0]), __fmul_rn(2.0f, d0));
    dv.y = __fsub_rn(__fadd_rn(ni, nrm[b*256 + j0+1]), __fmul_rn(2.0f, d1));
    dv.z = __fsub_rn(__fadd_rn(ni, nrm[b*256 + j0+2]), __fmul_rn(2.0f, d2));
    dv.w = __fsub_rn(__fadd_rn(ni, nrm[b*256 + j0+3]), __fmul_rn(2.0f, d3));
    *(float4*)(ds + w*256 + j0) = dv;
  }
  __syncthreads();
  for (int r = 0; r < KC; ++r){
    float bv = 3.4e38f; int bj = NPp;
    float4 dv = *(const float4*)(ds + w*256 + 4*lane);
#pragma unroll
    for (int q = 0; q < 4; ++q){
      float v = (q==0)?dv.x:((q==1)?dv.y:((q==2)?dv.z:dv.w));
      int j = 4*lane + q;
      if (v < bv){ bv = v; bj = j; }
    }
#pragma unroll
    for (int off = 32; off >= 1; off >>= 1){
      float ov = __shfl_xor(bv, off, 64);
      int   oj = __shfl_xor(bj, off, 64);
      if (ov < bv || (ov == bv && oj < bj)){ bv = ov; bj = oj; }
    }
    if (lane == 0){ idxo[((size_t)b*256 + coli)*KC + r] = bj; ds[w*256 + bj] = 3.0e38f; }
    __syncthreads();
  }
}

// ---------------- DGCNN edge conv layer 1: CIN=131,COUT=128, 8 centroids/block ----------------
__global__ __launch_bounds__(512, 2) void k_edgeL1(const float* __restrict__ x,
    const int* __restrict__ idx, const float* __restrict__ wt, float* __restrict__ out){
  constexpr int ST = 136;
  __shared__ float xis[8*ST];
  __shared__ float ed[20*8*ST];
  int bi = blockIdx.x, t = threadIdx.x;
  int w = t >> 6, lane = t & 63;
  int cl = lane & 31, ks = lane >> 5, k0 = ks*10;
  int b = bi >> 5, rb = b << 8;
  int c0 = bi*8;
  for (int gg = 0; gg < 8; ++gg){
    const float* xr = x + (size_t)(c0+gg)*132;
    for (int m = t; m < 131; m += 512) xis[gg*ST + m] = xr[m];
  }
  __syncthreads();
  for (int r = w; r < 160; r += 8){
    int k = r >> 3, gg = r & 7;
    int j = idx[(size_t)(c0+gg)*KC + k];
    const float* xj = x + (size_t)(rb+j)*132;
    float* er = ed + k*(8*ST) + gg*ST;
    const float* xg = xis + gg*ST;
    for (int m = lane; m < 131; m += 64) er[m] = xj[m] - xg[m];
  }
  __syncthreads();
  const float* xg = xis + w*ST;
  float4 base = make_float4(0.f,0.f,0.f,0.f);
  for (int m = 0; m < 131; ++m)
    base = fma4s(*(const float4*)(wt + (size_t)m*128 + 4*cl), xg[m], base);
  float4 acc[10];
#pragma unroll
  for (int kk = 0; kk < 10; ++kk) acc[kk] = base;
  const float* wtd = wt + 131*128;
  const float* edg = ed + w*ST;
  for (int m4 = 0; m4 < 32; ++m4){
    float4 e[10];
#pragma unroll
    for (int kk = 0; kk < 10; ++kk) e[kk] = *(const float4*)(edg + (k0+kk)*(8*ST) + 4*m4);
#pragma unroll
    for (int mm = 0; mm < 4; ++mm){
      float4 wv = *(const float4*)(wtd + (size_t)(4*m4+mm)*128 + 4*cl);
#pragma unroll
      for (int kk = 0; kk < 10; ++kk){
        float ev = (mm==0)?e[kk].x:((mm==1)?e[kk].y:((mm==2)?e[kk].z:e[kk].w));
        acc[kk] = fma4s(wv, ev, acc[kk]);
      }
    }
  }
  for (int m = 128; m < 131; ++m){
    float4 wv = *(const float4*)(wtd + (size_t)m*128 + 4*cl);
#pragma unroll
    for (int kk = 0; kk < 10; ++kk)
      acc[kk] = fma4s(wv, edg[(k0+kk)*(8*ST) + m], acc[kk]);
  }
  float4 p = make_float4(0.f,0.f,0.f,0.f);
#pragma unroll
  for (int kk = 0; kk < 10; ++kk) p = max4(p, acc[kk]);
  p.x = fmaxf(p.x, __shfl_xor(p.x, 32, 64));
  p.y = fmaxf(p.y, __shfl_xor(p.y, 32, 64));
  p.z = fmaxf(p.z, __shfl_xor(p.z, 32, 64));
  p.w = fmaxf(p.w, __shfl_xor(p.w, 32, 64));
  if (ks == 0) *(float4*)(out + (size_t)(c0+w)*128 + 4*cl) = p;
}

// ---------------- DGCNN edge conv layer 2: CIN=128,COUT=256, 8 centroids/block ----------------
__global__ __launch_bounds__(512, 2) void k_edgeL2(const float* __restrict__ x,
    const int* __restrict__ idx, const float* __restrict__ wt, float* __restrict__ out){
  constexpr int ST = 136;
  __shared__ float xis[8*ST];
  __shared__ float ed[20*8*ST];
  int bi = blockIdx.x, t = threadIdx.x;
  int w = t >> 6, lane = t & 63;
  int b = bi >> 5, rb = b << 8;
  int c0 = bi*8;
  for (int i = t; i < 8*128; i += 512){
    int gg = i >> 7, m = i & 127;
    xis[gg*ST + m] = x[(size_t)(c0+gg)*128 + m];
  }
  __syncthreads();
  for (int r = w; r < 160; r += 8){
    int k = r >> 3, gg = r & 7;
    int j = idx[(size_t)(c0+gg)*KC + k];
    const float* xj = x + (size_t)(rb+j)*128;
    float* er = ed + k*(8*ST) + gg*ST;
    const float* xg = xis + gg*ST;
    for (int m = lane; m < 128; m += 64) er[m] = xj[m] - xg[m];
  }
  __syncthreads();
  const float* xg = xis + w*ST;
  float4 base = make_float4(0.f,0.f,0.f,0.f);
  for (int m = 0; m < 128; ++m)
    base = fma4s(*(const float4*)(wt + (size_t)m*256 + 4*lane), xg[m], base);
  float4 acca[10], accb[10];
#pragma unroll
  for (int kk = 0; kk < 10; ++kk){ acca[kk] = base; accb[kk] = base; }
  const float* wtd = wt + 128*256;
  const float* edg = ed + w*ST;
  for (int m4 = 0; m4 < 32; ++m4){
    {
      float4 e[10];
#pragma unroll
      for (int kk = 0; kk < 10; ++kk) e[kk] = *(const float4*)(edg + kk*(8*ST) + 4*m4);
#pragma unroll
      for (int mm = 0; mm < 4; ++mm){
        float4 wv = *(const float4*)(wtd + (size_t)(4*m4+mm)*256 + 4*lane);
#pragma unroll
        for (int kk = 0; kk < 10; ++kk){
          float ev = (mm==0)?e[kk].x:((mm==1)?e[kk].y:((mm==2)?e[kk].z:e[kk].w));
          acca[kk] = fma4s(wv, ev, acca[kk]);
        }
      }
    }
    {
      float4 e[10];
#pragma unroll
      for (int kk = 0; kk < 10; ++kk) e[kk] = *(const float4*)(edg + (10+kk)*(8*ST) + 4*m4);
#pragma unroll
      for (int mm = 0; mm < 4; ++mm){
        float4 wv = *(const float4*)(wtd + (size_t)(4*m4+mm)*256 + 4*lane);
#pragma unroll
        for (int kk = 0; kk < 10; ++kk){
          float ev = (mm==0)?e[kk].x:((mm==1)?e[kk].y:((mm==2)?e[kk].z:e[kk].w));
          accb[kk] = fma4s(wv, ev, accb[kk]);
        }
      }
    }
  }
  float4 p = make_float4(0.f,0.f,0.f,0.f);
#pragma unroll
  for (int kk = 0; kk < 10; ++kk){ p = max4(p, acca[kk]); p = max4(p, accb[kk]); }
  *(float4*)(out + (size_t)(c0+w)*256 + 4*lane) = p;
}

// ---------------- DGCNN edge conv layer 3: CIN=256,COUT=512, 4 centroids/block ----------------
__global__ __launch_bounds__(512, 2) void k_edgeL3(const float* __restrict__ x,
    const int* __restrict__ idx, const float* __restrict__ wt, float* __restrict__ out){
  constexpr int ST = 260;
  __shared__ float xis[4*ST];                 // 4160 B
  __shared__ float ed[20*4*ST];               // 83200 B
  __shared__ __align__(16) float smax[8*512]; // 16384 B
  int bi = blockIdx.x, t = threadIdx.x;
  int w = t >> 6, lane = t & 63;
  int g = w >> 1, kh = w & 1, k0 = kh*10;
  int b = bi >> 6, rb = b << 8;
  int c0 = bi*4;
  for (int i = t; i < 4*256; i += 512){
    int gg = i >> 8, m = i & 255;
    xis[gg*ST + m] = x[(size_t)(c0+gg)*256 + m];
  }
  __syncthreads();
  for (int r = w; r < 80; r += 8){
    int k = r >> 2, gg = r & 3;
    int j = idx[(size_t)(c0+gg)*KC + k];
    const float* xj = x + (size_t)(rb+j)*256;
    float* er = ed + k*(4*ST) + gg*ST;
    const float* xg = xis + gg*ST;
    for (int m = lane; m < 256; m += 64) er[m] = xj[m] - xg[m];
  }
  __syncthreads();
  const float* xg = xis + g*ST;
  float4 base0 = make_float4(0.f,0.f,0.f,0.f);
  float4 base1 = make_float4(0.f,0.f,0.f,0.f);
  for (int m = 0; m < 256; ++m){
    float xm = xg[m];
    base0 = fma4s(*(const float4*)(wt + (size_t)m*512 + 4*lane),       xm, base0);
    base1 = fma4s(*(const float4*)(wt + (size_t)m*512 + 4*lane + 256), xm, base1);
  }
  float4 acc0[10], acc1[10];
#pragma unroll
  for (int kk = 0; kk < 10; ++kk){ acc0[kk] = base0; acc1[kk] = base1; }
  const float* wtd = wt + 256*512;
  const float* edg = ed + g*ST;
  for (int m4 = 0; m4 < 64; ++m4){
    float4 e[10];
#pragma unroll
    for (int kk = 0; kk < 10; ++kk) e[kk] = *(const float4*)(edg + (k0+kk)*(4*ST) + 4*m4);
#pragma unroll
    for (int mm = 0; mm < 4; ++mm){
      float4 w0 = *(const float4*)(wtd + (size_t)(4*m4+mm)*512 + 4*lane);
      float4 w1 = *(const float4*)(wtd + (size_t)(4*m4+mm)*512 + 4*lane + 256);
#pragma unroll
      for (int kk = 0; kk < 10; ++kk){
        float ev = (mm==0)?e[kk].x:((mm==1)?e[kk].y:((mm==2)?e[kk].z:e[kk].w));
        acc0[kk] = fma4s(w0, ev, acc0[kk]);
        acc1[kk] = fma4s(w1, ev, acc1[kk]);
      }
    }
  }
  float4 p0 = make_float4(0.f,0.f,0.f,0.f);
  float4 p1 = make_float4(0.f,0.f,0.f,0.f);
#pragma unroll
  for (int kk = 0; kk < 10; ++kk){ p0 = max4(p0, acc0[kk]); p1 = max4(p1, acc1[kk]); }
  *(float4*)(smax + (g*2+kh)*512 + 4*lane)       = p0;
  *(float4*)(smax + (g*2+kh)*512 + 4*lane + 256) = p1;
  __syncthreads();
  if (kh == 0){
    float4 r0 = max4(*(const float4*)(smax + (g*2)*512 + 4*lane),
                     *(const float4*)(smax + (g*2+1)*512 + 4*lane));
    float4 r1 = max4(*(const float4*)(smax + (g*2)*512 + 4*lane + 256),
                     *(const float4*)(smax + (g*2+1)*512 + 4*lane + 256));
    *(float4*)(out + (size_t)(c0+g)*512 + 4*lane)       = r0;
    *(float4*)(out + (size_t)(c0+g)*512 + 4*lane + 256) = r1;
  }
}

// ---------------- T-Net 2-layer edge conv + k-maxpool (transposed weights) ----------------
__global__ __launch_bounds__(128) void k_tedge2(const float* __restrict__ x, const int* __restrict__ idx,
    const float* __restrict__ wt0, const float* __restrict__ wt1, float* __restrict__ out){
  __shared__ float xi[132];
  __shared__ float ed[20*132];
  __shared__ __align__(16) float h0s[20*68];
  __shared__ __align__(16) float smax[4*128];
  int bi = blockIdx.x, t = threadIdx.x;
  int cg = t & 31, kg = t >> 5, k0 = kg*5;
  int rb = (bi >> 8) << 8;
  const float* xr = x + (size_t)bi*132;
  for (int m = t; m < 131; m += 128) xi[m] = xr[m];
  __syncthreads();
  for (int k = 0; k < KC; ++k){
    int j = idx[(size_t)bi*KC + k];
    const float* xj = x + (size_t)(rb + j)*132;
    for (int m = t; m < 131; m += 128) ed[k*132 + m] = xj[m] - xi[m];
  }
  __syncthreads();
  float base0 = 0.0f, base1 = 0.0f;
  for (int m = 0; m < 131; ++m){
    float xm = xi[m];
    base0 = fmaf(wt0[m*64 + cg],      xm, base0);
    base1 = fmaf(wt0[m*64 + cg + 32], xm, base1);
  }
  float a0[5], a1[5];
#pragma unroll
  for (int kk = 0; kk < 5; ++kk){ a0[kk] = base0; a1[kk] = base1; }
  const float* wt0d = wt0 + 131*64;
  for (int m4 = 0; m4 < 32; ++m4){
    float4 e[5];
#pragma unroll
    for (int kk = 0; kk < 5; ++kk) e[kk] = *(const float4*)(ed + (k0+kk)*132 + 4*m4);
#pragma unroll
    for (int mm = 0; mm < 4; ++mm){
      int m = 4*m4 + mm;
      float w0v = wt0d[m*64 + cg];
      float w1v = wt0d[m*64 + cg + 32];
#pragma unroll
      for (int kk = 0; kk < 5; ++kk){
        float ev = (mm==0)?e[kk].x:((mm==1)?e[kk].y:((mm==2)?e[kk].z:e[kk].w));
        a0[kk] = fmaf(w0v, ev, a0[kk]);
        a1[kk] = fmaf(w1v, ev, a1[kk]);
      }
    }
  }
  for (int m = 128; m < 131; ++m){
    float w0v = wt0d[m*64 + cg];
    float w1v = wt0d[m*64 + cg + 32];
#pragma unroll
    for (int kk = 0; kk < 5; ++kk){
      float ev = ed[(k0+kk)*132 + m];
      a0[kk] = fmaf(w0v, ev, a0[kk]);
      a1[kk] = fmaf(w1v, ev, a1[kk]);
    }
  }
#pragma unroll
  for (int kk = 0; kk < 5; ++kk){
    h0s[(k0+kk)*68 + cg]      = fmaxf(a0[kk], 0.0f);
    h0s[(k0+kk)*68 + cg + 32] = fmaxf(a1[kk], 0.0f);
  }
  __syncthreads();
  float4 b2[5];
#pragma unroll
  for (int kk = 0; kk < 5; ++kk) b2[kk] = make_float4(0.f,0.f,0.f,0.f);
  for (int m4 = 0; m4 < 16; ++m4){
    float4 e[5];
#pragma unroll
    for (int kk = 0; kk < 5; ++kk) e[kk] = *(const float4*)(h0s + (k0+kk)*68 + 4*m4);
#pragma unroll
    for (int mm = 0; mm < 4; ++mm){
      float4 w = *(const float4*)(wt1 + (4*m4+mm)*128 + 4*cg);
#pragma unroll
      for (int kk = 0; kk < 5; ++kk){
        float ev = (mm==0)?e[kk].x:((mm==1)?e[kk].y:((mm==2)?e[kk].z:e[kk].w));
        b2[kk] = fma4s(w, ev, b2[kk]);
      }
    }
  }
  float4 p = make_float4(0.f,0.f,0.f,0.f);
#pragma unroll
  for (int kk = 0; kk < 5; ++kk) p = max4(p, b2[kk]);
  *(float4*)(smax + kg*128 + 4*cg) = p;
  __syncthreads();
  if (kg == 0){
    float4 r = *(const float4*)(smax + 4*cg);
#pragma unroll
    for (int g = 1; g < 4; ++g) r = max4(r, *(const float4*)(smax + g*128 + 4*cg));
    *(float4*)(out + (size_t)bi*128 + 4*cg) = r;
  }
}

// ---------------- T-Net 128->1024 + pool over points ----------------
__global__ __launch_bounds__(128) void k_tpool(const float* __restrict__ h, const float* __restrict__ W,
    float* __restrict__ g1024){
  int b = blockIdx.x, t = threadIdx.x;
  int c = blockIdx.y*128 + t;
  float4 w[32];
#pragma unroll
  for (int qq = 0; qq < 32; ++qq) w[qq] = *(const float4*)(W + (size_t)c*128 + 4*qq);
  const float* hb = h + (size_t)b*NPp*128;
  float mx = 0.0f;
  for (int i = 0; i < NPp; ++i){
    const float4* hr = (const float4*)(hb + (size_t)i*128);
    float a = 0.0f;
#pragma unroll
    for (int qq = 0; qq < 32; ++qq) a = fma4(w[qq], hr[qq], a);
    mx = fmaxf(mx, a);
  }
  g1024[(size_t)b*1024 + c] = mx;
}

// ---------------- T-Net MLP + 3x3 transform applied to new_xyz ----------------
__global__ __launch_bounds__(256) void k_trest(const float* __restrict__ g1024,
    const float* __restrict__ Wg0, const float* __restrict__ Wg1,
    const float* __restrict__ Wl, const float* __restrict__ bl,
    const float* __restrict__ new_xyz, float* __restrict__ x131){
  __shared__ __align__(16) float g1[1024];
  __shared__ __align__(16) float g5[512];
  __shared__ __align__(16) float g2[256];
  __shared__ float tm[12];
  int b = blockIdx.x, t = threadIdx.x;
  for (int m = t; m < 1024; m += 256) g1[m] = g1024[(size_t)b*1024 + m];
  __syncthreads();
#pragma unroll
  for (int cc = 0; cc < 2; ++cc){
    int c = t + cc*256;
    const float4* wr = (const float4*)(Wg0 + (size_t)c*1024);
    const float4* gv = (const float4*)g1;
    float a = 0.0f;
    for (int qq = 0; qq < 256; ++qq) a = fma4(wr[qq], gv[qq], a);
    g5[c] = fmaxf(a, 0.0f);
  }
  __syncthreads();
  {
    const float4* wr = (const float4*)(Wg1 + (size_t)t*512);
    const float4* gv = (const float4*)g5;
    float a = 0.0f;
    for (int qq = 0; qq < 128; ++qq) a = fma4(wr[qq], gv[qq], a);
    g2[t] = fmaxf(a, 0.0f);
  }
  __syncthreads();
  if (t < 9){
    const float4* wr = (const float4*)(Wl + (size_t)t*256);
    const float4* gv = (const float4*)g2;
    float a = 0.0f;
#pragma unroll
    for (int qq = 0; qq < 64; ++qq) a = fma4(wr[qq], gv[qq], a);
    a += bl[t];
    if (t == 0 || t == 4 || t == 8) a += 1.0f;
    tm[t] = a;
  }
  __syncthreads();
  {
    const float* nx = new_xyz + ((size_t)b*NPp + t)*3;
    float X = nx[0], Y = nx[1], Z = nx[2];
#pragma unroll
    for (int i = 0; i < 3; ++i){
      float v = __fadd_rn(__fadd_rn(__fmul_rn(tm[i*3+0], X), __fmul_rn(tm[i*3+1], Y)), __fmul_rn(tm[i*3+2], Z));
      x131[((size_t)b*NPp + t)*132 + 128 + i] = v;
    }
  }
}

// ---------------- zero scratch ----------------
__global__ void k_zero(float* p, int n){
  int i = blockIdx.x*256 + threadIdx.x;
  if (i < n) p[i] = 0.0f;
}

// ---------------- 896->128 conv + global max pool (atomic) ----------------
__global__ __launch_bounds__(128) void k_dgl(const float* __restrict__ f1, const float* __restrict__ f2,
    const float* __restrict__ f3, const float* __restrict__ W, float* __restrict__ g128){
  int b = blockIdx.x, t = threadIdx.x;
  int i0 = blockIdx.y * 16;
  const float* wr = W + (size_t)t*896;
  float acc[16];
#pragma unroll
  for (int ii = 0; ii < 16; ++ii) acc[ii] = 0.0f;
  for (int q = 0; q < 32; ++q){
    float4 w = *(const float4*)(wr + 4*q);
#pragma unroll
    for (int ii = 0; ii < 16; ++ii){
      float4 v = *(const float4*)(f1 + ((size_t)b*NPp + i0 + ii)*128 + 4*q);
      acc[ii] = fma4(w, v, acc[ii]);
    }
  }
  for (int q = 0; q < 64; ++q){
    float4 w = *(const float4*)(wr + 128 + 4*q);
#pragma unroll
    for (int ii = 0; ii < 16; ++ii){
      float4 v = *(const float4*)(f2 + ((size_t)b*NPp + i0 + ii)*256 + 4*q);
      acc[ii] = fma4(w, v, acc[ii]);
    }
  }
  for (int q = 0; q < 128; ++q){
    float4 w = *(const float4*)(wr + 384 + 4*q);
#pragma unroll
    for (int ii = 0; ii < 16; ++ii){
      float4 v = *(const float4*)(f3 + ((size_t)b*NPp + i0 + ii)*512 + 4*q);
      acc[ii] = fma4(w, v, acc[ii]);
    }
  }
#pragma unroll
  for (int ii = 0; ii < 16; ++ii){
    float v = fmaxf(acc[ii], 0.0f);
    atomicMax((int*)(g128 + (size_t)b*128 + t), __float_as_int(v));
  }
}

// ---------------- classifier head ----------------
__global__ __launch_bounds__(256) void k_final(const float* __restrict__ g128,
    const float* __restrict__ W0, const float* __restrict__ W1,
    const float* __restrict__ Wc, const float* __restrict__ bc, float* __restrict__ out){
  __shared__ __align__(16) float g0[128];
  __shared__ __align__(16) float g5[512];
  __shared__ __align__(16) float g2[256];
  int b = blockIdx.x, t = threadIdx.x;
  if (t < 128) g0[t] = g128[(size_t)b*128 + t];
  __syncthreads();
#pragma unroll
  for (int cc = 0; cc < 2; ++cc){
    int c = t + cc*256;
    const float4* wr = (const float4*)(W0 + (size_t)c*128);
    const float4* gv = (const float4*)g0;
    float a = 0.0f;
#pragma unroll
    for (int qq = 0; qq < 32; ++qq) a = fma4(wr[qq], gv[qq], a);
    g5[c] = fmaxf(a, 0.0f);
  }
  __syncthreads();
  {
    const float4* wr = (const float4*)(W1 + (size_t)t*512);
    const float4* gv = (const float4*)g5;
    float a = 0.0f;
    for (int qq = 0; qq < 128; ++qq) a = fma4(wr[qq], gv[qq], a);
    g2[t] = fmaxf(a, 0.0f);
  }
  __syncthreads();
  if (t < 40){
    const float4* wr = (const float4*)(Wc + (size_t)t*256);
    const float4* gv = (const float4*)g2;
    float a = 0.0f;
#pragma unroll
    for (int qq = 0; qq < 64; ++qq) a = fma4(wr[qq], gv[qq], a);
    out[(size_t)b*40 + t] = a + bc[t];
  }
}

extern "C" void kernel_launch(void* const* d_in, const int* in_sizes, int n_in,
                              void* d_out, int out_size, void* d_ws, size_t ws_size,
                              hipStream_t stream){
  (void)in_sizes; (void)n_in; (void)out_size; (void)ws_size;
  const float* points     = (const float*)d_in[0];
  const float* sa_w0      = (const float*)d_in[1];
  const float* sa_w1      = (const float*)d_in[2];
  const float* sa_w2      = (const float*)d_in[3];
  const float* t_ec_w0    = (const float*)d_in[4];
  const float* t_ec_w1    = (const float*)d_in[5];
  const float* t_local_w  = (const float*)d_in[6];
  const float* t_g_w0     = (const float*)d_in[7];
  const float* t_g_w1     = (const float*)d_in[8];
  const float* t_lin_w    = (const float*)d_in[9];
  const float* t_lin_b    = (const float*)d_in[10];
  const float* dg_ec_w0   = (const float*)d_in[11];
  const float* dg_ec_w1   = (const float*)d_in[12];
  const float* dg_ec_w2   = (const float*)d_in[13];
  const float* dg_local_w = (const float*)d_in[14];
  const float* dg_g_w0    = (const float*)d_in[15];
  const float* dg_g_w1    = (const float*)d_in[16];
  const float* cls_w      = (const float*)d_in[17];
  const float* cls_b      = (const float*)d_in[18];
  float* out = (float*)d_out;

  float* ws     = (float*)d_ws;
  float* xyz    = ws;                    // B*N*3          = 393216
  float* xnrm   = xyz    + 393216;       // B*N            = 131072
  float* nxyz   = xnrm   + 131072;       // B*256*3        = 24576
  float* feat   = nxyz   + 24576;        // B*256*128      = 1048576
  float* x131   = feat   + 1048576;      // B*256*132      = 1081344
  float* nrm    = x131   + 1081344;      // B*256          = 8192
  int*   idx    = (int*)(nrm + 8192);    // B*256*20       = 163840
  float* ht     = (float*)(idx + 163840);// B*256*128      = 1048576  (reused as f1)
  float* g1024v = ht     + 1048576;      // B*1024         = 32768
  float* f2     = g1024v + 32768;        // B*256*256      = 2097152
  float* f3     = f2     + 2097152;      // B*256*512      = 4194304
  float* g128v  = f3     + 4194304;      // B*128          = 4096
  float* wt_t0  = g128v  + 4096;         // 262*64         = 16768
  float* wt_t1  = wt_t0  + 16768;        // 64*128         = 8192
  float* wt_d0  = wt_t1  + 8192;         // 262*128        = 33536
  float* wt_d1  = wt_d0  + 33536;        // 256*256        = 65536
  float* wt_d2  = wt_d1  + 65536;        // 512*512        = 262144
  float* f1 = ht;
  float* xT = f3;                        // alias: xT lives in f3 until k_edgeL3 writes f3

  k_prep<<<512, 256, 0, stream>>>(points, xyz, xnrm);
  k_wt<<<(64*262+255)/256,  256, 0, stream>>>(t_ec_w0,  wt_t0, 64, 262);
  k_wt<<<(128*64+255)/256,  256, 0, stream>>>(t_ec_w1,  wt_t1, 128, 64);
  k_wt<<<(128*262+255)/256, 256, 0, stream>>>(dg_ec_w0, wt_d0, 128, 262);
  k_wt<<<(256*256+255)/256, 256, 0, stream>>>(dg_ec_w1, wt_d1, 256, 256);
  k_wt<<<(512*512+255)/256, 256, 0, stream>>>(dg_ec_w2, wt_d2, 512, 512);

  k_fps<<<BB, 256, 0, stream>>>(xyz, nxyz);
  k_sa<<<BB*NPp, 64, 0, stream>>>(xyz, xnrm, nxyz, sa_w0, sa_w1, sa_w2, feat, x131);

  // T-Net branch (x = [feat, new_xyz])
  k_xt<131><<<(BB*131*256+255)/256, 256, 0, stream>>>(x131, 132, xT);
  k_norm2<131><<<128, 64, 0, stream>>>(xT, nrm);
  k_knn3<131><<<1024, 512, 0, stream>>>(xT, nrm, idx);
  k_tedge2<<<BB*NPp, 128, 0, stream>>>(x131, idx, wt_t0, wt_t1, ht);
  k_tpool<<<dim3(BB, 8), 128, 0, stream>>>(ht, t_local_w, g1024v);
  k_trest<<<BB, 256, 0, stream>>>(g1024v, t_g_w0, t_g_w1, t_lin_w, t_lin_b, nxyz, x131);

  // DGCNN layer 1 (x = [feat, xyz_t], 131 dims)
  k_xt<131><<<(BB*131*256+255)/256, 256, 0, stream>>>(x131, 132, xT);
  k_norm2<131><<<128, 64, 0, stream>>>(xT, nrm);
  k_knn3<131><<<1024, 512, 0, stream>>>(xT, nrm, idx);
  k_edgeL1<<<1024, 512, 0, stream>>>(x131, idx, wt_d0, f1);
  // layer 2
  k_xt<128><<<(BB*128*256+255)/256, 256, 0, stream>>>(f1, 128, xT);
  k_norm2<128><<<128, 64, 0, stream>>>(xT, nrm);
  k_knn3<128><<<1024, 512, 0, stream>>>(xT, nrm, idx);
  k_edgeL2<<<1024, 512, 0, stream>>>(f1, idx, wt_d1, f2);
  // layer 3
  k_xt<256><<<(BB*256*256+255)/256, 256, 0, stream>>>(f2, 256, xT);
  k_norm2<256><<<128, 64, 0, stream>>>(xT, nrm);
  k_knn3<256><<<1024, 512, 0, stream>>>(xT, nrm, idx);
  k_edgeL3<<<2048, 512, 0, stream>>>(f2, idx, wt_d2, f3);

  // local conv + global pool + head
  k_zero<<<16, 256, 0, stream>>>(g128v, 4096);
  k_dgl<<<dim3(BB, 16), 128, 0, stream>>>(f1, f2, f3, dg_local_w, g128v);
  k_final<<<BB, 256, 0, stream>>>(g128v, dg_g_w0, dg_g_w1, cls_w, cls_b, out);
}

// Round 4
// 2093.061 us; speedup vs baseline: 2.9284x; 1.3395x over previous
//
#include <hip/hip_runtime.h>
#include <math.h>

#define BB 32
#define NN 4096
#define NPp 256
#define NSs 64
#define KC 20

__device__ __forceinline__ float fma4(const float4 w, const float4 v, float a){
  a = fmaf(w.x, v.x, a); a = fmaf(w.y, v.y, a);
  a = fmaf(w.z, v.z, a); a = fmaf(w.w, v.w, a); return a;
}
__device__ __forceinline__ float4 fma4s(const float4 w, float s, float4 a){
  a.x = fmaf(w.x, s, a.x); a.y = fmaf(w.y, s, a.y);
  a.z = fmaf(w.z, s, a.z); a.w = fmaf(w.w, s, a.w); return a;
}
__device__ __forceinline__ float4 max4(float4 a, float4 b){
  a.x = fmaxf(a.x, b.x); a.y = fmaxf(a.y, b.y);
  a.z = fmaxf(a.z, b.z); a.w = fmaxf(a.w, b.w); return a;
}
__device__ __forceinline__ float4 add4(float4 a, float4 b){
  a.x += b.x; a.y += b.y; a.z += b.z; a.w += b.w; return a;
}

// ---------------- weight transpose: WT[c*R + r] = W[r*C + c] ----------------
__global__ void k_wt(const float* __restrict__ W, float* __restrict__ WT, int R, int C){
  int i = blockIdx.x*256 + threadIdx.x;
  if (i >= R*C) return;
  int r = i % R, c = i / R;
  WT[(size_t)c*R + r] = W[(size_t)r*C + c];
}

// ---------------- split+transpose edge weights: wA[m][c]=Wb-Wd, wB[m][c]=Wd ----------------
__global__ void k_wab(const float* __restrict__ W, float* __restrict__ wA, float* __restrict__ wB,
                      int CIN, int COUT){
  int i = blockIdx.x*256 + threadIdx.x;
  if (i >= CIN*COUT) return;
  int m = i / COUT, c = i - m*COUT;
  float b = W[(size_t)c*(2*CIN) + m];
  float d = W[(size_t)c*(2*CIN) + CIN + m];
  wA[i] = __fsub_rn(b, d);
  wB[i] = d;
}

// ---------------- transpose + point norms ----------------
__global__ void k_prep(const float* __restrict__ pts, float* __restrict__ xyz, float* __restrict__ xnrm){
  int i = blockIdx.x*256 + threadIdx.x;
  if (i >= BB*NN) return;
  int b = i >> 12, n = i & (NN-1);
  float X = pts[(b*3+0)*NN + n];
  float Y = pts[(b*3+1)*NN + n];
  float Z = pts[(b*3+2)*NN + n];
  xyz[i*3+0]=X; xyz[i*3+1]=Y; xyz[i*3+2]=Z;
  xnrm[i] = __fadd_rn(__fadd_rn(__fmul_rn(X,X), __fmul_rn(Y,Y)), __fmul_rn(Z,Z));
}

// ---------------- farthest point sampling (1024 threads) ----------------
__global__ __launch_bounds__(1024) void k_fps(const float* __restrict__ xyz, float* __restrict__ new_xyz){
  __shared__ float xs[NN], ys[NN], zs[NN];
  __shared__ float rv[16];
  __shared__ int   ri[16];
  __shared__ int   slast;
  int b = blockIdx.x, t = threadIdx.x;
  for (int j = t; j < NN; j += 1024){
    const float* p = xyz + ((size_t)b*NN + j)*3;
    xs[j] = p[0]; ys[j] = p[1]; zs[j] = p[2];
  }
  float dist[4];
#pragma unroll
  for (int q = 0; q < 4; ++q) dist[q] = __builtin_inff();
  int last = 0;
  __syncthreads();
  for (int it = 0; it < NPp; ++it){
    if (t == 0){
      float* o = new_xyz + ((size_t)b*NPp + it)*3;
      o[0] = xs[last]; o[1] = ys[last]; o[2] = zs[last];
    }
    float px = xs[last], py = ys[last], pz = zs[last];
    float bv = -1.0f; int bj = 0;
#pragma unroll
    for (int q = 0; q < 4; ++q){
      int j = q*1024 + t;
      float dx = __fsub_rn(xs[j], px);
      float dy = __fsub_rn(ys[j], py);
      float dz = __fsub_rn(zs[j], pz);
      float dd = __fadd_rn(__fadd_rn(__fmul_rn(dx,dx), __fmul_rn(dy,dy)), __fmul_rn(dz,dz));
      float dm = fminf(dist[q], dd);
      dist[q] = dm;
      if (dm > bv){ bv = dm; bj = j; }
    }
#pragma unroll
    for (int off = 32; off >= 1; off >>= 1){
      float ov = __shfl_xor(bv, off, 64);
      int   oj = __shfl_xor(bj, off, 64);
      if (ov > bv || (ov == bv && oj < bj)){ bv = ov; bj = oj; }
    }
    if ((t & 63) == 0){ rv[t >> 6] = bv; ri[t >> 6] = bj; }
    __syncthreads();
    if (t == 0){
      float fv = rv[0]; int fj = ri[0];
      for (int ww = 1; ww < 16; ++ww)
        if (rv[ww] > fv || (rv[ww] == fv && ri[ww] < fj)){ fv = rv[ww]; fj = ri[ww]; }
      slast = fj;
    }
    __syncthreads();
    last = slast;
  }
}

// ---------------- ball query + SA convs + maxpool ----------------
__global__ __launch_bounds__(64) void k_sa(const float* __restrict__ xyz, const float* __restrict__ xnrm,
    const float* __restrict__ new_xyz, const float* __restrict__ w0, const float* __restrict__ w1,
    const float* __restrict__ w2, float* __restrict__ feat, float* __restrict__ x131){
  __shared__ __align__(16) float h1s[64*68];
  __shared__ int gix[64];
  int bi = blockIdx.x, lane = threadIdx.x;
  int b = bi >> 8;
  const float* q = new_xyz + (size_t)bi*3;
  float qx=q[0], qy=q[1], qz=q[2];
  float nq = __fadd_rn(__fadd_rn(__fmul_rn(qx,qx), __fmul_rn(qy,qy)), __fmul_rn(qz,qz));
  int cnt = 0;
  for (int base = 0; base < NN && cnt < NSs; base += 64){
    int j = base + lane;
    const float* p = xyz + ((size_t)b*NN + j)*3;
    float dot = __fadd_rn(__fadd_rn(__fmul_rn(qx,p[0]), __fmul_rn(qy,p[1])), __fmul_rn(qz,p[2]));
    float d2 = __fsub_rn(__fadd_rn(nq, xnrm[b*NN + j]), __fmul_rn(2.0f, dot));
    bool inb = d2 < 0.04f;
    unsigned long long m = __ballot(inb);
    int pos = cnt + (int)__popcll(m & ((1ull << lane) - 1ull));
    if (inb && pos < NSs) gix[pos] = j;
    cnt += (int)__popcll(m);
  }
  __syncthreads();
  int g0 = gix[0];
  if (lane >= cnt) gix[lane] = g0;
  __syncthreads();
  {
    int gj = gix[lane];
    const float* p = xyz + ((size_t)b*NN + gj)*3;
    float px = p[0]-qx, py = p[1]-qy, pz = p[2]-qz;
    float h0[64];
#pragma unroll
    for (int c = 0; c < 64; ++c){
      float a = fmaf(w0[c*3+2], pz, fmaf(w0[c*3+1], py, w0[c*3]*px));
      h0[c] = fmaxf(a, 0.0f);
    }
    for (int c = 0; c < 64; ++c){
      const float4* wr = (const float4*)(w1 + c*64);
      float a = 0.0f;
#pragma unroll
      for (int qq = 0; qq < 16; ++qq){
        float4 w = wr[qq];
        a = fmaf(w.x, h0[4*qq+0], a);
        a = fmaf(w.y, h0[4*qq+1], a);
        a = fmaf(w.z, h0[4*qq+2], a);
        a = fmaf(w.w, h0[4*qq+3], a);
      }
      h1s[lane*68 + c] = fmaxf(a, 0.0f);
    }
  }
  __syncthreads();
  float4 wa[16], wb[16];
#pragma unroll
  for (int qq = 0; qq < 16; ++qq){
    wa[qq] = *(const float4*)(w2 + (size_t)lane*64 + 4*qq);
    wb[qq] = *(const float4*)(w2 + (size_t)(lane+64)*64 + 4*qq);
  }
  float m0 = 0.0f, m1 = 0.0f;
  for (int s = 0; s < 64; s += 2){
    const float4* hr0 = (const float4*)(h1s + s*68);
    const float4* hr1 = (const float4*)(h1s + (s+1)*68);
    float a0 = 0.0f, a1 = 0.0f, a2 = 0.0f, a3 = 0.0f;
#pragma unroll
    for (int qq = 0; qq < 16; ++qq){
      float4 h0v = hr0[qq], h1v = hr1[qq];
      a0 = fma4(wa[qq], h0v, a0);
      a1 = fma4(wb[qq], h0v, a1);
      a2 = fma4(wa[qq], h1v, a2);
      a3 = fma4(wb[qq], h1v, a3);
    }
    m0 = fmaxf(fmaxf(m0, a0), a2); m1 = fmaxf(fmaxf(m1, a1), a3);
  }
  feat[(size_t)bi*128 + lane]      = m0;
  feat[(size_t)bi*128 + 64 + lane] = m1;
  x131[(size_t)bi*132 + lane]      = m0;
  x131[(size_t)bi*132 + 64 + lane] = m1;
  if (lane < 3) x131[(size_t)bi*132 + 128 + lane] = (lane==0)?qx:((lane==1)?qy:qz);
}

// ---------------- per-batch feature transpose: xT[b][m][256] ----------------
template<int CIN>
__global__ void k_xt(const float* __restrict__ x, int xstride, float* __restrict__ xT){
  int o = blockIdx.x*256 + threadIdx.x;
  if (o >= BB*CIN*256) return;
  int col = o & 255; int t1 = o >> 8; int m = t1 % CIN; int b = t1 / CIN;
  xT[o] = x[((size_t)(b*256+col))*xstride + m];
}

// ---------------- feature norms (from xT, coalesced) ----------------
template<int CIN>
__global__ void k_norm2(const float* __restrict__ xT, float* __restrict__ nrm){
  int p = blockIdx.x*64 + threadIdx.x;
  if (p >= BB*NPp) return;
  int b = p >> 8, col = p & 255;
  const float* base = xT + (size_t)b*CIN*256 + col;
  float a = 0.0f;
  for (int m = 0; m < CIN; ++m){
    float v = base[m*256];
    a = __fadd_rn(a, __fmul_rn(v, v));
  }
  nrm[p] = a;
}

// ---------------- kNN, 8 centroids/block, LDS-staged xT chunks ----------------
template<int CIN>
__global__ __launch_bounds__(512) void k_knn3(const float* __restrict__ xT,
    const float* __restrict__ nrm, int* __restrict__ idxo){
  __shared__ __align__(16) float sch[16*256];
  __shared__ __align__(16) float ds[8*256];
  int bi = blockIdx.x, t = threadIdx.x;
  int w = t >> 6, lane = t & 63;
  int b = bi >> 5;
  int coli = (bi & 31)*8 + w;
  const float* xb = xT + (size_t)b*CIN*256;
  float d0=0.f, d1=0.f, d2=0.f, d3=0.f;
  for (int m0 = 0; m0 < CIN; m0 += 16){
    int mc = (CIN - m0 < 16) ? (CIN - m0) : 16;
    for (int i = t; i < mc*64; i += 512){
      int mm = i >> 6, c4 = i & 63;
      *(float4*)(sch + mm*256 + c4*4) = *(const float4*)(xb + (size_t)(m0+mm)*256 + c4*4);
    }
    __syncthreads();
    for (int mm = 0; mm < mc; ++mm){
      float xm = sch[mm*256 + coli];
      float4 v = *(const float4*)(sch + mm*256 + 4*lane);
      d0 = fmaf(v.x, xm, d0); d1 = fmaf(v.y, xm, d1);
      d2 = fmaf(v.z, xm, d2); d3 = fmaf(v.w, xm, d3);
    }
    __syncthreads();
  }
  float ni = nrm[b*256 + coli];
  {
    int j0 = 4*lane;
    float4 dv;
    dv.x = __fsub_rn(__fadd_rn(ni, nrm[b*256 + j0+0]), __fmul_rn(2.0f, d0));
    dv.y = __fsub_rn(__fadd_rn(ni, nrm[b*256 + j0+1]), __fmul_rn(2.0f, d1));
    dv.z = __fsub_rn(__fadd_rn(ni, nrm[b*256 + j0+2]), __fmul_rn(2.0f, d2));
    dv.w = __fsub_rn(__fadd_rn(ni, nrm[b*256 + j0+3]), __fmul_rn(2.0f, d3));
    *(float4*)(ds + w*256 + j0) = dv;
  }
  __syncthreads();
  for (int r = 0; r < KC; ++r){
    float bv = 3.4e38f; int bj = NPp;
    float4 dv = *(const float4*)(ds + w*256 + 4*lane);
#pragma unroll
    for (int q = 0; q < 4; ++q){
      float v = (q==0)?dv.x:((q==1)?dv.y:((q==2)?dv.z:dv.w));
      int j = 4*lane + q;
      if (v < bv){ bv = v; bj = j; }
    }
#pragma unroll
    for (int off = 32; off >= 1; off >>= 1){
      float ov = __shfl_xor(bv, off, 64);
      int   oj = __shfl_xor(bj, off, 64);
      if (ov < bv || (ov == bv && oj < bj)){ bv = ov; bj = oj; }
    }
    if (lane == 0){ idxo[((size_t)b*256 + coli)*KC + r] = bj; ds[w*256 + bj] = 3.0e38f; }
    __syncthreads();
  }
}

// ---------------- per-point dual GEMM: A = wA^T x, B = wB^T x ----------------
// 16 points per block; wA/wB layout [CIN][COUT].
template<int CIN, int COUT, int T>
__global__ __launch_bounds__(T) void k_gab(const float* __restrict__ x, int xstride,
    const float* __restrict__ wA, const float* __restrict__ wB,
    float* __restrict__ A, float* __restrict__ B){
  constexpr int G   = COUT/4;   // col groups
  constexpr int RS  = T/G;      // row slots
  constexpr int RPT = 16/RS;    // rows per thread
  __shared__ float xsh[16*CIN];
  int bi = blockIdx.x, t = threadIdx.x;
  int g = t % G, rs = t / G;
  int i0 = bi*16;
  for (int i = t; i < 16*CIN; i += T){
    int r = i / CIN, m = i - r*CIN;
    xsh[r*CIN + m] = x[(size_t)(i0+r)*xstride + m];
  }
  __syncthreads();
  float4 accA[RPT], accB[RPT];
#pragma unroll
  for (int rr = 0; rr < RPT; ++rr){
    accA[rr] = make_float4(0.f,0.f,0.f,0.f);
    accB[rr] = make_float4(0.f,0.f,0.f,0.f);
  }
  for (int m = 0; m < CIN; ++m){
    float4 wa = *(const float4*)(wA + (size_t)m*COUT + 4*g);
    float4 wb = *(const float4*)(wB + (size_t)m*COUT + 4*g);
#pragma unroll
    for (int rr = 0; rr < RPT; ++rr){
      float xv = xsh[(rs + rr*RS)*CIN + m];
      accA[rr] = fma4s(wa, xv, accA[rr]);
      accB[rr] = fma4s(wb, xv, accB[rr]);
    }
  }
#pragma unroll
  for (int rr = 0; rr < RPT; ++rr){
    int r = i0 + rs + rr*RS;
    *(float4*)(A + (size_t)r*COUT + 4*g) = accA[rr];
    *(float4*)(B + (size_t)r*COUT + 4*g) = accB[rr];
  }
}

// ---------------- edge epilogue: out[i][c] = max_k relu(A[i][c] + B[j_ik][c]) ----------------
template<int COUT>
__global__ __launch_bounds__(256) void k_emax(const float* __restrict__ A, const float* __restrict__ Bm,
    const int* __restrict__ idx, float* __restrict__ out){
  constexpr int GT = COUT/4;     // threads per centroid
  constexpr int NC = 256/GT;     // centroids per block
  __shared__ int js[NC*KC];
  int bi = blockIdx.x, t = threadIdx.x;
  int li = t / GT, c4 = (t % GT)*4;
  int ci = bi*NC + li;
  int rb = (ci >> 8) << 8;
  if (t < NC*KC) js[t] = idx[(size_t)bi*NC*KC + t];
  __syncthreads();
  float4 a = *(const float4*)(A + (size_t)ci*COUT + c4);
  float4 p = make_float4(0.f,0.f,0.f,0.f);
#pragma unroll
  for (int k = 0; k < KC; ++k){
    int j = js[li*KC + k];
    float4 b = *(const float4*)(Bm + (size_t)(rb + j)*COUT + c4);
    p = max4(p, add4(a, b));
  }
  *(float4*)(out + (size_t)ci*COUT + c4) = p;
}

// ---------------- T-Net edge: h0 = relu(A0+B0) then 64->128 conv + k-maxpool ----------------
__global__ __launch_bounds__(128) void k_tedge3(const float* __restrict__ A0, const float* __restrict__ B0,
    const int* __restrict__ idx, const float* __restrict__ wt1, float* __restrict__ out){
  __shared__ __align__(16) float h0s[20*68];
  __shared__ __align__(16) float smax[4*128];
  __shared__ int js[KC];
  int bi = blockIdx.x, t = threadIdx.x;
  int cg = t & 31, kg = t >> 5, k0 = kg*5;
  int rb = (bi >> 8) << 8;
  if (t < KC) js[t] = idx[(size_t)bi*KC + t];
  __syncthreads();
  for (int i = t; i < 20*64; i += 128){
    int k = i >> 6, c = i & 63;
    float v = A0[(size_t)bi*64 + c] + B0[(size_t)(rb + js[k])*64 + c];
    h0s[k*68 + c] = fmaxf(v, 0.0f);
  }
  __syncthreads();
  float4 b2[5];
#pragma unroll
  for (int kk = 0; kk < 5; ++kk) b2[kk] = make_float4(0.f,0.f,0.f,0.f);
  for (int m4 = 0; m4 < 16; ++m4){
    float4 e[5];
#pragma unroll
    for (int kk = 0; kk < 5; ++kk) e[kk] = *(const float4*)(h0s + (k0+kk)*68 + 4*m4);
#pragma unroll
    for (int mm = 0; mm < 4; ++mm){
      float4 w = *(const float4*)(wt1 + (4*m4+mm)*128 + 4*cg);
#pragma unroll
      for (int kk = 0; kk < 5; ++kk){
        float ev = (mm==0)?e[kk].x:((mm==1)?e[kk].y:((mm==2)?e[kk].z:e[kk].w));
        b2[kk] = fma4s(w, ev, b2[kk]);
      }
    }
  }
  float4 p = make_float4(0.f,0.f,0.f,0.f);
#pragma unroll
  for (int kk = 0; kk < 5; ++kk) p = max4(p, b2[kk]);
  *(float4*)(smax + kg*128 + 4*cg) = p;
  __syncthreads();
  if (kg == 0){
    float4 r = *(const float4*)(smax + 4*cg);
#pragma unroll
    for (int g = 1; g < 4; ++g) r = max4(r, *(const float4*)(smax + g*128 + 4*cg));
    *(float4*)(out + (size_t)bi*128 + 4*cg) = r;
  }
}

// ---------------- T-Net 128->1024 + pool over points ----------------
__global__ __launch_bounds__(128) void k_tpool(const float* __restrict__ h, const float* __restrict__ W,
    float* __restrict__ g1024){
  int b = blockIdx.x, t = threadIdx.x;
  int c = blockIdx.y*128 + t;
  float4 w[32];
#pragma unroll
  for (int qq = 0; qq < 32; ++qq) w[qq] = *(const float4*)(W + (size_t)c*128 + 4*qq);
  const float* hb = h + (size_t)b*NPp*128;
  float mx = 0.0f;
  for (int i = 0; i < NPp; ++i){
    const float4* hr = (const float4*)(hb + (size_t)i*128);
    float a = 0.0f;
#pragma unroll
    for (int qq = 0; qq < 32; ++qq) a = fma4(w[qq], hr[qq], a);
    mx = fmaxf(mx, a);
  }
  g1024[(size_t)b*1024 + c] = mx;
}

// ---------------- T-Net MLP + 3x3 transform applied to new_xyz ----------------
__global__ __launch_bounds__(256) void k_trest(const float* __restrict__ g1024,
    const float* __restrict__ Wg0, const float* __restrict__ Wg1,
    const float* __restrict__ Wl, const float* __restrict__ bl,
    const float* __restrict__ new_xyz, float* __restrict__ x131){
  __shared__ __align__(16) float g1[1024];
  __shared__ __align__(16) float g5[512];
  __shared__ __align__(16) float g2[256];
  __shared__ float tm[12];
  int b = blockIdx.x, t = threadIdx.x;
  for (int m = t; m < 1024; m += 256) g1[m] = g1024[(size_t)b*1024 + m];
  __syncthreads();
#pragma unroll
  for (int cc = 0; cc < 2; ++cc){
    int c = t + cc*256;
    const float4* wr = (const float4*)(Wg0 + (size_t)c*1024);
    const float4* gv = (const float4*)g1;
    float a = 0.0f;
    for (int qq = 0; qq < 256; ++qq) a = fma4(wr[qq], gv[qq], a);
    g5[c] = fmaxf(a, 0.0f);
  }
  __syncthreads();
  {
    const float4* wr = (const float4*)(Wg1 + (size_t)t*512);
    const float4* gv = (const float4*)g5;
    float a = 0.0f;
    for (int qq = 0; qq < 128; ++qq) a = fma4(wr[qq], gv[qq], a);
    g2[t] = fmaxf(a, 0.0f);
  }
  __syncthreads();
  if (t < 9){
    const float4* wr = (const float4*)(Wl + (size_t)t*256);
    const float4* gv = (const float4*)g2;
    float a = 0.0f;
#pragma unroll
    for (int qq = 0; qq < 64; ++qq) a = fma4(wr[qq], gv[qq], a);
    a += bl[t];
    if (t == 0 || t == 4 || t == 8) a += 1.0f;
    tm[t] = a;
  }
  __syncthreads();
  {
    const float* nx = new_xyz + ((size_t)b*NPp + t)*3;
    float X = nx[0], Y = nx[1], Z = nx[2];
#pragma unroll
    for (int i = 0; i < 3; ++i){
      float v = __fadd_rn(__fadd_rn(__fmul_rn(tm[i*3+0], X), __fmul_rn(tm[i*3+1], Y)), __fmul_rn(tm[i*3+2], Z));
      x131[((size_t)b*NPp + t)*132 + 128 + i] = v;
    }
  }
}

// ---------------- zero scratch ----------------
__global__ void k_zero(float* p, int n){
  int i = blockIdx.x*256 + threadIdx.x;
  if (i < n) p[i] = 0.0f;
}

// ---------------- 896->128 conv + global max pool (atomic) ----------------
__global__ __launch_bounds__(128) void k_dgl(const float* __restrict__ f1, const float* __restrict__ f2,
    const float* __restrict__ f3, const float* __restrict__ W, float* __restrict__ g128){
  int b = blockIdx.x, t = threadIdx.x;
  int i0 = blockIdx.y * 16;
  const float* wr = W + (size_t)t*896;
  float acc[16];
#pragma unroll
  for (int ii = 0; ii < 16; ++ii) acc[ii] = 0.0f;
  for (int q = 0; q < 32; ++q){
    float4 w = *(const float4*)(wr + 4*q);
#pragma unroll
    for (int ii = 0; ii < 16; ++ii){
      float4 v = *(const float4*)(f1 + ((size_t)b*NPp + i0 + ii)*128 + 4*q);
      acc[ii] = fma4(w, v, acc[ii]);
    }
  }
  for (int q = 0; q < 64; ++q){
    float4 w = *(const float4*)(wr + 128 + 4*q);
#pragma unroll
    for (int ii = 0; ii < 16; ++ii){
      float4 v = *(const float4*)(f2 + ((size_t)b*NPp + i0 + ii)*256 + 4*q);
      acc[ii] = fma4(w, v, acc[ii]);
    }
  }
  for (int q = 0; q < 128; ++q){
    float4 w = *(const float4*)(wr + 384 + 4*q);
#pragma unroll
    for (int ii = 0; ii < 16; ++ii){
      float4 v = *(const float4*)(f3 + ((size_t)b*NPp + i0 + ii)*512 + 4*q);
      acc[ii] = fma4(w, v, acc[ii]);
    }
  }
#pragma unroll
  for (int ii = 0; ii < 16; ++ii){
    float v = fmaxf(acc[ii], 0.0f);
    atomicMax((int*)(g128 + (size_t)b*128 + t), __float_as_int(v));
  }
}

// ---------------- classifier head ----------------
__global__ __launch_bounds__(256) void k_final(const float* __restrict__ g128,
    const float* __restrict__ W0, const float* __restrict__ W1,
    const float* __restrict__ Wc, const float* __restrict__ bc, float* __restrict__ out){
  __shared__ __align__(16) float g0[128];
  __shared__ __align__(16) float g5[512];
  __shared__ __align__(16) float g2[256];
  int b = blockIdx.x, t = threadIdx.x;
  if (t < 128) g0[t] = g128[(size_t)b*128 + t];
  __syncthreads();
#pragma unroll
  for (int cc = 0; cc < 2; ++cc){
    int c = t + cc*256;
    const float4* wr = (const float4*)(W0 + (size_t)c*128);
    const float4* gv = (const float4*)g0;
    float a = 0.0f;
#pragma unroll
    for (int qq = 0; qq < 32; ++qq) a = fma4(wr[qq], gv[qq], a);
    g5[c] = fmaxf(a, 0.0f);
  }
  __syncthreads();
  {
    const float4* wr = (const float4*)(W1 + (size_t)t*512);
    const float4* gv = (const float4*)g5;
    float a = 0.0f;
    for (int qq = 0; qq < 128; ++qq) a = fma4(wr[qq], gv[qq], a);
    g2[t] = fmaxf(a, 0.0f);
  }
  __syncthreads();
  if (t < 40){
    const float4* wr = (const float4*)(Wc + (size_t)t*256);
    const float4* gv = (const float4*)g2;
    float a = 0.0f;
#pragma unroll
    for (int qq = 0; qq < 64; ++qq) a = fma4(wr[qq], gv[qq], a);
    out[(size_t)b*40 + t] = a + bc[t];
  }
}

extern "C" void kernel_launch(void* const* d_in, const int* in_sizes, int n_in,
                              void* d_out, int out_size, void* d_ws, size_t ws_size,
                              hipStream_t stream){
  (void)in_sizes; (void)n_in; (void)out_size; (void)ws_size;
  const float* points     = (const float*)d_in[0];
  const float* sa_w0      = (const float*)d_in[1];
  const float* sa_w1      = (const float*)d_in[2];
  const float* sa_w2      = (const float*)d_in[3];
  const float* t_ec_w0    = (const float*)d_in[4];
  const float* t_ec_w1    = (const float*)d_in[5];
  const float* t_local_w  = (const float*)d_in[6];
  const float* t_g_w0     = (const float*)d_in[7];
  const float* t_g_w1     = (const float*)d_in[8];
  const float* t_lin_w    = (const float*)d_in[9];
  const float* t_lin_b    = (const float*)d_in[10];
  const float* dg_ec_w0   = (const float*)d_in[11];
  const float* dg_ec_w1   = (const float*)d_in[12];
  const float* dg_ec_w2   = (const float*)d_in[13];
  const float* dg_local_w = (const float*)d_in[14];
  const float* dg_g_w0    = (const float*)d_in[15];
  const float* dg_g_w1    = (const float*)d_in[16];
  const float* cls_w      = (const float*)d_in[17];
  const float* cls_b      = (const float*)d_in[18];
  float* out = (float*)d_out;

  float* ws     = (float*)d_ws;
  float* xyz    = ws;                    // 393216
  float* xnrm   = xyz    + 393216;       // 131072
  float* nxyz   = xnrm   + 131072;       // 24576
  float* feat   = nxyz   + 24576;        // 1048576
  float* x131   = feat   + 1048576;      // 1081344
  float* nrm    = x131   + 1081344;      // 8192
  int*   idx    = (int*)(nrm + 8192);    // 163840
  float* ht     = (float*)(idx + 163840);// 1048576 (reused as f1)
  float* g1024v = ht     + 1048576;      // 32768
  float* f2     = g1024v + 32768;        // 2097152
  float* f3     = f2     + 2097152;      // 4194304
  float* g128v  = f3     + 4194304;      // 4096
  float* wt_t1  = g128v  + 4096;         // 8192   (64x128)
  float* waT0   = wt_t1  + 8192;         // 8384   (131x64)
  float* wbT0   = waT0   + 8384;         // 8384
  float* waD0   = wbT0   + 8384;         // 16768  (131x128)
  float* wbD0   = waD0   + 16768;        // 16768
  float* waD1   = wbD0   + 16768;        // 32768  (128x256)
  float* wbD1   = waD1   + 32768;        // 32768
  float* waD2   = wbD1   + 32768;        // 131072 (256x512)
  float* wbD2   = waD2   + 131072;       // 131072
  float* Ab     = wbD2   + 131072;       // 4194304
  float* Bb     = Ab     + 4194304;      // 4194304
  float* f1 = ht;
  float* xT = f3;                        // alias: xT lives in f3 until k_emax<512> writes f3

  k_prep<<<512, 256, 0, stream>>>(points, xyz, xnrm);
  k_wab<<<(131*64+255)/256,  256, 0, stream>>>(t_ec_w0,  waT0, wbT0, 131, 64);
  k_wt <<<(128*64+255)/256,  256, 0, stream>>>(t_ec_w1,  wt_t1, 128, 64);
  k_wab<<<(131*128+255)/256, 256, 0, stream>>>(dg_ec_w0, waD0, wbD0, 131, 128);
  k_wab<<<(128*256+255)/256, 256, 0, stream>>>(dg_ec_w1, waD1, wbD1, 128, 256);
  k_wab<<<(256*512+255)/256, 256, 0, stream>>>(dg_ec_w2, waD2, wbD2, 256, 512);

  k_fps<<<BB, 1024, 0, stream>>>(xyz, nxyz);
  k_sa<<<BB*NPp, 64, 0, stream>>>(xyz, xnrm, nxyz, sa_w0, sa_w1, sa_w2, feat, x131);

  // T-Net branch (x = [feat, new_xyz])
  k_xt<131><<<(BB*131*256+255)/256, 256, 0, stream>>>(x131, 132, xT);
  k_norm2<131><<<128, 64, 0, stream>>>(xT, nrm);
  k_knn3<131><<<1024, 512, 0, stream>>>(xT, nrm, idx);
  k_gab<131,64,256><<<512, 256, 0, stream>>>(x131, 132, waT0, wbT0, Ab, Bb);
  k_tedge3<<<BB*NPp, 128, 0, stream>>>(Ab, Bb, idx, wt_t1, ht);
  k_tpool<<<dim3(BB, 8), 128, 0, stream>>>(ht, t_local_w, g1024v);
  k_trest<<<BB, 256, 0, stream>>>(g1024v, t_g_w0, t_g_w1, t_lin_w, t_lin_b, nxyz, x131);

  // DGCNN layer 1 (x = [feat, xyz_t], 131 dims)
  k_xt<131><<<(BB*131*256+255)/256, 256, 0, stream>>>(x131, 132, xT);
  k_norm2<131><<<128, 64, 0, stream>>>(xT, nrm);
  k_knn3<131><<<1024, 512, 0, stream>>>(xT, nrm, idx);
  k_gab<131,128,512><<<512, 512, 0, stream>>>(x131, 132, waD0, wbD0, Ab, Bb);
  k_emax<128><<<1024, 256, 0, stream>>>(Ab, Bb, idx, f1);
  // layer 2
  k_xt<128><<<(BB*128*256+255)/256, 256, 0, stream>>>(f1, 128, xT);
  k_norm2<128><<<128, 64, 0, stream>>>(xT, nrm);
  k_knn3<128><<<1024, 512, 0, stream>>>(xT, nrm, idx);
  k_gab<128,256,512><<<512, 512, 0, stream>>>(f1, 128, waD1, wbD1, Ab, Bb);
  k_emax<256><<<2048, 256, 0, stream>>>(Ab, Bb, idx, f2);
  // layer 3
  k_xt<256><<<(BB*256*256+255)/256, 256, 0, stream>>>(f2, 256, xT);
  k_norm2<256><<<128, 64, 0, stream>>>(xT, nrm);
  k_knn3<256><<<1024, 512, 0, stream>>>(xT, nrm, idx);
  k_gab<256,512,512><<<512, 512, 0, stream>>>(f2, 256, waD2, wbD2, Ab, Bb);
  k_emax<512><<<4096, 256, 0, stream>>>(Ab, Bb, idx, f3);

  // local conv + global pool + head
  k_zero<<<16, 256, 0, stream>>>(g128v, 4096);
  k_dgl<<<dim3(BB, 16), 128, 0, stream>>>(f1, f2, f3, dg_local_w, g128v);
  k_final<<<BB, 256, 0, stream>>>(g128v, dg_g_w0, dg_g_w1, cls_w, cls_b, out);
}

// Round 5
// 1780.044 us; speedup vs baseline: 3.4434x; 1.1758x over previous
//
#include <hip/hip_runtime.h>
#include <math.h>

#define BB 32
#define NN 4096
#define NPp 256
#define NSs 64
#define KC 20

__device__ __forceinline__ float fma4(const float4 w, const float4 v, float a){
  a = fmaf(w.x, v.x, a); a = fmaf(w.y, v.y, a);
  a = fmaf(w.z, v.z, a); a = fmaf(w.w, v.w, a); return a;
}
__device__ __forceinline__ float4 fma4s(const float4 w, float s, float4 a){
  a.x = fmaf(w.x, s, a.x); a.y = fmaf(w.y, s, a.y);
  a.z = fmaf(w.z, s, a.z); a.w = fmaf(w.w, s, a.w); return a;
}
__device__ __forceinline__ float4 max4(float4 a, float4 b){
  a.x = fmaxf(a.x, b.x); a.y = fmaxf(a.y, b.y);
  a.z = fmaxf(a.z, b.z); a.w = fmaxf(a.w, b.w); return a;
}
__device__ __forceinline__ float4 add4(float4 a, float4 b){
  a.x += b.x; a.y += b.y; a.z += b.z; a.w += b.w; return a;
}

// ---------------- unified weight prep (all transposes/splits in one kernel) ----------------
__global__ void k_wprep(const float* __restrict__ t0, const float* __restrict__ t1,
                        const float* __restrict__ d0, const float* __restrict__ d1,
                        const float* __restrict__ d2,
                        float* __restrict__ waT0, float* __restrict__ wbT0,
                        float* __restrict__ wt_t1,
                        float* __restrict__ waD0, float* __restrict__ wbD0,
                        float* __restrict__ waD1, float* __restrict__ wbD1,
                        float* __restrict__ waD2, float* __restrict__ wbD2){
  int i = blockIdx.x*256 + threadIdx.x;
  if (i < 8384){                       // t_ec_w0: [64][262] -> A/B [131][64]
    int m = i >> 6;
    int c = i & 63;
    float bb = t0[(size_t)c*262 + m];
    float dd = t0[(size_t)c*262 + 131 + m];
    waT0[i] = __fsub_rn(bb, dd); wbT0[i] = dd;
    return;
  }
  i -= 8384;
  if (i < 8192){                       // t_ec_w1: [128][64] -> [64][128]
    int m = i >> 7, c = i & 127;
    wt_t1[i] = t1[(size_t)c*64 + m];
    return;
  }
  i -= 8192;
  if (i < 16768){                      // dg_ec_w0: [128][262] -> A/B [131][128]
    int m = i >> 7, c = i & 127;
    float bb = d0[(size_t)c*262 + m];
    float dd = d0[(size_t)c*262 + 131 + m];
    waD0[i] = __fsub_rn(bb, dd); wbD0[i] = dd;
    return;
  }
  i -= 16768;
  if (i < 32768){                      // dg_ec_w1: [256][256] -> A/B [128][256]
    int m = i >> 8, c = i & 255;
    float bb = d1[(size_t)c*256 + m];
    float dd = d1[(size_t)c*256 + 128 + m];
    waD1[i] = __fsub_rn(bb, dd); wbD1[i] = dd;
    return;
  }
  i -= 32768;
  if (i < 131072){                     // dg_ec_w2: [512][512] -> A/B [256][512]
    int m = i >> 9, c = i & 511;
    float bb = d2[(size_t)c*512 + m];
    float dd = d2[(size_t)c*512 + 256 + m];
    waD2[i] = __fsub_rn(bb, dd); wbD2[i] = dd;
  }
}

// ---------------- transpose + point norms ----------------
__global__ void k_prep(const float* __restrict__ pts, float* __restrict__ xyz, float* __restrict__ xnrm){
  int i = blockIdx.x*256 + threadIdx.x;
  if (i >= BB*NN) return;
  int b = i >> 12, n = i & (NN-1);
  float X = pts[(b*3+0)*NN + n];
  float Y = pts[(b*3+1)*NN + n];
  float Z = pts[(b*3+2)*NN + n];
  xyz[i*3+0]=X; xyz[i*3+1]=Y; xyz[i*3+2]=Z;
  xnrm[i] = __fadd_rn(__fadd_rn(__fmul_rn(X,X), __fmul_rn(Y,Y)), __fmul_rn(Z,Z));
}

// ---------------- farthest point sampling: 256 thr, 1 barrier/iter ----------------
__global__ __launch_bounds__(256) void k_fps(const float* __restrict__ xyz, float* __restrict__ new_xyz){
  __shared__ __align__(16) float pts[NN*4];  // float4-packed, 64 KB
  __shared__ float rv[2][4];
  __shared__ int   ri[2][4];
  int b = blockIdx.x, t = threadIdx.x;
  int w = t >> 6, lane = t & 63;
  for (int j = t; j < NN; j += 256){
    const float* p = xyz + ((size_t)b*NN + j)*3;
    float4 v = make_float4(p[0], p[1], p[2], 0.0f);
    *(float4*)(pts + 4*j) = v;
  }
  float dist[16];
#pragma unroll
  for (int q = 0; q < 16; ++q) dist[q] = __builtin_inff();
  int last = 0;
  __syncthreads();
  for (int it = 0; it < NPp; ++it){
    float4 P = *(const float4*)(pts + 4*last);   // broadcast read
    if (t == 0){
      float* o = new_xyz + ((size_t)b*NPp + it)*3;
      o[0] = P.x; o[1] = P.y; o[2] = P.z;
    }
    float bv = -1.0f; int bj = 0;
#pragma unroll
    for (int q = 0; q < 16; ++q){
      int j = q*256 + t;
      float4 v = *(const float4*)(pts + 4*j);
      float dx = __fsub_rn(v.x, P.x);
      float dy = __fsub_rn(v.y, P.y);
      float dz = __fsub_rn(v.z, P.z);
      float dd = __fadd_rn(__fadd_rn(__fmul_rn(dx,dx), __fmul_rn(dy,dy)), __fmul_rn(dz,dz));
      float dm = fminf(dist[q], dd);
      dist[q] = dm;
      if (dm > bv){ bv = dm; bj = j; }
    }
#pragma unroll
    for (int off = 32; off >= 1; off >>= 1){
      float ov = __shfl_xor(bv, off, 64);
      int   oj = __shfl_xor(bj, off, 64);
      if (ov > bv || (ov == bv && oj < bj)){ bv = ov; bj = oj; }
    }
    int par = it & 1;
    if (lane == 0){ rv[par][w] = bv; ri[par][w] = bj; }
    __syncthreads();
    // all threads redundantly reduce the 4 partials (no 2nd barrier: double-buffered)
    float fv = rv[par][0]; int fj = ri[par][0];
#pragma unroll
    for (int ww = 1; ww < 4; ++ww){
      float ov = rv[par][ww]; int oj = ri[par][ww];
      if (ov > fv || (ov == fv && oj < fj)){ fv = ov; fj = oj; }
    }
    last = fj;
  }
}

// ---------------- ball query + SA convs + maxpool ----------------
__global__ __launch_bounds__(64) void k_sa(const float* __restrict__ xyz, const float* __restrict__ xnrm,
    const float* __restrict__ new_xyz, const float* __restrict__ w0, const float* __restrict__ w1,
    const float* __restrict__ w2, float* __restrict__ feat, float* __restrict__ x131){
  __shared__ __align__(16) float h1s[64*68];
  __shared__ int gix[64];
  int bi = blockIdx.x, lane = threadIdx.x;
  int b = bi >> 8;
  const float* q = new_xyz + (size_t)bi*3;
  float qx=q[0], qy=q[1], qz=q[2];
  float nq = __fadd_rn(__fadd_rn(__fmul_rn(qx,qx), __fmul_rn(qy,qy)), __fmul_rn(qz,qz));
  int cnt = 0;
  for (int base = 0; base < NN && cnt < NSs; base += 64){
    int j = base + lane;
    const float* p = xyz + ((size_t)b*NN + j)*3;
    float dot = __fadd_rn(__fadd_rn(__fmul_rn(qx,p[0]), __fmul_rn(qy,p[1])), __fmul_rn(qz,p[2]));
    float d2 = __fsub_rn(__fadd_rn(nq, xnrm[b*NN + j]), __fmul_rn(2.0f, dot));
    bool inb = d2 < 0.04f;
    unsigned long long m = __ballot(inb);
    int pos = cnt + (int)__popcll(m & ((1ull << lane) - 1ull));
    if (inb && pos < NSs) gix[pos] = j;
    cnt += (int)__popcll(m);
  }
  __syncthreads();
  int g0 = gix[0];
  if (lane >= cnt) gix[lane] = g0;
  __syncthreads();
  {
    int gj = gix[lane];
    const float* p = xyz + ((size_t)b*NN + gj)*3;
    float px = p[0]-qx, py = p[1]-qy, pz = p[2]-qz;
    float h0[64];
#pragma unroll
    for (int c = 0; c < 64; ++c){
      float a = fmaf(w0[c*3+2], pz, fmaf(w0[c*3+1], py, w0[c*3]*px));
      h0[c] = fmaxf(a, 0.0f);
    }
    for (int c = 0; c < 64; ++c){
      const float4* wr = (const float4*)(w1 + c*64);
      float a = 0.0f;
#pragma unroll
      for (int qq = 0; qq < 16; ++qq){
        float4 w = wr[qq];
        a = fmaf(w.x, h0[4*qq+0], a);
        a = fmaf(w.y, h0[4*qq+1], a);
        a = fmaf(w.z, h0[4*qq+2], a);
        a = fmaf(w.w, h0[4*qq+3], a);
      }
      h1s[lane*68 + c] = fmaxf(a, 0.0f);
    }
  }
  __syncthreads();
  float4 wa[16], wb[16];
#pragma unroll
  for (int qq = 0; qq < 16; ++qq){
    wa[qq] = *(const float4*)(w2 + (size_t)lane*64 + 4*qq);
    wb[qq] = *(const float4*)(w2 + (size_t)(lane+64)*64 + 4*qq);
  }
  float m0 = 0.0f, m1 = 0.0f;
  for (int s = 0; s < 64; s += 2){
    const float4* hr0 = (const float4*)(h1s + s*68);
    const float4* hr1 = (const float4*)(h1s + (s+1)*68);
    float a0 = 0.0f, a1 = 0.0f, a2 = 0.0f, a3 = 0.0f;
#pragma unroll
    for (int qq = 0; qq < 16; ++qq){
      float4 h0v = hr0[qq], h1v = hr1[qq];
      a0 = fma4(wa[qq], h0v, a0);
      a1 = fma4(wb[qq], h0v, a1);
      a2 = fma4(wa[qq], h1v, a2);
      a3 = fma4(wb[qq], h1v, a3);
    }
    m0 = fmaxf(fmaxf(m0, a0), a2); m1 = fmaxf(fmaxf(m1, a1), a3);
  }
  feat[(size_t)bi*128 + lane]      = m0;
  feat[(size_t)bi*128 + 64 + lane] = m1;
  x131[(size_t)bi*132 + lane]      = m0;
  x131[(size_t)bi*132 + 64 + lane] = m1;
  if (lane < 3) x131[(size_t)bi*132 + 128 + lane] = (lane==0)?qx:((lane==1)?qy:qz);
}

// ---------------- feature norms (from xT, coalesced) ----------------
template<int CIN>
__global__ void k_norm2(const float* __restrict__ xT, float* __restrict__ nrm){
  int p = blockIdx.x*64 + threadIdx.x;
  if (p >= BB*NPp) return;
  int b = p >> 8, col = p & 255;
  const float* base = xT + (size_t)b*CIN*256 + col;
  float a = 0.0f;
  for (int m = 0; m < CIN; ++m){
    float v = base[m*256];
    a = __fadd_rn(a, __fmul_rn(v, v));
  }
  nrm[p] = a;
}

// ---------------- kNN, 8 centroids/block, LDS-staged xT chunks ----------------
template<int CIN>
__global__ __launch_bounds__(512) void k_knn3(const float* __restrict__ xT,
    const float* __restrict__ nrm, int* __restrict__ idxo){
  __shared__ __align__(16) float sch[16*256];
  __shared__ __align__(16) float ds[8*256];
  int bi = blockIdx.x, t = threadIdx.x;
  int w = t >> 6, lane = t & 63;
  int b = bi >> 5;
  int coli = (bi & 31)*8 + w;
  const float* xb = xT + (size_t)b*CIN*256;
  float d0=0.f, d1=0.f, d2=0.f, d3=0.f;
  for (int m0 = 0; m0 < CIN; m0 += 16){
    int mc = (CIN - m0 < 16) ? (CIN - m0) : 16;
    for (int i = t; i < mc*64; i += 512){
      int mm = i >> 6, c4 = i & 63;
      *(float4*)(sch + mm*256 + c4*4) = *(const float4*)(xb + (size_t)(m0+mm)*256 + c4*4);
    }
    __syncthreads();
    for (int mm = 0; mm < mc; ++mm){
      float xm = sch[mm*256 + coli];
      float4 v = *(const float4*)(sch + mm*256 + 4*lane);
      d0 = fmaf(v.x, xm, d0); d1 = fmaf(v.y, xm, d1);
      d2 = fmaf(v.z, xm, d2); d3 = fmaf(v.w, xm, d3);
    }
    __syncthreads();
  }
  float ni = nrm[b*256 + coli];
  {
    int j0 = 4*lane;
    float4 dv;
    dv.x = __fsub_rn(__fadd_rn(ni, nrm[b*256 + j0+0]), __fmul_rn(2.0f, d0));
    dv.y = __fsub_rn(__fadd_rn(ni, nrm[b*256 + j0+1]), __fmul_rn(2.0f, d1));
    dv.z = __fsub_rn(__fadd_rn(ni, nrm[b*256 + j0+2]), __fmul_rn(2.0f, d2));
    dv.w = __fsub_rn(__fadd_rn(ni, nrm[b*256 + j0+3]), __fmul_rn(2.0f, d3));
    *(float4*)(ds + w*256 + j0) = dv;
  }
  __syncthreads();
  for (int r = 0; r < KC; ++r){
    float bv = 3.4e38f; int bj = NPp;
    float4 dv = *(const float4*)(ds + w*256 + 4*lane);
#pragma unroll
    for (int q = 0; q < 4; ++q){
      float v = (q==0)?dv.x:((q==1)?dv.y:((q==2)?dv.z:dv.w));
      int j = 4*lane + q;
      if (v < bv){ bv = v; bj = j; }
    }
#pragma unroll
    for (int off = 32; off >= 1; off >>= 1){
      float ov = __shfl_xor(bv, off, 64);
      int   oj = __shfl_xor(bj, off, 64);
      if (ov < bv || (ov == bv && oj < bj)){ bv = ov; bj = oj; }
    }
    if (lane == 0){ idxo[((size_t)b*256 + coli)*KC + r] = bj; ds[w*256 + bj] = 3.0e38f; }
    __syncthreads();
  }
}

// ---------------- per-point dual GEMM + fused xT transpose ----------------
// 16 points per block; wA/wB layout [CIN][COUT]; also writes xT[b][m][256].
template<int CIN, int COUT, int T>
__global__ __launch_bounds__(T) void k_gab(const float* __restrict__ x, int xstride,
    const float* __restrict__ wA, const float* __restrict__ wB,
    float* __restrict__ A, float* __restrict__ B, float* __restrict__ xT){
  constexpr int PC  = CIN + 1;  // padded LDS stride (conflict-free transpose read)
  constexpr int G   = COUT/4;
  constexpr int RS  = T/G;
  constexpr int RPT = 16/RS;
  __shared__ float xsh[16*PC];
  int bi = blockIdx.x, t = threadIdx.x;
  int g = t % G, rs = t / G;
  int i0 = bi*16;
  for (int i = t; i < 16*CIN; i += T){
    int r = i / CIN, m = i - r*CIN;
    xsh[r*PC + m] = x[(size_t)(i0+r)*xstride + m];
  }
  __syncthreads();
  // fused transpose write: xT[b][m][col]
  {
    int bb = i0 >> 8, col0 = i0 & 255;
    float* xTb = xT + (size_t)bb*CIN*256 + col0;
    for (int i = t; i < 16*CIN; i += T){
      int m = i >> 4, r = i & 15;
      xTb[m*256 + r] = xsh[r*PC + m];
    }
  }
  float4 accA[RPT], accB[RPT];
#pragma unroll
  for (int rr = 0; rr < RPT; ++rr){
    accA[rr] = make_float4(0.f,0.f,0.f,0.f);
    accB[rr] = make_float4(0.f,0.f,0.f,0.f);
  }
  for (int m = 0; m < CIN; ++m){
    float4 wa = *(const float4*)(wA + (size_t)m*COUT + 4*g);
    float4 wb = *(const float4*)(wB + (size_t)m*COUT + 4*g);
#pragma unroll
    for (int rr = 0; rr < RPT; ++rr){
      float xv = xsh[(rs + rr*RS)*PC + m];
      accA[rr] = fma4s(wa, xv, accA[rr]);
      accB[rr] = fma4s(wb, xv, accB[rr]);
    }
  }
#pragma unroll
  for (int rr = 0; rr < RPT; ++rr){
    int r = i0 + rs + rr*RS;
    *(float4*)(A + (size_t)r*COUT + 4*g) = accA[rr];
    *(float4*)(B + (size_t)r*COUT + 4*g) = accB[rr];
  }
}

// ---------------- edge epilogue: out[i][c] = max_k relu(A[i][c] + B[j_ik][c]) ----------------
template<int COUT>
__global__ __launch_bounds__(256) void k_emax(const float* __restrict__ A, const float* __restrict__ Bm,
    const int* __restrict__ idx, float* __restrict__ out){
  constexpr int GT = COUT/4;
  constexpr int NC = 256/GT;
  __shared__ int js[NC*KC];
  int bi = blockIdx.x, t = threadIdx.x;
  int li = t / GT, c4 = (t % GT)*4;
  int ci = bi*NC + li;
  int rb = (ci >> 8) << 8;
  if (t < NC*KC) js[t] = idx[(size_t)bi*NC*KC + t];
  __syncthreads();
  float4 a = *(const float4*)(A + (size_t)ci*COUT + c4);
  float4 p = make_float4(0.f,0.f,0.f,0.f);
#pragma unroll
  for (int k = 0; k < KC; ++k){
    int j = js[li*KC + k];
    float4 b = *(const float4*)(Bm + (size_t)(rb + j)*COUT + c4);
    p = max4(p, add4(a, b));
  }
  *(float4*)(out + (size_t)ci*COUT + c4) = p;
}

// ---------------- T-Net edge: h0 = relu(A0+B0) then 64->128 conv + k-maxpool ----------------
__global__ __launch_bounds__(128) void k_tedge3(const float* __restrict__ A0, const float* __restrict__ B0,
    const int* __restrict__ idx, const float* __restrict__ wt1, float* __restrict__ out){
  __shared__ __align__(16) float h0s[20*68];
  __shared__ __align__(16) float smax[4*128];
  __shared__ int js[KC];
  int bi = blockIdx.x, t = threadIdx.x;
  int cg = t & 31, kg = t >> 5, k0 = kg*5;
  int rb = (bi >> 8) << 8;
  if (t < KC) js[t] = idx[(size_t)bi*KC + t];
  __syncthreads();
  for (int i = t; i < 20*64; i += 128){
    int k = i >> 6, c = i & 63;
    float v = A0[(size_t)bi*64 + c] + B0[(size_t)(rb + js[k])*64 + c];
    h0s[k*68 + c] = fmaxf(v, 0.0f);
  }
  __syncthreads();
  float4 b2[5];
#pragma unroll
  for (int kk = 0; kk < 5; ++kk) b2[kk] = make_float4(0.f,0.f,0.f,0.f);
  for (int m4 = 0; m4 < 16; ++m4){
    float4 e[5];
#pragma unroll
    for (int kk = 0; kk < 5; ++kk) e[kk] = *(const float4*)(h0s + (k0+kk)*68 + 4*m4);
#pragma unroll
    for (int mm = 0; mm < 4; ++mm){
      float4 w = *(const float4*)(wt1 + (4*m4+mm)*128 + 4*cg);
#pragma unroll
      for (int kk = 0; kk < 5; ++kk){
        float ev = (mm==0)?e[kk].x:((mm==1)?e[kk].y:((mm==2)?e[kk].z:e[kk].w));
        b2[kk] = fma4s(w, ev, b2[kk]);
      }
    }
  }
  float4 p = make_float4(0.f,0.f,0.f,0.f);
#pragma unroll
  for (int kk = 0; kk < 5; ++kk) p = max4(p, b2[kk]);
  *(float4*)(smax + kg*128 + 4*cg) = p;
  __syncthreads();
  if (kg == 0){
    float4 r = *(const float4*)(smax + 4*cg);
#pragma unroll
    for (int g = 1; g < 4; ++g) r = max4(r, *(const float4*)(smax + g*128 + 4*cg));
    *(float4*)(out + (size_t)bi*128 + 4*cg) = r;
  }
}

// ---------------- T-Net 128->1024 + pool over points ----------------
__global__ __launch_bounds__(128) void k_tpool(const float* __restrict__ h, const float* __restrict__ W,
    float* __restrict__ g1024){
  int b = blockIdx.x, t = threadIdx.x;
  int c = blockIdx.y*128 + t;
  float4 w[32];
#pragma unroll
  for (int qq = 0; qq < 32; ++qq) w[qq] = *(const float4*)(W + (size_t)c*128 + 4*qq);
  const float* hb = h + (size_t)b*NPp*128;
  float mx = 0.0f;
  for (int i = 0; i < NPp; ++i){
    const float4* hr = (const float4*)(hb + (size_t)i*128);
    float a = 0.0f;
#pragma unroll
    for (int qq = 0; qq < 32; ++qq) a = fma4(w[qq], hr[qq], a);
    mx = fmaxf(mx, a);
  }
  g1024[(size_t)b*1024 + c] = mx;
}

// ---------------- T-Net MLP + 3x3 transform applied to new_xyz ----------------
__global__ __launch_bounds__(256) void k_trest(const float* __restrict__ g1024,
    const float* __restrict__ Wg0, const float* __restrict__ Wg1,
    const float* __restrict__ Wl, const float* __restrict__ bl,
    const float* __restrict__ new_xyz, float* __restrict__ x131){
  __shared__ __align__(16) float g1[1024];
  __shared__ __align__(16) float g5[512];
  __shared__ __align__(16) float g2[256];
  __shared__ float tm[12];
  int b = blockIdx.x, t = threadIdx.x;
  for (int m = t; m < 1024; m += 256) g1[m] = g1024[(size_t)b*1024 + m];
  __syncthreads();
#pragma unroll
  for (int cc = 0; cc < 2; ++cc){
    int c = t + cc*256;
    const float4* wr = (const float4*)(Wg0 + (size_t)c*1024);
    const float4* gv = (const float4*)g1;
    float a = 0.0f;
    for (int qq = 0; qq < 256; ++qq) a = fma4(wr[qq], gv[qq], a);
    g5[c] = fmaxf(a, 0.0f);
  }
  __syncthreads();
  {
    const float4* wr = (const float4*)(Wg1 + (size_t)t*512);
    const float4* gv = (const float4*)g5;
    float a = 0.0f;
    for (int qq = 0; qq < 128; ++qq) a = fma4(wr[qq], gv[qq], a);
    g2[t] = fmaxf(a, 0.0f);
  }
  __syncthreads();
  if (t < 9){
    const float4* wr = (const float4*)(Wl + (size_t)t*256);
    const float4* gv = (const float4*)g2;
    float a = 0.0f;
#pragma unroll
    for (int qq = 0; qq < 64; ++qq) a = fma4(wr[qq], gv[qq], a);
    a += bl[t];
    if (t == 0 || t == 4 || t == 8) a += 1.0f;
    tm[t] = a;
  }
  __syncthreads();
  {
    const float* nx = new_xyz + ((size_t)b*NPp + t)*3;
    float X = nx[0], Y = nx[1], Z = nx[2];
#pragma unroll
    for (int i = 0; i < 3; ++i){
      float v = __fadd_rn(__fadd_rn(__fmul_rn(tm[i*3+0], X), __fmul_rn(tm[i*3+1], Y)), __fmul_rn(tm[i*3+2], Z));
      x131[((size_t)b*NPp + t)*132 + 128 + i] = v;
    }
  }
}

// ---------------- 896->128 conv + global max pool (atomicMax; poison is negative int) ----------------
__global__ __launch_bounds__(128) void k_dgl(const float* __restrict__ f1, const float* __restrict__ f2,
    const float* __restrict__ f3, const float* __restrict__ W, float* __restrict__ g128){
  int b = blockIdx.x, t = threadIdx.x;
  int i0 = blockIdx.y * 16;
  const float* wr = W + (size_t)t*896;
  float acc[16];
#pragma unroll
  for (int ii = 0; ii < 16; ++ii) acc[ii] = 0.0f;
  for (int q = 0; q < 32; ++q){
    float4 w = *(const float4*)(wr + 4*q);
#pragma unroll
    for (int ii = 0; ii < 16; ++ii){
      float4 v = *(const float4*)(f1 + ((size_t)b*NPp + i0 + ii)*128 + 4*q);
      acc[ii] = fma4(w, v, acc[ii]);
    }
  }
  for (int q = 0; q < 64; ++q){
    float4 w = *(const float4*)(wr + 128 + 4*q);
#pragma unroll
    for (int ii = 0; ii < 16; ++ii){
      float4 v = *(const float4*)(f2 + ((size_t)b*NPp + i0 + ii)*256 + 4*q);
      acc[ii] = fma4(w, v, acc[ii]);
    }
  }
  for (int q = 0; q < 128; ++q){
    float4 w = *(const float4*)(wr + 384 + 4*q);
#pragma unroll
    for (int ii = 0; ii < 16; ++ii){
      float4 v = *(const float4*)(f3 + ((size_t)b*NPp + i0 + ii)*512 + 4*q);
      acc[ii] = fma4(w, v, acc[ii]);
    }
  }
#pragma unroll
  for (int ii = 0; ii < 16; ++ii){
    float v = fmaxf(acc[ii], 0.0f);
    atomicMax((int*)(g128 + (size_t)b*128 + t), __float_as_int(v));
  }
}

// ---------------- classifier head ----------------
__global__ __launch_bounds__(256) void k_final(const float* __restrict__ g128,
    const float* __restrict__ W0, const float* __restrict__ W1,
    const float* __restrict__ Wc, const float* __restrict__ bc, float* __restrict__ out){
  __shared__ __align__(16) float g0[128];
  __shared__ __align__(16) float g5[512];
  __shared__ __align__(16) float g2[256];
  int b = blockIdx.x, t = threadIdx.x;
  if (t < 128) g0[t] = g128[(size_t)b*128 + t];
  __syncthreads();
#pragma unroll
  for (int cc = 0; cc < 2; ++cc){
    int c = t + cc*256;
    const float4* wr = (const float4*)(W0 + (size_t)c*128);
    const float4* gv = (const float4*)g0;
    float a = 0.0f;
#pragma unroll
    for (int qq = 0; qq < 32; ++qq) a = fma4(wr[qq], gv[qq], a);
    g5[c] = fmaxf(a, 0.0f);
  }
  __syncthreads();
  {
    const float4* wr = (const float4*)(W1 + (size_t)t*512);
    const float4* gv = (const float4*)g5;
    float a = 0.0f;
    for (int qq = 0; qq < 128; ++qq) a = fma4(wr[qq], gv[qq], a);
    g2[t] = fmaxf(a, 0.0f);
  }
  __syncthreads();
  if (t < 40){
    const float4* wr = (const float4*)(Wc + (size_t)t*256);
    const float4* gv = (const float4*)g2;
    float a = 0.0f;
#pragma unroll
    for (int qq = 0; qq < 64; ++qq) a = fma4(wr[qq], gv[qq], a);
    out[(size_t)b*40 + t] = a + bc[t];
  }
}

extern "C" void kernel_launch(void* const* d_in, const int* in_sizes, int n_in,
                              void* d_out, int out_size, void* d_ws, size_t ws_size,
                              hipStream_t stream){
  (void)in_sizes; (void)n_in; (void)out_size; (void)ws_size;
  const float* points     = (const float*)d_in[0];
  const float* sa_w0      = (const float*)d_in[1];
  const float* sa_w1      = (const float*)d_in[2];
  const float* sa_w2      = (const float*)d_in[3];
  const float* t_ec_w0    = (const float*)d_in[4];
  const float* t_ec_w1    = (const float*)d_in[5];
  const float* t_local_w  = (const float*)d_in[6];
  const float* t_g_w0     = (const float*)d_in[7];
  const float* t_g_w1     = (const float*)d_in[8];
  const float* t_lin_w    = (const float*)d_in[9];
  const float* t_lin_b    = (const float*)d_in[10];
  const float* dg_ec_w0   = (const float*)d_in[11];
  const float* dg_ec_w1   = (const float*)d_in[12];
  const float* dg_ec_w2   = (const float*)d_in[13];
  const float* dg_local_w = (const float*)d_in[14];
  const float* dg_g_w0    = (const float*)d_in[15];
  const float* dg_g_w1    = (const float*)d_in[16];
  const float* cls_w      = (const float*)d_in[17];
  const float* cls_b      = (const float*)d_in[18];
  float* out = (float*)d_out;

  float* ws     = (float*)d_ws;
  float* xyz    = ws;                    // 393216
  float* xnrm   = xyz    + 393216;       // 131072
  float* nxyz   = xnrm   + 131072;       // 24576
  float* feat   = nxyz   + 24576;        // 1048576
  float* x131   = feat   + 1048576;      // 1081344
  float* nrm    = x131   + 1081344;      // 8192
  int*   idx    = (int*)(nrm + 8192);    // 163840
  float* ht     = (float*)(idx + 163840);// 1048576 (reused as f1)
  float* g1024v = ht     + 1048576;      // 32768
  float* f2     = g1024v + 32768;        // 2097152
  float* f3     = f2     + 2097152;      // 4194304
  float* g128v  = f3     + 4194304;      // 4096
  float* wt_t1  = g128v  + 4096;         // 8192   (64x128)
  float* waT0   = wt_t1  + 8192;         // 8384   (131x64)
  float* wbT0   = waT0   + 8384;         // 8384
  float* waD0   = wbT0   + 8384;         // 16768  (131x128)
  float* wbD0   = waD0   + 16768;        // 16768
  float* waD1   = wbD0   + 16768;        // 32768  (128x256)
  float* wbD1   = waD1   + 32768;        // 32768
  float* waD2   = wbD1   + 32768;        // 131072 (256x512)
  float* wbD2   = waD2   + 131072;       // 131072
  float* Ab     = wbD2   + 131072;       // 4194304
  float* Bb     = Ab     + 4194304;      // 4194304
  float* f1 = ht;
  float* xT = f3;                        // alias: xT lives in f3 until k_emax<512> writes f3

  k_prep<<<512, 256, 0, stream>>>(points, xyz, xnrm);
  k_wprep<<<771, 256, 0, stream>>>(t_ec_w0, t_ec_w1, dg_ec_w0, dg_ec_w1, dg_ec_w2,
                                   waT0, wbT0, wt_t1, waD0, wbD0, waD1, wbD1, waD2, wbD2);
  k_fps<<<BB, 256, 0, stream>>>(xyz, nxyz);
  k_sa<<<BB*NPp, 64, 0, stream>>>(xyz, xnrm, nxyz, sa_w0, sa_w1, sa_w2, feat, x131);

  // T-Net branch (x = [feat, new_xyz])
  k_gab<131,64,256><<<512, 256, 0, stream>>>(x131, 132, waT0, wbT0, Ab, Bb, xT);
  k_norm2<131><<<128, 64, 0, stream>>>(xT, nrm);
  k_knn3<131><<<1024, 512, 0, stream>>>(xT, nrm, idx);
  k_tedge3<<<BB*NPp, 128, 0, stream>>>(Ab, Bb, idx, wt_t1, ht);
  k_tpool<<<dim3(BB, 8), 128, 0, stream>>>(ht, t_local_w, g1024v);
  k_trest<<<BB, 256, 0, stream>>>(g1024v, t_g_w0, t_g_w1, t_lin_w, t_lin_b, nxyz, x131);

  // DGCNN layer 1 (x = [feat, xyz_t], 131 dims)
  k_gab<131,128,512><<<512, 512, 0, stream>>>(x131, 132, waD0, wbD0, Ab, Bb, xT);
  k_norm2<131><<<128, 64, 0, stream>>>(xT, nrm);
  k_knn3<131><<<1024, 512, 0, stream>>>(xT, nrm, idx);
  k_emax<128><<<1024, 256, 0, stream>>>(Ab, Bb, idx, f1);
  // layer 2
  k_gab<128,256,512><<<512, 512, 0, stream>>>(f1, 128, waD1, wbD1, Ab, Bb, xT);
  k_norm2<128><<<128, 64, 0, stream>>>(xT, nrm);
  k_knn3<128><<<1024, 512, 0, stream>>>(xT, nrm, idx);
  k_emax<256><<<2048, 256, 0, stream>>>(Ab, Bb, idx, f2);
  // layer 3
  k_gab<256,512,512><<<512, 512, 0, stream>>>(f2, 256, waD2, wbD2, Ab, Bb, xT);
  k_norm2<256><<<128, 64, 0, stream>>>(xT, nrm);
  k_knn3<256><<<1024, 512, 0, stream>>>(xT, nrm, idx);
  k_emax<512><<<4096, 256, 0, stream>>>(Ab, Bb, idx, f3);

  // local conv + global pool + head
  k_dgl<<<dim3(BB, 16), 128, 0, stream>>>(f1, f2, f3, dg_local_w, g128v);
  k_final<<<BB, 256, 0, stream>>>(g128v, dg_g_w0, dg_g_w1, cls_w, cls_b, out);
}

// Round 6
// 1741.177 us; speedup vs baseline: 3.5203x; 1.0223x over previous
//
#include <hip/hip_runtime.h>
#include <math.h>

#define BB 32
#define NN 4096
#define NPp 256
#define NSs 64
#define KC 20

__device__ __forceinline__ float fma4(const float4 w, const float4 v, float a){
  a = fmaf(w.x, v.x, a); a = fmaf(w.y, v.y, a);
  a = fmaf(w.z, v.z, a); a = fmaf(w.w, v.w, a); return a;
}
__device__ __forceinline__ float4 fma4s(const float4 w, float s, float4 a){
  a.x = fmaf(w.x, s, a.x); a.y = fmaf(w.y, s, a.y);
  a.z = fmaf(w.z, s, a.z); a.w = fmaf(w.w, s, a.w); return a;
}
__device__ __forceinline__ float4 max4(float4 a, float4 b){
  a.x = fmaxf(a.x, b.x); a.y = fmaxf(a.y, b.y);
  a.z = fmaxf(a.z, b.z); a.w = fmaxf(a.w, b.w); return a;
}
__device__ __forceinline__ float4 add4(float4 a, float4 b){
  a.x += b.x; a.y += b.y; a.z += b.z; a.w += b.w; return a;
}

template<int C>
__device__ __forceinline__ int dpp_i(int x){
  return __builtin_amdgcn_update_dpp(x, x, C, 0xf, 0xf, false);
}

// ---------------- unified weight prep (all transposes/splits in one kernel) ----------------
__global__ void k_wprep(const float* __restrict__ t0, const float* __restrict__ t1,
                        const float* __restrict__ d0, const float* __restrict__ d1,
                        const float* __restrict__ d2,
                        float* __restrict__ waT0, float* __restrict__ wbT0,
                        float* __restrict__ wt_t1,
                        float* __restrict__ waD0, float* __restrict__ wbD0,
                        float* __restrict__ waD1, float* __restrict__ wbD1,
                        float* __restrict__ waD2, float* __restrict__ wbD2){
  int i = blockIdx.x*256 + threadIdx.x;
  if (i < 8384){                       // t_ec_w0: [64][262] -> A/B [131][64]
    int m = i >> 6;
    int c = i & 63;
    float bb = t0[(size_t)c*262 + m];
    float dd = t0[(size_t)c*262 + 131 + m];
    waT0[i] = __fsub_rn(bb, dd); wbT0[i] = dd;
    return;
  }
  i -= 8384;
  if (i < 8192){                       // t_ec_w1: [128][64] -> [64][128]
    int m = i >> 7, c = i & 127;
    wt_t1[i] = t1[(size_t)c*64 + m];
    return;
  }
  i -= 8192;
  if (i < 16768){                      // dg_ec_w0: [128][262] -> A/B [131][128]
    int m = i >> 7, c = i & 127;
    float bb = d0[(size_t)c*262 + m];
    float dd = d0[(size_t)c*262 + 131 + m];
    waD0[i] = __fsub_rn(bb, dd); wbD0[i] = dd;
    return;
  }
  i -= 16768;
  if (i < 32768){                      // dg_ec_w1: [256][256] -> A/B [128][256]
    int m = i >> 8, c = i & 255;
    float bb = d1[(size_t)c*256 + m];
    float dd = d1[(size_t)c*256 + 128 + m];
    waD1[i] = __fsub_rn(bb, dd); wbD1[i] = dd;
    return;
  }
  i -= 32768;
  if (i < 131072){                     // dg_ec_w2: [512][512] -> A/B [256][512]
    int m = i >> 9, c = i & 511;
    float bb = d2[(size_t)c*512 + m];
    float dd = d2[(size_t)c*512 + 256 + m];
    waD2[i] = __fsub_rn(bb, dd); wbD2[i] = dd;
  }
}

// ---------------- transpose + point norms ----------------
__global__ void k_prep(const float* __restrict__ pts, float* __restrict__ xyz, float* __restrict__ xnrm){
  int i = blockIdx.x*256 + threadIdx.x;
  if (i >= BB*NN) return;
  int b = i >> 12, n = i & (NN-1);
  float X = pts[(b*3+0)*NN + n];
  float Y = pts[(b*3+1)*NN + n];
  float Z = pts[(b*3+2)*NN + n];
  xyz[i*3+0]=X; xyz[i*3+1]=Y; xyz[i*3+2]=Z;
  xnrm[i] = __fadd_rn(__fadd_rn(__fmul_rn(X,X), __fmul_rn(Y,Y)), __fmul_rn(Z,Z));
}

// ---------------- farthest point sampling: registers + DPP reduce, 1 barrier/iter ----------------
__global__ __launch_bounds__(256) void k_fps(const float* __restrict__ xyz, float* __restrict__ new_xyz){
  __shared__ float part[2][4][8];
  int b = blockIdx.x, t = threadIdx.x;
  int w = t >> 6;
  float px[16], py[16], pz[16], dist[16];
#pragma unroll
  for (int q = 0; q < 16; ++q){
    const float* p = xyz + ((size_t)b*NN + q*256 + t)*3;
    px[q] = p[0]; py[q] = p[1]; pz[q] = p[2];
    dist[q] = __builtin_inff();
  }
  const float* p0 = xyz + (size_t)b*NN*3;
  float Px = p0[0], Py = p0[1], Pz = p0[2];
  for (int it = 0; it < NPp; ++it){
    if (t == 0){
      float* o = new_xyz + ((size_t)b*NPp + it)*3;
      o[0] = Px; o[1] = Py; o[2] = Pz;
    }
    float bv = -1.0f, bx = 0.f, by = 0.f, bz = 0.f; int bj = 0;
#pragma unroll
    for (int q = 0; q < 16; ++q){
      float dx = __fsub_rn(px[q], Px);
      float dy = __fsub_rn(py[q], Py);
      float dz = __fsub_rn(pz[q], Pz);
      float dd = __fadd_rn(__fadd_rn(__fmul_rn(dx,dx), __fmul_rn(dy,dy)), __fmul_rn(dz,dz));
      float dm = fminf(dist[q], dd);
      dist[q] = dm;
      if (dm > bv){ bv = dm; bj = q*256 + t; bx = px[q]; by = py[q]; bz = pz[q]; }
    }
    // wave64 DPP reduce (row_shr 1,2,4,8 then row_bcast 15,31) -> lane 63 holds winner
#define FPS_STAGE(C) { \
    float ov = __int_as_float(dpp_i<C>(__float_as_int(bv))); \
    int   oj = dpp_i<C>(bj); \
    float ox = __int_as_float(dpp_i<C>(__float_as_int(bx))); \
    float oy = __int_as_float(dpp_i<C>(__float_as_int(by))); \
    float oz = __int_as_float(dpp_i<C>(__float_as_int(bz))); \
    bool tk = (ov > bv) || (ov == bv && oj < bj); \
    bv = tk ? ov : bv; bj = tk ? oj : bj; \
    bx = tk ? ox : bx; by = tk ? oy : by; bz = tk ? oz : bz; }
    FPS_STAGE(0x111) FPS_STAGE(0x112) FPS_STAGE(0x114) FPS_STAGE(0x118)
    FPS_STAGE(0x142) FPS_STAGE(0x143)
#undef FPS_STAGE
    int par = it & 1;
    if ((t & 63) == 63){
      float* pp = part[par][w];
      pp[0] = bv; ((int*)pp)[1] = bj; pp[2] = bx; pp[3] = by; pp[4] = bz;
    }
    __syncthreads();
    const float* q0 = part[par][0];
    float fv = q0[0]; int fj = ((const int*)q0)[1];
    float fx = q0[2], fy = q0[3], fz = q0[4];
#pragma unroll
    for (int ww = 1; ww < 4; ++ww){
      const float* pp = part[par][ww];
      float ov = pp[0]; int oj = ((const int*)pp)[1];
      if (ov > fv || (ov == fv && oj < fj)){ fv = ov; fj = oj; fx = pp[2]; fy = pp[3]; fz = pp[4]; }
    }
    Px = fx; Py = fy; Pz = fz;
  }
}

// ---------------- ball query + SA convs + maxpool ----------------
__global__ __launch_bounds__(64) void k_sa(const float* __restrict__ xyz, const float* __restrict__ xnrm,
    const float* __restrict__ new_xyz, const float* __restrict__ w0, const float* __restrict__ w1,
    const float* __restrict__ w2, float* __restrict__ feat, float* __restrict__ x131){
  __shared__ __align__(16) float h1s[64*68];
  __shared__ int gix[64];
  int bi = blockIdx.x, lane = threadIdx.x;
  int b = bi >> 8;
  const float* q = new_xyz + (size_t)bi*3;
  float qx=q[0], qy=q[1], qz=q[2];
  float nq = __fadd_rn(__fadd_rn(__fmul_rn(qx,qx), __fmul_rn(qy,qy)), __fmul_rn(qz,qz));
  int cnt = 0;
  for (int base = 0; base < NN && cnt < NSs; base += 64){
    int j = base + lane;
    const float* p = xyz + ((size_t)b*NN + j)*3;
    float dot = __fadd_rn(__fadd_rn(__fmul_rn(qx,p[0]), __fmul_rn(qy,p[1])), __fmul_rn(qz,p[2]));
    float d2 = __fsub_rn(__fadd_rn(nq, xnrm[b*NN + j]), __fmul_rn(2.0f, dot));
    bool inb = d2 < 0.04f;
    unsigned long long m = __ballot(inb);
    int pos = cnt + (int)__popcll(m & ((1ull << lane) - 1ull));
    if (inb && pos < NSs) gix[pos] = j;
    cnt += (int)__popcll(m);
  }
  __syncthreads();
  int g0 = gix[0];
  if (lane >= cnt) gix[lane] = g0;
  __syncthreads();
  {
    int gj = gix[lane];
    const float* p = xyz + ((size_t)b*NN + gj)*3;
    float px = p[0]-qx, py = p[1]-qy, pz = p[2]-qz;
    float h0[64];
#pragma unroll
    for (int c = 0; c < 64; ++c){
      float a = fmaf(w0[c*3+2], pz, fmaf(w0[c*3+1], py, w0[c*3]*px));
      h0[c] = fmaxf(a, 0.0f);
    }
    for (int c = 0; c < 64; ++c){
      const float4* wr = (const float4*)(w1 + c*64);
      float a = 0.0f;
#pragma unroll
      for (int qq = 0; qq < 16; ++qq){
        float4 w = wr[qq];
        a = fmaf(w.x, h0[4*qq+0], a);
        a = fmaf(w.y, h0[4*qq+1], a);
        a = fmaf(w.z, h0[4*qq+2], a);
        a = fmaf(w.w, h0[4*qq+3], a);
      }
      h1s[lane*68 + c] = fmaxf(a, 0.0f);
    }
  }
  __syncthreads();
  float4 wa[16], wb[16];
#pragma unroll
  for (int qq = 0; qq < 16; ++qq){
    wa[qq] = *(const float4*)(w2 + (size_t)lane*64 + 4*qq);
    wb[qq] = *(const float4*)(w2 + (size_t)(lane+64)*64 + 4*qq);
  }
  float m0 = 0.0f, m1 = 0.0f;
  for (int s = 0; s < 64; s += 2){
    const float4* hr0 = (const float4*)(h1s + s*68);
    const float4* hr1 = (const float4*)(h1s + (s+1)*68);
    float a0 = 0.0f, a1 = 0.0f, a2 = 0.0f, a3 = 0.0f;
#pragma unroll
    for (int qq = 0; qq < 16; ++qq){
      float4 h0v = hr0[qq], h1v = hr1[qq];
      a0 = fma4(wa[qq], h0v, a0);
      a1 = fma4(wb[qq], h0v, a1);
      a2 = fma4(wa[qq], h1v, a2);
      a3 = fma4(wb[qq], h1v, a3);
    }
    m0 = fmaxf(fmaxf(m0, a0), a2); m1 = fmaxf(fmaxf(m1, a1), a3);
  }
  feat[(size_t)bi*128 + lane]      = m0;
  feat[(size_t)bi*128 + 64 + lane] = m1;
  x131[(size_t)bi*132 + lane]      = m0;
  x131[(size_t)bi*132 + 64 + lane] = m1;
  if (lane < 3) x131[(size_t)bi*132 + 128 + lane] = (lane==0)?qx:((lane==1)?qy:qz);
}

// ---------------- feature norms (from xT, coalesced) ----------------
template<int CIN>
__global__ void k_norm2(const float* __restrict__ xT, float* __restrict__ nrm){
  int p = blockIdx.x*64 + threadIdx.x;
  if (p >= BB*NPp) return;
  int b = p >> 8, col = p & 255;
  const float* base = xT + (size_t)b*CIN*256 + col;
  float a = 0.0f;
  for (int m = 0; m < CIN; ++m){
    float v = base[m*256];
    a = __fadd_rn(a, __fmul_rn(v, v));
  }
  nrm[p] = a;
}

// ---------------- kNN, 8 centroids/block, LDS-staged xT chunks ----------------
template<int CIN>
__global__ __launch_bounds__(512) void k_knn3(const float* __restrict__ xT,
    const float* __restrict__ nrm, int* __restrict__ idxo){
  __shared__ __align__(16) float sch[16*256];
  __shared__ __align__(16) float ds[8*256];
  int bi = blockIdx.x, t = threadIdx.x;
  int w = t >> 6, lane = t & 63;
  int b = bi >> 5;
  int coli = (bi & 31)*8 + w;
  const float* xb = xT + (size_t)b*CIN*256;
  float d0=0.f, d1=0.f, d2=0.f, d3=0.f;
  for (int m0 = 0; m0 < CIN; m0 += 16){
    int mc = (CIN - m0 < 16) ? (CIN - m0) : 16;
    for (int i = t; i < mc*64; i += 512){
      int mm = i >> 6, c4 = i & 63;
      *(float4*)(sch + mm*256 + c4*4) = *(const float4*)(xb + (size_t)(m0+mm)*256 + c4*4);
    }
    __syncthreads();
    for (int mm = 0; mm < mc; ++mm){
      float xm = sch[mm*256 + coli];
      float4 v = *(const float4*)(sch + mm*256 + 4*lane);
      d0 = fmaf(v.x, xm, d0); d1 = fmaf(v.y, xm, d1);
      d2 = fmaf(v.z, xm, d2); d3 = fmaf(v.w, xm, d3);
    }
    __syncthreads();
  }
  float ni = nrm[b*256 + coli];
  {
    int j0 = 4*lane;
    float4 dv;
    dv.x = __fsub_rn(__fadd_rn(ni, nrm[b*256 + j0+0]), __fmul_rn(2.0f, d0));
    dv.y = __fsub_rn(__fadd_rn(ni, nrm[b*256 + j0+1]), __fmul_rn(2.0f, d1));
    dv.z = __fsub_rn(__fadd_rn(ni, nrm[b*256 + j0+2]), __fmul_rn(2.0f, d2));
    dv.w = __fsub_rn(__fadd_rn(ni, nrm[b*256 + j0+3]), __fmul_rn(2.0f, d3));
    *(float4*)(ds + w*256 + j0) = dv;
  }
  __syncthreads();
  for (int r = 0; r < KC; ++r){
    float bv = 3.4e38f; int bj = NPp;
    float4 dv = *(const float4*)(ds + w*256 + 4*lane);
#pragma unroll
    for (int q = 0; q < 4; ++q){
      float v = (q==0)?dv.x:((q==1)?dv.y:((q==2)?dv.z:dv.w));
      int j = 4*lane + q;
      if (v < bv){ bv = v; bj = j; }
    }
#pragma unroll
    for (int off = 32; off >= 1; off >>= 1){
      float ov = __shfl_xor(bv, off, 64);
      int   oj = __shfl_xor(bj, off, 64);
      if (ov < bv || (ov == bv && oj < bj)){ bv = ov; bj = oj; }
    }
    if (lane == 0){ idxo[((size_t)b*256 + coli)*KC + r] = bj; ds[w*256 + bj] = 3.0e38f; }
    __syncthreads();
  }
}

// ---------------- per-point dual GEMM + fused xT transpose ----------------
template<int CIN, int COUT, int T>
__global__ __launch_bounds__(T) void k_gab(const float* __restrict__ x, int xstride,
    const float* __restrict__ wA, const float* __restrict__ wB,
    float* __restrict__ A, float* __restrict__ B, float* __restrict__ xT){
  constexpr int PC  = CIN + 1;
  constexpr int G   = COUT/4;
  constexpr int RS  = T/G;
  constexpr int RPT = 16/RS;
  __shared__ float xsh[16*PC];
  int bi = blockIdx.x, t = threadIdx.x;
  int g = t % G, rs = t / G;
  int i0 = bi*16;
  for (int i = t; i < 16*CIN; i += T){
    int r = i / CIN, m = i - r*CIN;
    xsh[r*PC + m] = x[(size_t)(i0+r)*xstride + m];
  }
  __syncthreads();
  {
    int bb = i0 >> 8, col0 = i0 & 255;
    float* xTb = xT + (size_t)bb*CIN*256 + col0;
    for (int i = t; i < 16*CIN; i += T){
      int m = i >> 4, r = i & 15;
      xTb[m*256 + r] = xsh[r*PC + m];
    }
  }
  float4 accA[RPT], accB[RPT];
#pragma unroll
  for (int rr = 0; rr < RPT; ++rr){
    accA[rr] = make_float4(0.f,0.f,0.f,0.f);
    accB[rr] = make_float4(0.f,0.f,0.f,0.f);
  }
  for (int m = 0; m < CIN; ++m){
    float4 wa = *(const float4*)(wA + (size_t)m*COUT + 4*g);
    float4 wb = *(const float4*)(wB + (size_t)m*COUT + 4*g);
#pragma unroll
    for (int rr = 0; rr < RPT; ++rr){
      float xv = xsh[(rs + rr*RS)*PC + m];
      accA[rr] = fma4s(wa, xv, accA[rr]);
      accB[rr] = fma4s(wb, xv, accB[rr]);
    }
  }
#pragma unroll
  for (int rr = 0; rr < RPT; ++rr){
    int r = i0 + rs + rr*RS;
    *(float4*)(A + (size_t)r*COUT + 4*g) = accA[rr];
    *(float4*)(B + (size_t)r*COUT + 4*g) = accB[rr];
  }
}

// ---------------- edge epilogue: out[i][c] = max_k relu(A[i][c] + B[j_ik][c]) ----------------
template<int COUT>
__global__ __launch_bounds__(256) void k_emax(const float* __restrict__ A, const float* __restrict__ Bm,
    const int* __restrict__ idx, float* __restrict__ out){
  constexpr int GT = COUT/4;
  constexpr int NC = 256/GT;
  __shared__ int js[NC*KC];
  int bi = blockIdx.x, t = threadIdx.x;
  int li = t / GT, c4 = (t % GT)*4;
  int ci = bi*NC + li;
  int rb = (ci >> 8) << 8;
  if (t < NC*KC) js[t] = idx[(size_t)bi*NC*KC + t];
  __syncthreads();
  float4 a = *(const float4*)(A + (size_t)ci*COUT + c4);
  float4 p = make_float4(0.f,0.f,0.f,0.f);
#pragma unroll
  for (int k = 0; k < KC; ++k){
    int j = js[li*KC + k];
    float4 b = *(const float4*)(Bm + (size_t)(rb + j)*COUT + c4);
    p = max4(p, add4(a, b));
  }
  *(float4*)(out + (size_t)ci*COUT + c4) = p;
}

// ---------------- T-Net edge: h0 = relu(A0+B0) then 64->128 conv + k-maxpool ----------------
__global__ __launch_bounds__(128) void k_tedge3(const float* __restrict__ A0, const float* __restrict__ B0,
    const int* __restrict__ idx, const float* __restrict__ wt1, float* __restrict__ out){
  __shared__ __align__(16) float h0s[20*68];
  __shared__ __align__(16) float smax[4*128];
  __shared__ int js[KC];
  int bi = blockIdx.x, t = threadIdx.x;
  int cg = t & 31, kg = t >> 5, k0 = kg*5;
  int rb = (bi >> 8) << 8;
  if (t < KC) js[t] = idx[(size_t)bi*KC + t];
  __syncthreads();
  for (int i = t; i < 20*64; i += 128){
    int k = i >> 6, c = i & 63;
    float v = A0[(size_t)bi*64 + c] + B0[(size_t)(rb + js[k])*64 + c];
    h0s[k*68 + c] = fmaxf(v, 0.0f);
  }
  __syncthreads();
  float4 b2[5];
#pragma unroll
  for (int kk = 0; kk < 5; ++kk) b2[kk] = make_float4(0.f,0.f,0.f,0.f);
  for (int m4 = 0; m4 < 16; ++m4){
    float4 e[5];
#pragma unroll
    for (int kk = 0; kk < 5; ++kk) e[kk] = *(const float4*)(h0s + (k0+kk)*68 + 4*m4);
#pragma unroll
    for (int mm = 0; mm < 4; ++mm){
      float4 w = *(const float4*)(wt1 + (4*m4+mm)*128 + 4*cg);
#pragma unroll
      for (int kk = 0; kk < 5; ++kk){
        float ev = (mm==0)?e[kk].x:((mm==1)?e[kk].y:((mm==2)?e[kk].z:e[kk].w));
        b2[kk] = fma4s(w, ev, b2[kk]);
      }
    }
  }
  float4 p = make_float4(0.f,0.f,0.f,0.f);
#pragma unroll
  for (int kk = 0; kk < 5; ++kk) p = max4(p, b2[kk]);
  *(float4*)(smax + kg*128 + 4*cg) = p;
  __syncthreads();
  if (kg == 0){
    float4 r = *(const float4*)(smax + 4*cg);
#pragma unroll
    for (int g = 1; g < 4; ++g) r = max4(r, *(const float4*)(smax + g*128 + 4*cg));
    *(float4*)(out + (size_t)bi*128 + 4*cg) = r;
  }
}

// ---------------- T-Net 128->1024 + pool over points ----------------
__global__ __launch_bounds__(128) void k_tpool(const float* __restrict__ h, const float* __restrict__ W,
    float* __restrict__ g1024){
  int b = blockIdx.x, t = threadIdx.x;
  int c = blockIdx.y*128 + t;
  float4 w[32];
#pragma unroll
  for (int qq = 0; qq < 32; ++qq) w[qq] = *(const float4*)(W + (size_t)c*128 + 4*qq);
  const float* hb = h + (size_t)b*NPp*128;
  float mx = 0.0f;
  for (int i = 0; i < NPp; ++i){
    const float4* hr = (const float4*)(hb + (size_t)i*128);
    float a = 0.0f;
#pragma unroll
    for (int qq = 0; qq < 32; ++qq) a = fma4(w[qq], hr[qq], a);
    mx = fmaxf(mx, a);
  }
  g1024[(size_t)b*1024 + c] = mx;
}

// ---------------- T-Net MLP + 3x3 transform applied to new_xyz ----------------
__global__ __launch_bounds__(256) void k_trest(const float* __restrict__ g1024,
    const float* __restrict__ Wg0, const float* __restrict__ Wg1,
    const float* __restrict__ Wl, const float* __restrict__ bl,
    const float* __restrict__ new_xyz, float* __restrict__ x131){
  __shared__ __align__(16) float g1[1024];
  __shared__ __align__(16) float g5[512];
  __shared__ __align__(16) float g2[256];
  __shared__ float tm[12];
  int b = blockIdx.x, t = threadIdx.x;
  for (int m = t; m < 1024; m += 256) g1[m] = g1024[(size_t)b*1024 + m];
  __syncthreads();
#pragma unroll
  for (int cc = 0; cc < 2; ++cc){
    int c = t + cc*256;
    const float4* wr = (const float4*)(Wg0 + (size_t)c*1024);
    const float4* gv = (const float4*)g1;
    float a = 0.0f;
    for (int qq = 0; qq < 256; ++qq) a = fma4(wr[qq], gv[qq], a);
    g5[c] = fmaxf(a, 0.0f);
  }
  __syncthreads();
  {
    const float4* wr = (const float4*)(Wg1 + (size_t)t*512);
    const float4* gv = (const float4*)g5;
    float a = 0.0f;
    for (int qq = 0; qq < 128; ++qq) a = fma4(wr[qq], gv[qq], a);
    g2[t] = fmaxf(a, 0.0f);
  }
  __syncthreads();
  if (t < 9){
    const float4* wr = (const float4*)(Wl + (size_t)t*256);
    const float4* gv = (const float4*)g2;
    float a = 0.0f;
#pragma unroll
    for (int qq = 0; qq < 64; ++qq) a = fma4(wr[qq], gv[qq], a);
    a += bl[t];
    if (t == 0 || t == 4 || t == 8) a += 1.0f;
    tm[t] = a;
  }
  __syncthreads();
  {
    const float* nx = new_xyz + ((size_t)b*NPp + t)*3;
    float X = nx[0], Y = nx[1], Z = nx[2];
#pragma unroll
    for (int i = 0; i < 3; ++i){
      float v = __fadd_rn(__fadd_rn(__fmul_rn(tm[i*3+0], X), __fmul_rn(tm[i*3+1], Y)), __fmul_rn(tm[i*3+2], Z));
      x131[((size_t)b*NPp + t)*132 + 128 + i] = v;
    }
  }
}

// ---------------- 896->128 conv + global max pool (atomicMax; poison is negative int) ----------------
__global__ __launch_bounds__(128) void k_dgl(const float* __restrict__ f1, const float* __restrict__ f2,
    const float* __restrict__ f3, const float* __restrict__ W, float* __restrict__ g128){
  int b = blockIdx.x, t = threadIdx.x;
  int i0 = blockIdx.y * 16;
  const float* wr = W + (size_t)t*896;
  float acc[16];
#pragma unroll
  for (int ii = 0; ii < 16; ++ii) acc[ii] = 0.0f;
  for (int q = 0; q < 32; ++q){
    float4 w = *(const float4*)(wr + 4*q);
#pragma unroll
    for (int ii = 0; ii < 16; ++ii){
      float4 v = *(const float4*)(f1 + ((size_t)b*NPp + i0 + ii)*128 + 4*q);
      acc[ii] = fma4(w, v, acc[ii]);
    }
  }
  for (int q = 0; q < 64; ++q){
    float4 w = *(const float4*)(wr + 128 + 4*q);
#pragma unroll
    for (int ii = 0; ii < 16; ++ii){
      float4 v = *(const float4*)(f2 + ((size_t)b*NPp + i0 + ii)*256 + 4*q);
      acc[ii] = fma4(w, v, acc[ii]);
    }
  }
  for (int q = 0; q < 128; ++q){
    float4 w = *(const float4*)(wr + 384 + 4*q);
#pragma unroll
    for (int ii = 0; ii < 16; ++ii){
      float4 v = *(const float4*)(f3 + ((size_t)b*NPp + i0 + ii)*512 + 4*q);
      acc[ii] = fma4(w, v, acc[ii]);
    }
  }
#pragma unroll
  for (int ii = 0; ii < 16; ++ii){
    float v = fmaxf(acc[ii], 0.0f);
    atomicMax((int*)(g128 + (size_t)b*128 + t), __float_as_int(v));
  }
}

// ---------------- classifier head ----------------
__global__ __launch_bounds__(256) void k_final(const float* __restrict__ g128,
    const float* __restrict__ W0, const float* __restrict__ W1,
    const float* __restrict__ Wc, const float* __restrict__ bc, float* __restrict__ out){
  __shared__ __align__(16) float g0[128];
  __shared__ __align__(16) float g5[512];
  __shared__ __align__(16) float g2[256];
  int b = blockIdx.x, t = threadIdx.x;
  if (t < 128) g0[t] = g128[(size_t)b*128 + t];
  __syncthreads();
#pragma unroll
  for (int cc = 0; cc < 2; ++cc){
    int c = t + cc*256;
    const float4* wr = (const float4*)(W0 + (size_t)c*128);
    const float4* gv = (const float4*)g0;
    float a = 0.0f;
#pragma unroll
    for (int qq = 0; qq < 32; ++qq) a = fma4(wr[qq], gv[qq], a);
    g5[c] = fmaxf(a, 0.0f);
  }
  __syncthreads();
  {
    const float4* wr = (const float4*)(W1 + (size_t)t*512);
    const float4* gv = (const float4*)g5;
    float a = 0.0f;
    for (int qq = 0; qq < 128; ++qq) a = fma4(wr[qq], gv[qq], a);
    g2[t] = fmaxf(a, 0.0f);
  }
  __syncthreads();
  if (t < 40){
    const float4* wr = (const float4*)(Wc + (size_t)t*256);
    const float4* gv = (const float4*)g2;
    float a = 0.0f;
#pragma unroll
    for (int qq = 0; qq < 64; ++qq) a = fma4(wr[qq], gv[qq], a);
    out[(size_t)b*40 + t] = a + bc[t];
  }
}

extern "C" void kernel_launch(void* const* d_in, const int* in_sizes, int n_in,
                              void* d_out, int out_size, void* d_ws, size_t ws_size,
                              hipStream_t stream){
  (void)in_sizes; (void)n_in; (void)out_size; (void)ws_size;
  const float* points     = (const float*)d_in[0];
  const float* sa_w0      = (const float*)d_in[1];
  const float* sa_w1      = (const float*)d_in[2];
  const float* sa_w2      = (const float*)d_in[3];
  const float* t_ec_w0    = (const float*)d_in[4];
  const float* t_ec_w1    = (const float*)d_in[5];
  const float* t_local_w  = (const float*)d_in[6];
  const float* t_g_w0     = (const float*)d_in[7];
  const float* t_g_w1     = (const float*)d_in[8];
  const float* t_lin_w    = (const float*)d_in[9];
  const float* t_lin_b    = (const float*)d_in[10];
  const float* dg_ec_w0   = (const float*)d_in[11];
  const float* dg_ec_w1   = (const float*)d_in[12];
  const float* dg_ec_w2   = (const float*)d_in[13];
  const float* dg_local_w = (const float*)d_in[14];
  const float* dg_g_w0    = (const float*)d_in[15];
  const float* dg_g_w1    = (const float*)d_in[16];
  const float* cls_w      = (const float*)d_in[17];
  const float* cls_b      = (const float*)d_in[18];
  float* out = (float*)d_out;

  float* ws     = (float*)d_ws;
  float* xyz    = ws;                    // 393216
  float* xnrm   = xyz    + 393216;       // 131072
  float* nxyz   = xnrm   + 131072;       // 24576
  float* feat   = nxyz   + 24576;        // 1048576
  float* x131   = feat   + 1048576;      // 1081344
  float* nrm    = x131   + 1081344;      // 8192
  int*   idx    = (int*)(nrm + 8192);    // 163840
  float* ht     = (float*)(idx + 163840);// 1048576 (reused as f1)
  float* g1024v = ht     + 1048576;      // 32768
  float* f2     = g1024v + 32768;        // 2097152
  float* f3     = f2     + 2097152;      // 4194304
  float* g128v  = f3     + 4194304;      // 4096
  float* wt_t1  = g128v  + 4096;         // 8192   (64x128)
  float* waT0   = wt_t1  + 8192;         // 8384   (131x64)
  float* wbT0   = waT0   + 8384;         // 8384
  float* waD0   = wbT0   + 8384;         // 16768  (131x128)
  float* wbD0   = waD0   + 16768;        // 16768
  float* waD1   = wbD0   + 16768;        // 32768  (128x256)
  float* wbD1   = waD1   + 32768;        // 32768
  float* waD2   = wbD1   + 32768;        // 131072 (256x512)
  float* wbD2   = waD2   + 131072;       // 131072
  float* Ab     = wbD2   + 131072;       // 4194304
  float* Bb     = Ab     + 4194304;      // 4194304
  float* f1 = ht;
  float* xT = f3;                        // alias: xT lives in f3 until k_emax<512> writes f3

  k_prep<<<512, 256, 0, stream>>>(points, xyz, xnrm);
  k_wprep<<<771, 256, 0, stream>>>(t_ec_w0, t_ec_w1, dg_ec_w0, dg_ec_w1, dg_ec_w2,
                                   waT0, wbT0, wt_t1, waD0, wbD0, waD1, wbD1, waD2, wbD2);
  k_fps<<<BB, 256, 0, stream>>>(xyz, nxyz);
  k_sa<<<BB*NPp, 64, 0, stream>>>(xyz, xnrm, nxyz, sa_w0, sa_w1, sa_w2, feat, x131);

  // T-Net branch (x = [feat, new_xyz])
  k_gab<131,64,256><<<512, 256, 0, stream>>>(x131, 132, waT0, wbT0, Ab, Bb, xT);
  k_norm2<131><<<128, 64, 0, stream>>>(xT, nrm);
  k_knn3<131><<<1024, 512, 0, stream>>>(xT, nrm, idx);
  k_tedge3<<<BB*NPp, 128, 0, stream>>>(Ab, Bb, idx, wt_t1, ht);
  k_tpool<<<dim3(BB, 8), 128, 0, stream>>>(ht, t_local_w, g1024v);
  k_trest<<<BB, 256, 0, stream>>>(g1024v, t_g_w0, t_g_w1, t_lin_w, t_lin_b, nxyz, x131);

  // DGCNN layer 1 (x = [feat, xyz_t], 131 dims)
  k_gab<131,128,512><<<512, 512, 0, stream>>>(x131, 132, waD0, wbD0, Ab, Bb, xT);
  k_norm2<131><<<128, 64, 0, stream>>>(xT, nrm);
  k_knn3<131><<<1024, 512, 0, stream>>>(xT, nrm, idx);
  k_emax<128><<<1024, 256, 0, stream>>>(Ab, Bb, idx, f1);
  // layer 2
  k_gab<128,256,512><<<512, 512, 0, stream>>>(f1, 128, waD1, wbD1, Ab, Bb, xT);
  k_norm2<128><<<128, 64, 0, stream>>>(xT, nrm);
  k_knn3<128><<<1024, 512, 0, stream>>>(xT, nrm, idx);
  k_emax<256><<<2048, 256, 0, stream>>>(Ab, Bb, idx, f2);
  // layer 3
  k_gab<256,512,512><<<512, 512, 0, stream>>>(f2, 256, waD2, wbD2, Ab, Bb, xT);
  k_norm2<256><<<128, 64, 0, stream>>>(xT, nrm);
  k_knn3<256><<<1024, 512, 0, stream>>>(xT, nrm, idx);
  k_emax<512><<<4096, 256, 0, stream>>>(Ab, Bb, idx, f3);

  // local conv + global pool + head
  k_dgl<<<dim3(BB, 16), 128, 0, stream>>>(f1, f2, f3, dg_local_w, g128v);
  k_final<<<BB, 256, 0, stream>>>(g128v, dg_g_w0, dg_g_w1, cls_w, cls_b, out);
}